// Round 10
// baseline (681.483 us; speedup 1.0000x reference)
//
#include <hip/hip_runtime.h>
#include <hip/hip_bf16.h>

// ---------------------------------------------------------------------------
// Sparse 3-level U-Net — Round 26: barrier-free gather convs (B direct L2).
// R25 (566us): stencil0 validated fragment-major B read DIRECT from global
// (L2-hot) — no staging. Top cost now y1 (77us, occ 18.8%): G=3 phase
// boundaries drain vmcnt(0) 8x/tile, killing gather prefetch; LDS caps TLP.
// R26: gmfma11/upmfma11 = ZERO LDS, ZERO barriers. 3-slot distance-2 A-gather
// register pipeline kept; B frags loaded inline (compiler-pipelined, VGPR-
// tracked deps); wave-uniform sparsity skip kept. Occupancy now VGPR-bound
// (~12-24 waves/CU vs 6) -> TLP hides gather latency.
// Baseline R25: 566.0us (y1 77). Prediction: 450-500us.
// ---------------------------------------------------------------------------

typedef __hip_bfloat16 hbf;
typedef __attribute__((ext_vector_type(8))) short short8;
typedef __attribute__((ext_vector_type(4))) float f32x4;

__device__ inline float b2f(short s) {
    unsigned u = ((unsigned)(unsigned short)s) << 16;
    float f; __builtin_memcpy(&f, &u, 4); return f;
}
__device__ inline short f2b(float f) {
    hbf h = __float2bfloat16(f);
    short s; __builtin_memcpy(&s, &h, 2); return s;
}

// ---------- weight prep: all 9 layers in one launch ------------------------
struct WPA {
    const float* src[9];
    short* dst[9];
    int CI[9], CO[9];
    int cum[10];
};
__global__ __launch_bounds__(256) void wprep_all(WPA a, int total) {
    int e0 = blockIdx.x * 256 + threadIdx.x;
    if (e0 >= total) return;
    int L = 0;
#pragma unroll
    for (int i = 1; i < 9; i++) L += (e0 >= a.cum[i]) ? 1 : 0;
    int e = e0 - a.cum[L];
    int CI = a.CI[L], CO = a.CO[L];
    int NT = CO >> 4, NCH = CI >> 5;
    int j    = e & 7;
    int lane = (e >> 3) & 63;
    int t    = (e >> 9) % NT;
    int c    = (e / (512 * NT)) % NCH;
    int k    = e / (512 * NT * NCH);
    int ci = c * 32 + (lane >> 4) * 8 + j;
    int co = t * 16 + (lane & 15);
    a.dst[L][e] = f2b(a.src[L][((long long)k * CI + ci) * CO + co]);
}

// ---------- zero the atomic-stats slots ------------------------------------
__global__ void zerok(float* p, int n) {
    int i = blockIdx.x * 256 + threadIdx.x;
    if (i < n) p[i] = 0.f;
}

// ---------- presence mask from nbr0 (27 bits/row) --------------------------
__global__ __launch_bounds__(256) void nbrmask_k(const int* __restrict__ nbr,
                                                 unsigned* __restrict__ msk, int N) {
    long long r = (long long)blockIdx.x * 256 + threadIdx.x;
    if (r >= N) return;
    unsigned mv = 0;
#pragma unroll
    for (int k = 0; k < 27; k++)
        mv |= (nbr[r * 27 + k] >= 0) ? (1u << k) : 0u;
    msk[r] = mv;
}

// ---------- input conv (CIN=3, f32 VALU, bf16 out) -------------------------
__global__ __launch_bounds__(256) void conv_in(
    const float* __restrict__ feat, const int* __restrict__ nbr,
    const float* __restrict__ W, short* __restrict__ out, int N) {
    __shared__ float sW[27 * 96];
    const int tid = threadIdx.x;
    for (int e = tid; e < 27 * 96; e += 256) sW[e] = W[e];
    __syncthreads();
    long long r = (long long)blockIdx.x * 256 + tid;
    if (r >= N) return;
    float acc[32];
#pragma unroll
    for (int c = 0; c < 32; c++) acc[c] = 0.f;
    for (int k = 0; k < 27; k++) {
        int idx = nbr[r * 27 + k];
        if (idx >= 0) {
            float f0 = feat[(long long)idx * 3];
            float f1 = feat[(long long)idx * 3 + 1];
            float f2 = feat[(long long)idx * 3 + 2];
            const float* w = sW + k * 96;
#pragma unroll
            for (int c = 0; c < 32; c++)
                acc[c] += f0 * w[c] + f1 * w[32 + c] + f2 * w[64 + c];
        }
    }
#pragma unroll
    for (int c = 0; c < 32; c++) out[r * 32 + c] = f2b(acc[c]);
}

// ---------- stencil conv for level 0 (dense 512x512 grid) ------------------
template<int CI1, int CI2, int COUT>
__global__ __launch_bounds__(256) void stencil0(
    const short* __restrict__ fA, const short* __restrict__ fB,
    const unsigned* __restrict__ msk, const short* __restrict__ Wf,
    short* __restrict__ out, float* __restrict__ pstat,
    const float* __restrict__ abA, const float* __restrict__ abB, int N) {
    constexpr int CIT  = CI1 + CI2;
    constexpr int NCH  = CIT / 32;
    constexpr int NT   = COUT / 16;
    constexpr int MT   = 2;
    constexpr int CIB  = CIT * 2;               // bytes per row
    constexpr int ROWS = 130;
    constexpr int NC8  = CIT / 8;               // 16B chunks per row
    constexpr int SWB  = (CIB >= 128) ? 7 : 3;  // swizzle row bits
    __shared__ __attribute__((aligned(16))) char sA[3 * ROWS * CIB];
    const int tid  = threadIdx.x;
    const int lane = tid & 63;
    const int wid  = tid >> 6;
    const int m    = lane & 15;
    const int quad = lane >> 4;
    const int bid  = blockIdx.x;
    const int xq     = bid >> 2;
    const int ystart = (bid & 3) << 7;
    const long long R = (long long)bid * 128;

    {
        const int c8 = tid % NC8;
        const bool isA = (c8 * 8) < CI1;
        const short* src  = isA ? fA : fB;
        const float* abp  = isA ? abA : abB;
        const int   srcCI = isA ? CI1 : CI2;
        const int   chb   = isA ? c8 * 8 : c8 * 8 - CI1;
        float s_[8], b_[8];
#pragma unroll
        for (int jj = 0; jj < 8; jj++) {
            s_[jj] = abp[chb + jj];
            b_[jj] = abp[srcCI + chb + jj];
        }
        for (int e = tid; e < 3 * ROWS * NC8; e += 256) {
            int rr = (e / NC8) % ROWS;
            int st = e / (NC8 * ROWS);
            long long gr = (long long)(xq - 1 + st) * 512 + (ystart - 1 + rr);
            long long grc = (gr < 0 || gr >= N) ? 0 : gr;
            short8 v = *reinterpret_cast<const short8*>(src + grc * srcCI + chb);
            short8 o;
#pragma unroll
            for (int jj = 0; jj < 8; jj++) {
                float f = b2f(v[jj]) * s_[jj] + b_[jj];
                o[jj] = f2b(f > 0.f ? f : 0.f);
            }
            int byte = (st * ROWS + rr) * CIB + c8 * 16;
            byte ^= ((rr & SWB) << 4);
            *reinterpret_cast<short8*>(sA + byte) = o;
        }
    }
    __syncthreads();

    f32x4 acc[MT][NT];
#pragma unroll
    for (int mt = 0; mt < MT; mt++)
#pragma unroll
        for (int t = 0; t < NT; t++) acc[mt][t] = (f32x4)0.f;

    unsigned mv[MT];
#pragma unroll
    for (int mt = 0; mt < MT; mt++) {
        long long r = R + wid * 32 + mt * 16 + m;
        mv[mt] = (r < N) ? msk[r] : 0u;
    }

#pragma unroll
    for (int s9 = 0; s9 < 9; s9++) {
        const int st = s9 / 3;
        const int dy = s9 % 3 - 1;
        short8 a[MT][NCH];
#pragma unroll
        for (int mt = 0; mt < MT; mt++) {
            int rl = 1 + wid * 32 + mt * 16 + m + dy;
#pragma unroll
            for (int c = 0; c < NCH; c++) {
                int byte = (st * ROWS + rl) * CIB + (c * 4 + quad) * 16;
                byte ^= ((rl & SWB) << 4);
                a[mt][c] = *reinterpret_cast<const short8*>(sA + byte);
            }
        }
#pragma unroll
        for (int z3 = 0; z3 < 3; z3++) {
            const int k = s9 * 3 + z3;
            unsigned anyb = (mv[0] >> k) & 1;
            if (MT > 1) anyb |= (mv[1] >> k) & 1;
            if (__any(anyb)) {
                short8 bf[NCH][NT];
#pragma unroll
                for (int c = 0; c < NCH; c++)
#pragma unroll
                    for (int t = 0; t < NT; t++)
                        bf[c][t] = *reinterpret_cast<const short8*>(
                            Wf + ((size_t)(k * NCH + c) * NT + t) * 512 + lane * 8);
#pragma unroll
                for (int mt = 0; mt < MT; mt++) {
                    const bool bb = (mv[mt] >> k) & 1;
                    short8 asel[NCH];
#pragma unroll
                    for (int c = 0; c < NCH; c++)
                        asel[c] = bb ? a[mt][c] : (short8)0;
#pragma unroll
                    for (int c = 0; c < NCH; c++)
#pragma unroll
                        for (int t = 0; t < NT; t++)
                            acc[mt][t] = __builtin_amdgcn_mfma_f32_16x16x32_bf16(
                                asel[c], bf[c][t], acc[mt][t], 0, 0, 0);
                }
            }
        }
    }

    float s[NT], q[NT];
#pragma unroll
    for (int t = 0; t < NT; t++) { s[t] = 0.f; q[t] = 0.f; }
#pragma unroll
    for (int mt = 0; mt < MT; mt++) {
#pragma unroll
        for (int g4 = 0; g4 < 4; g4++) {
            long long sr = R + wid * 32 + mt * 16 + quad * 4 + g4;
            if (sr < N) {
#pragma unroll
                for (int t = 0; t < NT; t++) {
                    float v = acc[mt][t][g4];
                    out[sr * COUT + t * 16 + m] = f2b(v);
                    s[t] += v; q[t] += v * v;
                }
            }
        }
    }
    float* pb = pstat + (blockIdx.x & 7) * 2 * COUT;
#pragma unroll
    for (int t = 0; t < NT; t++) {
        float sv = s[t], qv = q[t];
        sv += __shfl_xor(sv, 16); qv += __shfl_xor(qv, 16);
        sv += __shfl_xor(sv, 32); qv += __shfl_xor(qv, 32);
        if (quad == 0) {
            atomicAdd(&pb[t * 16 + m], sv);
            atomicAdd(&pb[COUT + t * 16 + m], qv);
        }
    }
}

// ---------- MFMA gather conv v11: barrier-free, B direct from L2 -----------
template<int CI1, int CI2, int COUT, int K, int MT, bool FACT>
__global__ __launch_bounds__(256) void gmfma11(
    const short* __restrict__ fA, const short* __restrict__ fB,
    const int* __restrict__ nbr, const short* __restrict__ Wf,
    short* __restrict__ out, float* __restrict__ pstat,
    const float* __restrict__ abp, int N) {
    static_assert(!FACT || CI2 == 0, "fused act only for single input");
    constexpr int NT  = COUT / 16;
    constexpr int NC1 = CI1 / 32;
    constexpr int NC2 = CI2 / 32;
    constexpr int NCH = (CI1 + CI2) / 32;
    const int tid  = threadIdx.x;
    const int lane = tid & 63;
    const int wid  = tid >> 6;
    const int m    = lane & 15;
    const int quad = lane >> 4;
    const long long tb0 = ((long long)blockIdx.x * 4 + wid) * (MT * 16);

    f32x4 acc[MT][NT];
#pragma unroll
    for (int mt = 0; mt < MT; mt++)
#pragma unroll
        for (int t = 0; t < NT; t++) acc[mt][t] = (f32x4)0.f;

    int idxs[MT][K];
#pragma unroll
    for (int mt = 0; mt < MT; mt++) {
        long long r = tb0 + mt * 16 + m;
        bool rv = r < N;
#pragma unroll
        for (int k = 0; k < K; k++)
            idxs[mt][k] = rv ? nbr[r * K + k] : -1;
    }
    unsigned pmask[MT];
#pragma unroll
    for (int mt = 0; mt < MT; mt++) {
        unsigned pm = 0;
#pragma unroll
        for (int k = 0; k < K; k++)
            pm |= __any(idxs[mt][k] >= 0) ? (1u << k) : 0u;
        pmask[mt] = __builtin_amdgcn_readfirstlane(pm);
    }

    float aS[FACT ? NC1 * 8 : 1], aBb[FACT ? NC1 * 8 : 1];
    if constexpr (FACT) {
#pragma unroll
        for (int c = 0; c < NC1; c++)
#pragma unroll
            for (int jj = 0; jj < 8; jj++) {
                int ch = c * 32 + quad * 8 + jj;
                aS[c * 8 + jj]  = abp[ch];
                aBb[c * 8 + jj] = abp[CI1 + ch];
            }
    }

    short8 S[3][NCH];   // 3-slot register pipeline (distance-2)

#define LOADS(sl, mt, kk)                                                      \
    {                                                                          \
        int _i = idxs[mt][kk];                                                 \
        long long _j = _i < 0 ? 0 : _i;                                        \
        _Pragma("unroll")                                                      \
        for (int c = 0; c < NC1; c++) {                                        \
            short8 _v = *reinterpret_cast<const short8*>(                      \
                fA + _j * CI1 + c * 32 + quad * 8);                            \
            if constexpr (FACT) {                                              \
                short8 _o;                                                     \
                _Pragma("unroll")                                              \
                for (int jj = 0; jj < 8; jj++) {                               \
                    float _f = b2f(_v[jj]) * aS[c * 8 + jj] + aBb[c * 8 + jj]; \
                    _o[jj] = f2b(_f > 0.f ? _f : 0.f);                         \
                }                                                              \
                _v = _o;                                                       \
            }                                                                  \
            S[sl][c] = (_i >= 0) ? _v : (short8)0;                             \
        }                                                                      \
        if constexpr (NC2 > 0) {                                               \
            _Pragma("unroll")                                                  \
            for (int c = 0; c < NC2; c++) {                                    \
                short8 _v = *reinterpret_cast<const short8*>(                  \
                    fB + _j * CI2 + c * 32 + quad * 8);                        \
                S[sl][NC1 + c] = (_i >= 0) ? _v : (short8)0;                   \
            }                                                                  \
        }                                                                      \
    }
    // MFMA with B fragments loaded directly from global (L2-hot, compiler-
    // pipelined; all deps VGPR-tracked -> no fences needed anywhere).
#define MFMAD(sl, mt, kk)                                                      \
    {                                                                          \
        _Pragma("unroll")                                                      \
        for (int c = 0; c < NCH; c++) {                                        \
            _Pragma("unroll")                                                  \
            for (int t = 0; t < NT; t++) {                                     \
                short8 b = *reinterpret_cast<const short8*>(                   \
                    Wf + ((size_t)((kk) * NCH + c) * NT + t) * 512 + lane * 8);\
                acc[mt][t] = __builtin_amdgcn_mfma_f32_16x16x32_bf16(          \
                    S[sl][c], b, acc[mt][t], 0, 0, 0);                         \
            }                                                                  \
        }                                                                      \
    }

#pragma unroll
    for (int mt = 0; mt < MT; mt++) {
        const unsigned mm = pmask[mt];
        if (mm & 1u) LOADS(0, mt, 0)
        if (K > 1 && (mm & 2u)) LOADS(1, mt, 1)
#pragma unroll
        for (int k = 0; k < K; k++) {
            if (k + 2 < K)
                if (mm & (1u << (k + 2))) LOADS((k + 2) % 3, mt, k + 2)
            if (mm & (1u << k)) MFMAD(k % 3, mt, k)
        }
    }
#undef LOADS
#undef MFMAD
    // D: col = lane&15, row = quad*4 + reg
    float s[NT], q[NT];
#pragma unroll
    for (int t = 0; t < NT; t++) { s[t] = 0.f; q[t] = 0.f; }
#pragma unroll
    for (int mt = 0; mt < MT; mt++) {
#pragma unroll
        for (int g4 = 0; g4 < 4; g4++) {
            long long sr = tb0 + mt * 16 + quad * 4 + g4;
            if (sr < N) {
#pragma unroll
                for (int t = 0; t < NT; t++) {
                    float v = acc[mt][t][g4];
                    out[sr * COUT + t * 16 + m] = f2b(v);
                    s[t] += v; q[t] += v * v;
                }
            }
        }
    }
    float* pb = pstat + (blockIdx.x & 7) * 2 * COUT;
#pragma unroll
    for (int t = 0; t < NT; t++) {
        float sv = s[t], qv = q[t];
        sv += __shfl_xor(sv, 16); qv += __shfl_xor(qv, 16);
        sv += __shfl_xor(sv, 32); qv += __shfl_xor(qv, 32);
        if (quad == 0) {
            atomicAdd(&pb[t * 16 + m], sv);
            atomicAdd(&pb[COUT + t * 16 + m], qv);
        }
    }
}

// ---------- MFMA up conv v11: barrier-free, B direct from L2 ---------------
template<int CIN, int COUT>
__global__ __launch_bounds__(256) void upmfma11(
    const short* __restrict__ f, const int* __restrict__ rb,
    const short* __restrict__ Wf, short* __restrict__ out,
    float* __restrict__ pstat, const float* __restrict__ abp, int N) {
    constexpr int NT = COUT / 16;
    constexpr int NK = CIN / 32;
    const int tid  = threadIdx.x;
    const int lane = tid & 63;
    const int wid  = tid >> 6;
    const int m    = lane & 15;
    const int quad = lane >> 4;
    const long long row0 = ((long long)blockIdx.x * 4 + wid) * 16;
    const long long r = row0 + m;
    const bool rv = r < N;
    const long long rc = rv ? r : 0;

    short8 af[NK];
#pragma unroll
    for (int kc = 0; kc < NK; kc++) {
        short8 v = *reinterpret_cast<const short8*>(
            f + rc * CIN + kc * 32 + quad * 8);
        short8 o;
#pragma unroll
        for (int jj = 0; jj < 8; jj++) {
            int ch = kc * 32 + quad * 8 + jj;
            float u = b2f(v[jj]) * abp[ch] + abp[CIN + ch];
            o[jj] = f2b(u > 0.f ? u : 0.f);
        }
        af[kc] = rv ? o : (short8)0;
    }
    int sidx[8][4];
#pragma unroll
    for (int g4 = 0; g4 < 4; g4++) {
        long long sr = row0 + quad * 4 + g4;
#pragma unroll
        for (int k = 0; k < 8; k++)
            sidx[k][g4] = (sr < N) ? rb[sr * 8 + k] : -1;
    }
    unsigned pm = 0;
#pragma unroll
    for (int k = 0; k < 8; k++) {
        int anyv = (sidx[k][0] >= 0) | (sidx[k][1] >= 0) |
                   (sidx[k][2] >= 0) | (sidx[k][3] >= 0);
        pm |= __any(anyv) ? (1u << k) : 0u;
    }
    pm = __builtin_amdgcn_readfirstlane(pm);

    float s[NT], q[NT];
#pragma unroll
    for (int t = 0; t < NT; t++) { s[t] = 0.f; q[t] = 0.f; }

#pragma unroll
    for (int k = 0; k < 8; k++) {
        if (pm & (1u << k)) {
            f32x4 acc[NT];
#pragma unroll
            for (int t = 0; t < NT; t++) acc[t] = (f32x4)0.f;
#pragma unroll
            for (int kc = 0; kc < NK; kc++) {
#pragma unroll
                for (int t = 0; t < NT; t++) {
                    short8 b = *reinterpret_cast<const short8*>(
                        Wf + ((size_t)(k * NK + kc) * NT + t) * 512 + lane * 8);
                    acc[t] = __builtin_amdgcn_mfma_f32_16x16x32_bf16(
                        af[kc], b, acc[t], 0, 0, 0);
                }
            }
#pragma unroll
            for (int g4 = 0; g4 < 4; g4++) {
                if (sidx[k][g4] >= 0) {
#pragma unroll
                    for (int t = 0; t < NT; t++) {
                        float v = acc[t][g4];
                        out[(long long)sidx[k][g4] * COUT + t * 16 + m] = f2b(v);
                        s[t] += v; q[t] += v * v;
                    }
                }
            }
        }
    }
    float* pb = pstat + (blockIdx.x & 7) * 2 * COUT;
#pragma unroll
    for (int t = 0; t < NT; t++) {
        float sv = s[t], qv = q[t];
        sv += __shfl_xor(sv, 16); qv += __shfl_xor(qv, 16);
        sv += __shfl_xor(sv, 32); qv += __shfl_xor(qv, 32);
        if (quad == 0) {
            atomicAdd(&pb[t * 16 + m], sv);
            atomicAdd(&pb[COUT + t * 16 + m], qv);
        }
    }
}

// ---------- BN stats (only for conv_in's output), f64 deterministic --------
template<int C>
__global__ void bn_stats(const short* __restrict__ x, double* __restrict__ part, int N) {
    constexpr int GR  = C / 8;
    constexpr int RPB = 256 / GR;
    constexpr int ACTIVE = GR * RPB;
    __shared__ double ls[256 * 8];
    __shared__ double lq[256 * 8];
    const int tid = threadIdx.x;
    const int g   = tid % GR;
    const int rr  = tid / GR;
    double s[8], q[8];
#pragma unroll
    for (int j = 0; j < 8; j++) { s[j] = 0.0; q[j] = 0.0; }
    if (tid < ACTIVE) {
        for (long long r = (long long)blockIdx.x * RPB + rr; r < N;
             r += (long long)gridDim.x * RPB) {
            short8 v = *reinterpret_cast<const short8*>(x + r * C + g * 8);
#pragma unroll
            for (int j = 0; j < 8; j++) {
                double f = (double)b2f(v[j]);
                s[j] += f; q[j] += f * f;
            }
        }
    }
#pragma unroll
    for (int j = 0; j < 8; j++) { ls[tid * 8 + j] = s[j]; lq[tid * 8 + j] = q[j]; }
    __syncthreads();
    if (tid < C) {
        int gg = tid / 8, jj = tid % 8;
        double S = 0.0, Q = 0.0;
        for (int r2 = 0; r2 < RPB; r2++) {
            S += ls[(r2 * GR + gg) * 8 + jj];
            Q += lq[(r2 * GR + gg) * 8 + jj];
        }
        part[blockIdx.x * 256 + tid]       = S;
        part[blockIdx.x * 256 + 128 + tid] = Q;
    }
}

__global__ void bn_fin(const double* __restrict__ part, const float* __restrict__ gb,
                       int gbfull, int goff, float* __restrict__ ab,
                       int C, int P, double invN) {
    __shared__ double ss[256], sq[256];
    const int tid = threadIdx.x;
    const int c   = tid % C;
    const int g   = tid / C;
    const int G   = 256 / C;
    double s = 0.0, q = 0.0;
    if (g < G) {
        for (int p = g; p < P; p += G) {
            s += part[p * 256 + c];
            q += part[p * 256 + 128 + c];
        }
    }
    ss[tid] = s; sq[tid] = q;
    __syncthreads();
    if (tid < C) {
        for (int j = 1; j < G; j++) { s += ss[j * C + c]; q += sq[j * C + c]; }
        double mu  = s * invN;
        double var = q * invN - mu * mu;
        double a   = (double)gb[goff + c] / sqrt(var + 1e-4);
        ab[c]     = (float)a;
        ab[C + c] = (float)((double)gb[gbfull + goff + c] - mu * a);
    }
}

// ---------- bn_fin_a: reduce 8 atomic banks -> ab --------------------------
__global__ void bn_fin_a(const float* __restrict__ pst, const float* __restrict__ gb,
                         int gbfull, int goff, float* __restrict__ ab,
                         int C, double invN) {
    int c = threadIdx.x;
    if (c >= C) return;
    double s = 0.0, q = 0.0;
#pragma unroll
    for (int b = 0; b < 8; b++) {
        s += (double)pst[b * 2 * C + c];
        q += (double)pst[b * 2 * C + C + c];
    }
    double mu  = s * invN;
    double var = q * invN - mu * mu;
    double a   = (double)gb[goff + c] / sqrt(var + 1e-4);
    ab[c]     = (float)a;
    ab[C + c] = (float)((double)gb[gbfull + goff + c] - mu * a);
}

// ---------- bnact: y = relu(x*a + b), bf16 -> bf16, 8 elems/thread ---------
template<int C>
__global__ void bnact(const short* __restrict__ x, const float* __restrict__ ab,
                      short* __restrict__ y, long long total8) {
    long long i = (long long)blockIdx.x * blockDim.x + threadIdx.x;
    if (i >= total8) return;
    long long base = i * 8;
    int c0 = (int)(base % C);
    short8 v = *reinterpret_cast<const short8*>(x + base);
    short8 o;
#pragma unroll
    for (int j = 0; j < 8; j++) {
        float f = b2f(v[j]) * ab[c0 + j] + ab[C + c0 + j];
        o[j] = f2b(f > 0.f ? f : 0.f);
    }
    *reinterpret_cast<short8*>(y + base) = o;
}

// ---------- bnact2: two tensors in one launch ------------------------------
template<int C>
__global__ void bnact2(const short* __restrict__ xa, const float* __restrict__ aba,
                       short* __restrict__ ya,
                       const short* __restrict__ xb, const float* __restrict__ abb,
                       short* __restrict__ yb, long long n8) {
    long long i = (long long)blockIdx.x * blockDim.x + threadIdx.x;
    if (i >= 2 * n8) return;
    const short* x; const float* ab; short* y; long long ii;
    if (i < n8) { x = xa; ab = aba; y = ya; ii = i; }
    else        { x = xb; ab = abb; y = yb; ii = i - n8; }
    long long base = ii * 8;
    int c0 = (int)(base % C);
    short8 v = *reinterpret_cast<const short8*>(x + base);
    short8 o;
#pragma unroll
    for (int j = 0; j < 8; j++) {
        float f = b2f(v[j]) * ab[c0 + j] + ab[C + c0 + j];
        o[j] = f2b(f > 0.f ? f : 0.f);
    }
    *reinterpret_cast<short8*>(y + base) = o;
}

// ---------- final linear (bnf fused), bf16 in, f32 out ---------------------
__global__ void final_k(const short* __restrict__ x, const float* __restrict__ ab,
                        const float* __restrict__ lw, const float* __restrict__ lb,
                        float* __restrict__ out, int N) {
    long long r = (long long)blockIdx.x * blockDim.x + threadIdx.x;
    if (r >= N) return;
    float a0 = lb[0], a1 = lb[1];
#pragma unroll
    for (int j = 0; j < 4; j++) {
        short8 v = *reinterpret_cast<const short8*>(x + r * 32 + j * 8);
#pragma unroll
        for (int t = 0; t < 8; t++) {
            int ci = 8 * j + t;
            float u = b2f(v[t]) * ab[ci] + ab[32 + ci];
            u = u > 0.f ? u : 0.f;
            a0 += u * lw[ci * 2];
            a1 += u * lw[ci * 2 + 1];
        }
    }
    out[2 * r]     = a0;
    out[2 * r + 1] = a1;
}

extern "C" void kernel_launch(void* const* d_in, const int* in_sizes, int n_in,
                              void* d_out, int out_size, void* d_ws, size_t ws_size,
                              hipStream_t stream) {
    const long long N0 = in_sizes[0] / 3;
    const long long N1 = in_sizes[26] / 8;
    const long long N2 = in_sizes[27] / 8;
    const int P = 256;

    const float* feat = (const float*)d_in[0];
    const int* nbr0 = (const int*)d_in[23];
    const int* nbr1 = (const int*)d_in[24];
    const int* nbr2 = (const int*)d_in[25];
    const int* rb0  = (const int*)d_in[26];
    const int* rb1  = (const int*)d_in[27];

    // ---- arena ----
    char* p = (char*)d_ws;
    double* part = (double*)p;            p += (size_t)P * 256 * 8;     // 512 KB
    float*  ab   = (float*)p;             p += 12 * 256 * 4;
    float*  pst  = (float*)p;             p += (size_t)10 * 2048 * 4;
    unsigned* msk0 = (unsigned*)p;        p += ((size_t)N0 * 4 + 63) & ~(size_t)63;
    const int wLayer[9] = {3, 5, 7, 9, 11, 13, 15, 17, 19};
    const int wK[9]  = {27, 8, 27, 8, 27, 8, 27, 8, 27};
    const int wCI[9] = {32, 32, 64, 64, 96, 96, 128, 64, 64};
    const int wCO[9] = {32, 64, 64, 96, 96, 64, 64, 32, 32};
    short* wt[9];
    WPA wpa;
    int cum = 0;
    for (int i = 0; i < 9; i++) {
        wt[i] = (short*)p;
        int n = wK[i] * wCI[i] * wCO[i];
        p += (((size_t)n * 2 + 63) & ~(size_t)63);
        wpa.src[i] = (const float*)d_in[wLayer[i]];
        wpa.dst[i] = wt[i];
        wpa.CI[i] = wCI[i]; wpa.CO[i] = wCO[i];
        wpa.cum[i] = cum; cum += n;
    }
    wpa.cum[9] = cum;
    auto balloc = [&](long long elems) {
        short* q = (short*)p;
        p += (((size_t)elems * 2 + 63) & ~(size_t)63);
        return q;
    };
    short* R0 = balloc(N0 * 32);   // t0 / d0 / d1 / u1 / u0 (raw)
    short* R1 = balloc(N0 * 32);   // x0 raw (persist)
    short* R2 = balloc(N1 * 64);   // x1 raw (persist)
    short* R3 = balloc(N0 * 32);   // x2 / y1 / y0 (raw)
    short* Xb = balloc(N0 * 32);   // act out #1
    short* Yb = balloc(N0 * 32);   // act out #2

    wprep_all<<<(cum + 255) / 256, 256, 0, stream>>>(wpa, cum);
    zerok<<<(10 * 2048 + 255) / 256, 256, 0, stream>>>(pst, 10 * 2048);
    nbrmask_k<<<(int)((N0 + 255) / 256), 256, 0, stream>>>(nbr0, msk0, (int)N0);

#define AB(SL) (ab + (SL) * 256)
#define PS(SL) (pst + (SL) * 2048)
#define FINA(PSL, GBI, GBFULL, GOFF, SL, CH, NN)                                     \
    bn_fin_a<<<1, 128, 0, stream>>>(PS(PSL), (const float*)d_in[GBI], GBFULL, GOFF,  \
                                    AB(SL), CH, 1.0 / (double)(NN))
#define GB1(N_) (int)(((N_) + 63) / 64)
#define GB2(N_) (int)(((N_) + 127) / 128)

    // ---- level 0 ----
    conv_in<<<(int)((N0 + 255) / 256), 256, 0, stream>>>(
        feat, nbr0, (const float*)d_in[1], R0, (int)N0);                  // t0 -> R0
    bn_stats<32><<<P, 256, 0, stream>>>(R0, part, (int)N0);               // bn1_0
    bn_fin<<<1, 256, 0, stream>>>(part, (const float*)d_in[2], 32, 0,
                                  AB(0), 32, P, 1.0 / (double)N0);
    stencil0<32, 0, 32><<<GB2(N0), 256, 0, stream>>>(
        R0, nullptr, msk0, wt[0], R1, PS(0), AB(0), nullptr, (int)N0);    // x0 -> R1
    FINA(0, 4, 32, 0, 1, 32, N0);                                         // bnd_0
    FINA(0, 18, 64, 0, 9, 32, N0);                                        // bn2_0[x0]
    gmfma11<32, 0, 64, 8, 2, true><<<GB2(N1), 256, 0, stream>>>(
        R1, nullptr, rb0, wt[1], R0, PS(1), AB(1), (int)N1);              // d0 -> R0
    FINA(1, 6, 64, 0, 2, 64, N1);                                         // bn1_1

    // ---- level 1 ----
    bnact<64><<<(int)((N1 * 64 / 8 + 255) / 256), 256, 0, stream>>>(
        R0, AB(2), Xb, N1 * 64 / 8);
    gmfma11<64, 0, 64, 27, 2, false><<<GB2(N1), 256, 0, stream>>>(
        Xb, nullptr, nbr1, wt[2], R2, PS(2), nullptr, (int)N1);           // x1 -> R2
    FINA(2, 8, 64, 0, 3, 64, N1);                                         // bnd_1
    FINA(2, 14, 128, 0, 6, 64, N1);                                       // bn2_1[x1]
    gmfma11<64, 0, 96, 8, 1, true><<<GB1(N2), 256, 0, stream>>>(
        R2, nullptr, rb1, wt[3], R0, PS(3), AB(3), (int)N2);              // d1 -> R0
    FINA(3, 10, 96, 0, 4, 96, N2);                                        // bn1_2

    // ---- level 2 ----
    bnact<96><<<(int)((N2 * 96 / 8 + 255) / 256), 256, 0, stream>>>(
        R0, AB(4), Xb, N2 * 96 / 8);
    gmfma11<96, 0, 96, 27, 1, false><<<GB1(N2), 256, 0, stream>>>(
        Xb, nullptr, nbr2, wt[4], R3, PS(4), nullptr, (int)N2);           // x2 -> R3
    FINA(4, 12, 96, 0, 5, 96, N2);                                        // bnu_1

    // ---- up to level 1 ----
    upmfma11<96, 64><<<GB1(N2), 256, 0, stream>>>(
        R3, rb1, wt[5], R0, PS(5), AB(5), (int)N2);                       // u1 -> R0
    FINA(5, 14, 128, 64, 7, 64, N1);                                      // bn2_1[u1]
    bnact2<64><<<(int)((2 * (N1 * 64 / 8) + 255) / 256), 256, 0, stream>>>(
        R2, AB(6), Xb, R0, AB(7), Yb, N1 * 64 / 8);
    gmfma11<64, 64, 64, 27, 2, false><<<GB2(N1), 256, 0, stream>>>(
        Xb, Yb, nbr1, wt[6], R3, PS(6), nullptr, (int)N1);                // y1 -> R3
    FINA(6, 16, 64, 0, 8, 64, N1);                                        // bnu_0

    // ---- up to level 0 ----
    upmfma11<64, 32><<<GB1(N1), 256, 0, stream>>>(
        R3, rb0, wt[7], R0, PS(7), AB(8), (int)N1);                       // u0 -> R0
    FINA(7, 18, 64, 32, 10, 32, N0);                                      // bn2_0[u0]
    stencil0<32, 32, 32><<<GB2(N0), 256, 0, stream>>>(
        R1, R0, msk0, wt[8], R3, PS(8), AB(9), AB(10), (int)N0);          // y0 -> R3
    FINA(8, 20, 32, 0, 11, 32, N0);                                       // bnf

    final_k<<<(int)((N0 + 255) / 256), 256, 0, stream>>>(
        R3, AB(11), (const float*)d_in[21], (const float*)d_in[22],
        (float*)d_out, (int)N0);

#undef AB
#undef PS
#undef FINA
#undef GB1
#undef GB2
}

// Round 11
// 616.014 us; speedup vs baseline: 1.1063x; 1.1063x over previous
//
#include <hip/hip_runtime.h>
#include <hip/hip_bf16.h>

// ---------------------------------------------------------------------------
// Sparse 3-level U-Net — Round 27: K-split gather convs (grid x4).
// R26 post-mortem: y1 is GRID-bound (512 blocks = 2/CU = 8 waves/CU max);
// B-direct-from-L2 needs >=4 blocks/CU (stencil0 at N0 proves it); at 2/CU
// the serial B-chain is unhidden -> 77->122us regression. Reverted.
// R27: x1/y1/x2 (K=27) -> gksp: 4 waves each own a K-chunk (7/7/7/6) of the
// SAME 32 rows; barrier-free main loop (A 3-slot distance-2 reg pipeline,
// B direct from L2); epilogue = LDS 4-way tree reduce (fixed order) + store
// + banked-atomic stats. Grid N1/32=2048 = 8 blk/CU. 2 barriers total.
// Rest identical to R25 (566us): stencil0 x0/y0, gmfma10-FACT d0/d1,
// upmfma10 u1/u0, banked stats, FINA.
// Baseline R25: 566.0us (y1/x1 77). Prediction: 460-500us.
// ---------------------------------------------------------------------------

typedef __hip_bfloat16 hbf;
typedef __attribute__((ext_vector_type(8))) short short8;
typedef __attribute__((ext_vector_type(4))) float f32x4;
typedef const __attribute__((address_space(1))) short gas_short;
typedef __attribute__((address_space(3))) short las_short;

__device__ inline float b2f(short s) {
    unsigned u = ((unsigned)(unsigned short)s) << 16;
    float f; __builtin_memcpy(&f, &u, 4); return f;
}
__device__ inline short f2b(float f) {
    hbf h = __float2bfloat16(f);
    short s; __builtin_memcpy(&s, &h, 2); return s;
}

// ---------- weight prep: all 9 layers in one launch ------------------------
struct WPA {
    const float* src[9];
    short* dst[9];
    int CI[9], CO[9];
    int cum[10];
};
__global__ __launch_bounds__(256) void wprep_all(WPA a, int total) {
    int e0 = blockIdx.x * 256 + threadIdx.x;
    if (e0 >= total) return;
    int L = 0;
#pragma unroll
    for (int i = 1; i < 9; i++) L += (e0 >= a.cum[i]) ? 1 : 0;
    int e = e0 - a.cum[L];
    int CI = a.CI[L], CO = a.CO[L];
    int NT = CO >> 4, NCH = CI >> 5;
    int j    = e & 7;
    int lane = (e >> 3) & 63;
    int t    = (e >> 9) % NT;
    int c    = (e / (512 * NT)) % NCH;
    int k    = e / (512 * NT * NCH);
    int ci = c * 32 + (lane >> 4) * 8 + j;
    int co = t * 16 + (lane & 15);
    a.dst[L][e] = f2b(a.src[L][((long long)k * CI + ci) * CO + co]);
}

// ---------- zero the atomic-stats slots ------------------------------------
__global__ void zerok(float* p, int n) {
    int i = blockIdx.x * 256 + threadIdx.x;
    if (i < n) p[i] = 0.f;
}

// ---------- presence mask from nbr0 (27 bits/row) --------------------------
__global__ __launch_bounds__(256) void nbrmask_k(const int* __restrict__ nbr,
                                                 unsigned* __restrict__ msk, int N) {
    long long r = (long long)blockIdx.x * 256 + threadIdx.x;
    if (r >= N) return;
    unsigned mv = 0;
#pragma unroll
    for (int k = 0; k < 27; k++)
        mv |= (nbr[r * 27 + k] >= 0) ? (1u << k) : 0u;
    msk[r] = mv;
}

// ---------- input conv (CIN=3, f32 VALU, bf16 out) -------------------------
__global__ __launch_bounds__(256) void conv_in(
    const float* __restrict__ feat, const int* __restrict__ nbr,
    const float* __restrict__ W, short* __restrict__ out, int N) {
    __shared__ float sW[27 * 96];
    const int tid = threadIdx.x;
    for (int e = tid; e < 27 * 96; e += 256) sW[e] = W[e];
    __syncthreads();
    long long r = (long long)blockIdx.x * 256 + tid;
    if (r >= N) return;
    float acc[32];
#pragma unroll
    for (int c = 0; c < 32; c++) acc[c] = 0.f;
    for (int k = 0; k < 27; k++) {
        int idx = nbr[r * 27 + k];
        if (idx >= 0) {
            float f0 = feat[(long long)idx * 3];
            float f1 = feat[(long long)idx * 3 + 1];
            float f2 = feat[(long long)idx * 3 + 2];
            const float* w = sW + k * 96;
#pragma unroll
            for (int c = 0; c < 32; c++)
                acc[c] += f0 * w[c] + f1 * w[32 + c] + f2 * w[64 + c];
        }
    }
#pragma unroll
    for (int c = 0; c < 32; c++) out[r * 32 + c] = f2b(acc[c]);
}

// ---------- stencil conv for level 0 (dense 512x512 grid) ------------------
template<int CI1, int CI2, int COUT>
__global__ __launch_bounds__(256) void stencil0(
    const short* __restrict__ fA, const short* __restrict__ fB,
    const unsigned* __restrict__ msk, const short* __restrict__ Wf,
    short* __restrict__ out, float* __restrict__ pstat,
    const float* __restrict__ abA, const float* __restrict__ abB, int N) {
    constexpr int CIT  = CI1 + CI2;
    constexpr int NCH  = CIT / 32;
    constexpr int NT   = COUT / 16;
    constexpr int MT   = 2;
    constexpr int CIB  = CIT * 2;
    constexpr int ROWS = 130;
    constexpr int NC8  = CIT / 8;
    constexpr int SWB  = (CIB >= 128) ? 7 : 3;
    __shared__ __attribute__((aligned(16))) char sA[3 * ROWS * CIB];
    const int tid  = threadIdx.x;
    const int lane = tid & 63;
    const int wid  = tid >> 6;
    const int m    = lane & 15;
    const int quad = lane >> 4;
    const int bid  = blockIdx.x;
    const int xq     = bid >> 2;
    const int ystart = (bid & 3) << 7;
    const long long R = (long long)bid * 128;

    {
        const int c8 = tid % NC8;
        const bool isA = (c8 * 8) < CI1;
        const short* src  = isA ? fA : fB;
        const float* abp  = isA ? abA : abB;
        const int   srcCI = isA ? CI1 : CI2;
        const int   chb   = isA ? c8 * 8 : c8 * 8 - CI1;
        float s_[8], b_[8];
#pragma unroll
        for (int jj = 0; jj < 8; jj++) {
            s_[jj] = abp[chb + jj];
            b_[jj] = abp[srcCI + chb + jj];
        }
        for (int e = tid; e < 3 * ROWS * NC8; e += 256) {
            int rr = (e / NC8) % ROWS;
            int st = e / (NC8 * ROWS);
            long long gr = (long long)(xq - 1 + st) * 512 + (ystart - 1 + rr);
            long long grc = (gr < 0 || gr >= N) ? 0 : gr;
            short8 v = *reinterpret_cast<const short8*>(src + grc * srcCI + chb);
            short8 o;
#pragma unroll
            for (int jj = 0; jj < 8; jj++) {
                float f = b2f(v[jj]) * s_[jj] + b_[jj];
                o[jj] = f2b(f > 0.f ? f : 0.f);
            }
            int byte = (st * ROWS + rr) * CIB + c8 * 16;
            byte ^= ((rr & SWB) << 4);
            *reinterpret_cast<short8*>(sA + byte) = o;
        }
    }
    __syncthreads();

    f32x4 acc[MT][NT];
#pragma unroll
    for (int mt = 0; mt < MT; mt++)
#pragma unroll
        for (int t = 0; t < NT; t++) acc[mt][t] = (f32x4)0.f;

    unsigned mv[MT];
#pragma unroll
    for (int mt = 0; mt < MT; mt++) {
        long long r = R + wid * 32 + mt * 16 + m;
        mv[mt] = (r < N) ? msk[r] : 0u;
    }

#pragma unroll
    for (int s9 = 0; s9 < 9; s9++) {
        const int st = s9 / 3;
        const int dy = s9 % 3 - 1;
        short8 a[MT][NCH];
#pragma unroll
        for (int mt = 0; mt < MT; mt++) {
            int rl = 1 + wid * 32 + mt * 16 + m + dy;
#pragma unroll
            for (int c = 0; c < NCH; c++) {
                int byte = (st * ROWS + rl) * CIB + (c * 4 + quad) * 16;
                byte ^= ((rl & SWB) << 4);
                a[mt][c] = *reinterpret_cast<const short8*>(sA + byte);
            }
        }
#pragma unroll
        for (int z3 = 0; z3 < 3; z3++) {
            const int k = s9 * 3 + z3;
            unsigned anyb = (mv[0] >> k) & 1;
            if (MT > 1) anyb |= (mv[1] >> k) & 1;
            if (__any(anyb)) {
                short8 bf[NCH][NT];
#pragma unroll
                for (int c = 0; c < NCH; c++)
#pragma unroll
                    for (int t = 0; t < NT; t++)
                        bf[c][t] = *reinterpret_cast<const short8*>(
                            Wf + ((size_t)(k * NCH + c) * NT + t) * 512 + lane * 8);
#pragma unroll
                for (int mt = 0; mt < MT; mt++) {
                    const bool bb = (mv[mt] >> k) & 1;
                    short8 asel[NCH];
#pragma unroll
                    for (int c = 0; c < NCH; c++)
                        asel[c] = bb ? a[mt][c] : (short8)0;
#pragma unroll
                    for (int c = 0; c < NCH; c++)
#pragma unroll
                        for (int t = 0; t < NT; t++)
                            acc[mt][t] = __builtin_amdgcn_mfma_f32_16x16x32_bf16(
                                asel[c], bf[c][t], acc[mt][t], 0, 0, 0);
                }
            }
        }
    }

    float s[NT], q[NT];
#pragma unroll
    for (int t = 0; t < NT; t++) { s[t] = 0.f; q[t] = 0.f; }
#pragma unroll
    for (int mt = 0; mt < MT; mt++) {
#pragma unroll
        for (int g4 = 0; g4 < 4; g4++) {
            long long sr = R + wid * 32 + mt * 16 + quad * 4 + g4;
            if (sr < N) {
#pragma unroll
                for (int t = 0; t < NT; t++) {
                    float v = acc[mt][t][g4];
                    out[sr * COUT + t * 16 + m] = f2b(v);
                    s[t] += v; q[t] += v * v;
                }
            }
        }
    }
    float* pb = pstat + (blockIdx.x & 7) * 2 * COUT;
#pragma unroll
    for (int t = 0; t < NT; t++) {
        float sv = s[t], qv = q[t];
        sv += __shfl_xor(sv, 16); qv += __shfl_xor(qv, 16);
        sv += __shfl_xor(sv, 32); qv += __shfl_xor(qv, 32);
        if (quad == 0) {
            atomicAdd(&pb[t * 16 + m], sv);
            atomicAdd(&pb[COUT + t * 16 + m], qv);
        }
    }
}

// ---------- K-split gather conv: 4 waves x K-chunks, B direct from L2 ------
// Block = MT*16 rows; wave w computes partial acc over its K-chunk; LDS
// tree-reduce (fixed order) + store + banked stats. 2 barriers total.
template<int CI1, int CI2, int COUT, int K, int MT>
__global__ __launch_bounds__(256) void gksp(
    const short* __restrict__ fA, const short* __restrict__ fB,
    const int* __restrict__ nbr, const short* __restrict__ Wf,
    short* __restrict__ out, float* __restrict__ pstat, int N) {
    constexpr int NT  = COUT / 16;
    constexpr int NC1 = CI1 / 32;
    constexpr int NC2 = CI2 / 32;
    constexpr int NCH = (CI1 + CI2) / 32;
    constexpr int CHK = (K + 3) / 4;            // max chunk length
    constexpr int RPB = MT * 16;                // rows per block
    __shared__ float sR[4][RPB][COUT];
    const int tid  = threadIdx.x;
    const int lane = tid & 63;
    const int wid  = tid >> 6;
    const int m    = lane & 15;
    const int quad = lane >> 4;
    const long long R = (long long)blockIdx.x * RPB;

    const int base = K / 4, rem = K % 4;
    const int clen = base + (wid < rem ? 1 : 0);
    const int k0   = wid * base + (wid < rem ? wid : rem);

    f32x4 acc[MT][NT];
#pragma unroll
    for (int mt = 0; mt < MT; mt++)
#pragma unroll
        for (int t = 0; t < NT; t++) acc[mt][t] = (f32x4)0.f;

    int idxs[MT][CHK];
#pragma unroll
    for (int mt = 0; mt < MT; mt++) {
        long long r = R + mt * 16 + m;
        bool rv = r < N;
#pragma unroll
        for (int kk = 0; kk < CHK; kk++)
            idxs[mt][kk] = (rv && kk < clen) ? nbr[r * K + k0 + kk] : -1;
    }
    unsigned pmask[MT];
#pragma unroll
    for (int mt = 0; mt < MT; mt++) {
        unsigned pm = 0;
#pragma unroll
        for (int kk = 0; kk < CHK; kk++)
            pm |= __any(idxs[mt][kk] >= 0) ? (1u << kk) : 0u;
        pmask[mt] = __builtin_amdgcn_readfirstlane(pm);
    }

    short8 S[3][NCH];   // 3-slot register pipeline (distance-2)

#define LOADS(sl, mt, kk)                                                      \
    {                                                                          \
        int _i = idxs[mt][kk];                                                 \
        long long _j = _i < 0 ? 0 : _i;                                        \
        _Pragma("unroll")                                                      \
        for (int c = 0; c < NC1; c++) {                                        \
            short8 _v = *reinterpret_cast<const short8*>(                      \
                fA + _j * CI1 + c * 32 + quad * 8);                            \
            S[sl][c] = (_i >= 0) ? _v : (short8)0;                             \
        }                                                                      \
        if constexpr (NC2 > 0) {                                               \
            _Pragma("unroll")                                                  \
            for (int c = 0; c < NC2; c++) {                                    \
                short8 _v = *reinterpret_cast<const short8*>(                  \
                    fB + _j * CI2 + c * 32 + quad * 8);                        \
                S[sl][NC1 + c] = (_i >= 0) ? _v : (short8)0;                   \
            }                                                                  \
        }                                                                      \
    }
#define MFMAD(sl, mt, kk)                                                      \
    {                                                                          \
        _Pragma("unroll")                                                      \
        for (int c = 0; c < NCH; c++) {                                        \
            _Pragma("unroll")                                                  \
            for (int t = 0; t < NT; t++) {                                     \
                short8 b = *reinterpret_cast<const short8*>(                   \
                    Wf + ((size_t)((k0 + (kk)) * NCH + c) * NT + t) * 512 +    \
                    lane * 8);                                                 \
                acc[mt][t] = __builtin_amdgcn_mfma_f32_16x16x32_bf16(          \
                    S[sl][c], b, acc[mt][t], 0, 0, 0);                         \
            }                                                                  \
        }                                                                      \
    }

#pragma unroll
    for (int mt = 0; mt < MT; mt++) {
        const unsigned mm = pmask[mt];
        if (mm & 1u) LOADS(0, mt, 0)
        if (CHK > 1 && (mm & 2u)) LOADS(1, mt, 1)
#pragma unroll
        for (int kk = 0; kk < CHK; kk++) {
            if (kk + 2 < CHK)
                if (mm & (1u << (kk + 2))) LOADS((kk + 2) % 3, mt, kk + 2)
            if (mm & (1u << kk)) MFMAD(kk % 3, mt, kk)
        }
    }
#undef LOADS
#undef MFMAD

    // ---- partial acc -> LDS (D layout: col=lane&15, row=quad*4+g4) --------
#pragma unroll
    for (int mt = 0; mt < MT; mt++)
#pragma unroll
        for (int t = 0; t < NT; t++)
#pragma unroll
            for (int g4 = 0; g4 < 4; g4++)
                sR[wid][mt * 16 + quad * 4 + g4][t * 16 + m] = acc[mt][t][g4];
    __syncthreads();

    // ---- 4-way tree reduce (fixed order), store, stash sum ----------------
    constexpr int CH8 = COUT / 8;
    {
        const int row = tid / CH8;
        const int ch0 = (tid % CH8) * 8;
        if (row < RPB) {
            long long sr = R + row;
            float val[8];
#pragma unroll
            for (int j = 0; j < 8; j++)
                val[j] = ((sR[0][row][ch0 + j] + sR[1][row][ch0 + j]) +
                          (sR[2][row][ch0 + j] + sR[3][row][ch0 + j]));
            if (sr < N) {
                short8 o;
#pragma unroll
                for (int j = 0; j < 8; j++) o[j] = f2b(val[j]);
                *reinterpret_cast<short8*>(out + sr * COUT + ch0) = o;
            }
#pragma unroll
            for (int j = 0; j < 8; j++)
                sR[0][row][ch0 + j] = (sr < N) ? val[j] : 0.f;
        }
    }
    __syncthreads();

    // ---- per-channel stats -> banked atomics ------------------------------
    if (tid < COUT) {
        float Sv = 0.f, Qv = 0.f;
#pragma unroll
        for (int row = 0; row < RPB; row++) {
            float v = sR[0][row][tid];
            Sv += v; Qv += v * v;
        }
        float* pb = pstat + (blockIdx.x & 7) * 2 * COUT;
        atomicAdd(&pb[tid], Sv);
        atomicAdd(&pb[COUT + tid], Qv);
    }
}

// ---------- MFMA gather conv v10 (R25, unchanged; used for d0/d1) ----------
template<int CI1, int CI2, int COUT, int K, int G, int MT, bool FACT>
__global__ __launch_bounds__(256) void gmfma10(
    const short* __restrict__ fA, const short* __restrict__ fB,
    const int* __restrict__ nbr, const short* __restrict__ Wf,
    short* __restrict__ out, float* __restrict__ pstat,
    const float* __restrict__ abp, int N) {
    static_assert(K % G == 0, "G must divide K");
    static_assert(!FACT || CI2 == 0, "fused act only for single input");
    constexpr int NT  = COUT / 16;
    constexpr int NC1 = CI1 / 32;
    constexpr int NC2 = CI2 / 32;
    constexpr int NCH = (CI1 + CI2) / 32;
    constexpr int PANEL = NCH * NT * 512;
    constexpr int GSH   = G * PANEL;
    constexpr int NPH   = K / G;
    constexpr int WCH   = GSH / 4;
    constexpr int S16   = (WCH * 2) / 1024;
    constexpr int S4    = ((WCH * 2) % 1024) / 256;
    __shared__ __attribute__((aligned(16))) short sB[GSH];
    const int tid  = threadIdx.x;
    const int lane = tid & 63;
    const int wid  = tid >> 6;
    const int m    = lane & 15;
    const int quad = lane >> 4;
    const long long tb0 = ((long long)blockIdx.x * 4 + wid) * (MT * 16);

    f32x4 acc[MT][NT];
#pragma unroll
    for (int mt = 0; mt < MT; mt++)
#pragma unroll
        for (int t = 0; t < NT; t++) acc[mt][t] = (f32x4)0.f;

#define STAGE(ph)                                                              \
    {                                                                          \
        const short* _src = Wf + (size_t)(ph) * GSH + wid * WCH;               \
        short* _dst = &sB[wid * WCH];                                          \
        _Pragma("unroll")                                                      \
        for (int i = 0; i < S16; i++)                                          \
            __builtin_amdgcn_global_load_lds(                                  \
                (gas_short*)(_src + i * 512 + lane * 8),                       \
                (las_short*)(_dst + i * 512), 16, 0, 0);                       \
        _Pragma("unroll")                                                      \
        for (int i = 0; i < S4; i++)                                           \
            __builtin_amdgcn_global_load_lds(                                  \
                (gas_short*)(_src + S16 * 512 + i * 128 + lane * 2),           \
                (las_short*)(_dst + S16 * 512 + i * 128), 4, 0, 0);            \
    }

    STAGE(0)
    __builtin_amdgcn_sched_barrier(0);

    int idxs[MT][K];
#pragma unroll
    for (int mt = 0; mt < MT; mt++) {
        long long r = tb0 + mt * 16 + m;
        bool rv = r < N;
#pragma unroll
        for (int k = 0; k < K; k++)
            idxs[mt][k] = rv ? nbr[r * K + k] : -1;
    }
    unsigned pmask[MT];
#pragma unroll
    for (int mt = 0; mt < MT; mt++) {
        unsigned pm = 0;
#pragma unroll
        for (int k = 0; k < K; k++)
            pm |= __any(idxs[mt][k] >= 0) ? (1u << k) : 0u;
        pmask[mt] = __builtin_amdgcn_readfirstlane(pm);
    }

    float aS[FACT ? NC1 * 8 : 1], aBb[FACT ? NC1 * 8 : 1];
    if constexpr (FACT) {
#pragma unroll
        for (int c = 0; c < NC1; c++)
#pragma unroll
            for (int jj = 0; jj < 8; jj++) {
                int ch = c * 32 + quad * 8 + jj;
                aS[c * 8 + jj]  = abp[ch];
                aBb[c * 8 + jj] = abp[CI1 + ch];
            }
    }

    __builtin_amdgcn_sched_barrier(0);
    asm volatile("s_waitcnt vmcnt(0)" ::: "memory");
    __builtin_amdgcn_s_barrier();
    __builtin_amdgcn_sched_barrier(0);
    asm volatile("" ::: "memory");

    short8 S[3][NCH];

#define LOADS(sl, mt, kk)                                                      \
    {                                                                          \
        int _i = idxs[mt][kk];                                                 \
        long long _j = _i < 0 ? 0 : _i;                                        \
        _Pragma("unroll")                                                      \
        for (int c = 0; c < NC1; c++) {                                        \
            short8 _v = *reinterpret_cast<const short8*>(                      \
                fA + _j * CI1 + c * 32 + quad * 8);                            \
            if constexpr (FACT) {                                              \
                short8 _o;                                                     \
                _Pragma("unroll")                                              \
                for (int jj = 0; jj < 8; jj++) {                               \
                    float _f = b2f(_v[jj]) * aS[c * 8 + jj] + aBb[c * 8 + jj]; \
                    _o[jj] = f2b(_f > 0.f ? _f : 0.f);                         \
                }                                                              \
                _v = _o;                                                       \
            }                                                                  \
            S[sl][c] = (_i >= 0) ? _v : (short8)0;                             \
        }                                                                      \
        if constexpr (NC2 > 0) {                                               \
            _Pragma("unroll")                                                  \
            for (int c = 0; c < NC2; c++) {                                    \
                short8 _v = *reinterpret_cast<const short8*>(                  \
                    fB + _j * CI2 + c * 32 + quad * 8);                        \
                S[sl][NC1 + c] = (_i >= 0) ? _v : (short8)0;                   \
            }                                                                  \
        }                                                                      \
    }
#define MFMAS(sl, mt, jl)                                                      \
    {                                                                          \
        _Pragma("unroll")                                                      \
        for (int c = 0; c < NCH; c++) {                                        \
            _Pragma("unroll")                                                  \
            for (int t = 0; t < NT; t++) {                                     \
                short8 b = *reinterpret_cast<const short8*>(                   \
                    &sB[((jl) * NCH * NT + c * NT + t) * 512 + lane * 8]);     \
                acc[mt][t] = __builtin_amdgcn_mfma_f32_16x16x32_bf16(          \
                    S[sl][c], b, acc[mt][t], 0, 0, 0);                         \
            }                                                                  \
        }                                                                      \
    }

#pragma unroll
    for (int ph = 0; ph < NPH; ph++) {
#pragma unroll
        for (int mt = 0; mt < MT; mt++) {
            const unsigned mm = (pmask[mt] >> (ph * G)) & ((1u << G) - 1);
#pragma unroll
            for (int j = 0; j < G + 2; j++) {
                if (j < G)
                    if (mm & (1u << j)) LOADS(j % 3, mt, ph * G + j)
                if (j >= 2)
                    if (mm & (1u << (j - 2))) MFMAS((j - 2) % 3, mt, j - 2)
            }
        }
        if (ph + 1 < NPH) {
            __builtin_amdgcn_sched_barrier(0);
            asm volatile("s_waitcnt lgkmcnt(0)" ::: "memory");
            __builtin_amdgcn_s_barrier();
            __builtin_amdgcn_sched_barrier(0);
            STAGE(ph + 1)
            __builtin_amdgcn_sched_barrier(0);
            asm volatile("s_waitcnt vmcnt(0)" ::: "memory");
            __builtin_amdgcn_s_barrier();
            __builtin_amdgcn_sched_barrier(0);
            asm volatile("" ::: "memory");
        }
    }
#undef LOADS
#undef MFMAS
#undef STAGE
    float s[NT], q[NT];
#pragma unroll
    for (int t = 0; t < NT; t++) { s[t] = 0.f; q[t] = 0.f; }
#pragma unroll
    for (int mt = 0; mt < MT; mt++) {
#pragma unroll
        for (int g4 = 0; g4 < 4; g4++) {
            long long sr = tb0 + mt * 16 + quad * 4 + g4;
            if (sr < N) {
#pragma unroll
                for (int t = 0; t < NT; t++) {
                    float v = acc[mt][t][g4];
                    out[sr * COUT + t * 16 + m] = f2b(v);
                    s[t] += v; q[t] += v * v;
                }
            }
        }
    }
    float* pb = pstat + (blockIdx.x & 7) * 2 * COUT;
#pragma unroll
    for (int t = 0; t < NT; t++) {
        float sv = s[t], qv = q[t];
        sv += __shfl_xor(sv, 16); qv += __shfl_xor(qv, 16);
        sv += __shfl_xor(sv, 32); qv += __shfl_xor(qv, 32);
        if (quad == 0) {
            atomicAdd(&pb[t * 16 + m], sv);
            atomicAdd(&pb[COUT + t * 16 + m], qv);
        }
    }
}

// ---------- MFMA up conv v10 (R25, unchanged) ------------------------------
template<int CIN, int COUT, int G>
__global__ __launch_bounds__(256) void upmfma10(
    const short* __restrict__ f, const int* __restrict__ rb,
    const short* __restrict__ Wf, short* __restrict__ out,
    float* __restrict__ pstat, const float* __restrict__ abp, int N) {
    static_assert(8 % G == 0, "G must divide 8");
    constexpr int NT = COUT / 16;
    constexpr int NK = CIN / 32;
    constexpr int PANEL = NK * NT * 512;
    constexpr int GSH   = G * PANEL;
    constexpr int NPH   = 8 / G;
    constexpr int WCH   = GSH / 4;
    constexpr int S16   = (WCH * 2) / 1024;
    constexpr int S4    = ((WCH * 2) % 1024) / 256;
    __shared__ __attribute__((aligned(16))) short sB[GSH];
    const int tid  = threadIdx.x;
    const int lane = tid & 63;
    const int wid  = tid >> 6;
    const int m    = lane & 15;
    const int quad = lane >> 4;
    const long long row0 = ((long long)blockIdx.x * 4 + wid) * 16;
    const long long r = row0 + m;
    const bool rv = r < N;
    const long long rc = rv ? r : 0;

#define STAGE(ph)                                                              \
    {                                                                          \
        const short* _src = Wf + (size_t)(ph) * GSH + wid * WCH;               \
        short* _dst = &sB[wid * WCH];                                          \
        _Pragma("unroll")                                                      \
        for (int i = 0; i < S16; i++)                                          \
            __builtin_amdgcn_global_load_lds(                                  \
                (gas_short*)(_src + i * 512 + lane * 8),                       \
                (las_short*)(_dst + i * 512), 16, 0, 0);                       \
        _Pragma("unroll")                                                      \
        for (int i = 0; i < S4; i++)                                           \
            __builtin_amdgcn_global_load_lds(                                  \
                (gas_short*)(_src + S16 * 512 + i * 128 + lane * 2),           \
                (las_short*)(_dst + S16 * 512 + i * 128), 4, 0, 0);            \
    }
    STAGE(0)
    __builtin_amdgcn_sched_barrier(0);

    short8 af[NK];
#pragma unroll
    for (int kc = 0; kc < NK; kc++) {
        short8 v = *reinterpret_cast<const short8*>(
            f + rc * CIN + kc * 32 + quad * 8);
        short8 o;
#pragma unroll
        for (int jj = 0; jj < 8; jj++) {
            int ch = kc * 32 + quad * 8 + jj;
            float u = b2f(v[jj]) * abp[ch] + abp[CIN + ch];
            o[jj] = f2b(u > 0.f ? u : 0.f);
        }
        af[kc] = rv ? o : (short8)0;
    }
    int sidx[8][4];
#pragma unroll
    for (int g4 = 0; g4 < 4; g4++) {
        long long sr = row0 + quad * 4 + g4;
#pragma unroll
        for (int k = 0; k < 8; k++)
            sidx[k][g4] = (sr < N) ? rb[sr * 8 + k] : -1;
    }
    unsigned pm = 0;
#pragma unroll
    for (int k = 0; k < 8; k++) {
        int anyv = (sidx[k][0] >= 0) | (sidx[k][1] >= 0) |
                   (sidx[k][2] >= 0) | (sidx[k][3] >= 0);
        pm |= __any(anyv) ? (1u << k) : 0u;
    }
    pm = __builtin_amdgcn_readfirstlane(pm);

    float s[NT], q[NT];
#pragma unroll
    for (int t = 0; t < NT; t++) { s[t] = 0.f; q[t] = 0.f; }

    __builtin_amdgcn_sched_barrier(0);
    asm volatile("s_waitcnt vmcnt(0)" ::: "memory");
    __builtin_amdgcn_s_barrier();
    __builtin_amdgcn_sched_barrier(0);
    asm volatile("" ::: "memory");

#pragma unroll
    for (int ph = 0; ph < NPH; ph++) {
#pragma unroll
        for (int j = 0; j < G; j++) {
            const int k = ph * G + j;
            if (pm & (1u << k)) {
                f32x4 acc[NT];
#pragma unroll
                for (int t = 0; t < NT; t++) acc[t] = (f32x4)0.f;
#pragma unroll
                for (int kc = 0; kc < NK; kc++) {
#pragma unroll
                    for (int t = 0; t < NT; t++) {
                        short8 b = *reinterpret_cast<const short8*>(
                            &sB[(j * NK * NT + kc * NT + t) * 512 + lane * 8]);
                        acc[t] = __builtin_amdgcn_mfma_f32_16x16x32_bf16(
                            af[kc], b, acc[t], 0, 0, 0);
                    }
                }
#pragma unroll
                for (int g4 = 0; g4 < 4; g4++) {
                    if (sidx[k][g4] >= 0) {
#pragma unroll
                        for (int t = 0; t < NT; t++) {
                            float v = acc[t][g4];
                            out[(long long)sidx[k][g4] * COUT + t * 16 + m] =
                                f2b(v);
                            s[t] += v; q[t] += v * v;
                        }
                    }
                }
            }
        }
        if (ph + 1 < NPH) {
            __builtin_amdgcn_sched_barrier(0);
            asm volatile("s_waitcnt lgkmcnt(0)" ::: "memory");
            __builtin_amdgcn_s_barrier();
            __builtin_amdgcn_sched_barrier(0);
            STAGE(ph + 1)
            __builtin_amdgcn_sched_barrier(0);
            asm volatile("s_waitcnt vmcnt(0)" ::: "memory");
            __builtin_amdgcn_s_barrier();
            __builtin_amdgcn_sched_barrier(0);
            asm volatile("" ::: "memory");
        }
    }
#undef STAGE
    float* pb = pstat + (blockIdx.x & 7) * 2 * COUT;
#pragma unroll
    for (int t = 0; t < NT; t++) {
        float sv = s[t], qv = q[t];
        sv += __shfl_xor(sv, 16); qv += __shfl_xor(qv, 16);
        sv += __shfl_xor(sv, 32); qv += __shfl_xor(qv, 32);
        if (quad == 0) {
            atomicAdd(&pb[t * 16 + m], sv);
            atomicAdd(&pb[COUT + t * 16 + m], qv);
        }
    }
}

// ---------- BN stats (only for conv_in's output), f64 deterministic --------
template<int C>
__global__ void bn_stats(const short* __restrict__ x, double* __restrict__ part, int N) {
    constexpr int GR  = C / 8;
    constexpr int RPB = 256 / GR;
    constexpr int ACTIVE = GR * RPB;
    __shared__ double ls[256 * 8];
    __shared__ double lq[256 * 8];
    const int tid = threadIdx.x;
    const int g   = tid % GR;
    const int rr  = tid / GR;
    double s[8], q[8];
#pragma unroll
    for (int j = 0; j < 8; j++) { s[j] = 0.0; q[j] = 0.0; }
    if (tid < ACTIVE) {
        for (long long r = (long long)blockIdx.x * RPB + rr; r < N;
             r += (long long)gridDim.x * RPB) {
            short8 v = *reinterpret_cast<const short8*>(x + r * C + g * 8);
#pragma unroll
            for (int j = 0; j < 8; j++) {
                double f = (double)b2f(v[j]);
                s[j] += f; q[j] += f * f;
            }
        }
    }
#pragma unroll
    for (int j = 0; j < 8; j++) { ls[tid * 8 + j] = s[j]; lq[tid * 8 + j] = q[j]; }
    __syncthreads();
    if (tid < C) {
        int gg = tid / 8, jj = tid % 8;
        double S = 0.0, Q = 0.0;
        for (int r2 = 0; r2 < RPB; r2++) {
            S += ls[(r2 * GR + gg) * 8 + jj];
            Q += lq[(r2 * GR + gg) * 8 + jj];
        }
        part[blockIdx.x * 256 + tid]       = S;
        part[blockIdx.x * 256 + 128 + tid] = Q;
    }
}

__global__ void bn_fin(const double* __restrict__ part, const float* __restrict__ gb,
                       int gbfull, int goff, float* __restrict__ ab,
                       int C, int P, double invN) {
    __shared__ double ss[256], sq[256];
    const int tid = threadIdx.x;
    const int c   = tid % C;
    const int g   = tid / C;
    const int G   = 256 / C;
    double s = 0.0, q = 0.0;
    if (g < G) {
        for (int p = g; p < P; p += G) {
            s += part[p * 256 + c];
            q += part[p * 256 + 128 + c];
        }
    }
    ss[tid] = s; sq[tid] = q;
    __syncthreads();
    if (tid < C) {
        for (int j = 1; j < G; j++) { s += ss[j * C + c]; q += sq[j * C + c]; }
        double mu  = s * invN;
        double var = q * invN - mu * mu;
        double a   = (double)gb[goff + c] / sqrt(var + 1e-4);
        ab[c]     = (float)a;
        ab[C + c] = (float)((double)gb[gbfull + goff + c] - mu * a);
    }
}

// ---------- bn_fin_a: reduce 8 atomic banks -> ab --------------------------
__global__ void bn_fin_a(const float* __restrict__ pst, const float* __restrict__ gb,
                         int gbfull, int goff, float* __restrict__ ab,
                         int C, double invN) {
    int c = threadIdx.x;
    if (c >= C) return;
    double s = 0.0, q = 0.0;
#pragma unroll
    for (int b = 0; b < 8; b++) {
        s += (double)pst[b * 2 * C + c];
        q += (double)pst[b * 2 * C + C + c];
    }
    double mu  = s * invN;
    double var = q * invN - mu * mu;
    double a   = (double)gb[goff + c] / sqrt(var + 1e-4);
    ab[c]     = (float)a;
    ab[C + c] = (float)((double)gb[gbfull + goff + c] - mu * a);
}

// ---------- bnact: y = relu(x*a + b), bf16 -> bf16, 8 elems/thread ---------
template<int C>
__global__ void bnact(const short* __restrict__ x, const float* __restrict__ ab,
                      short* __restrict__ y, long long total8) {
    long long i = (long long)blockIdx.x * blockDim.x + threadIdx.x;
    if (i >= total8) return;
    long long base = i * 8;
    int c0 = (int)(base % C);
    short8 v = *reinterpret_cast<const short8*>(x + base);
    short8 o;
#pragma unroll
    for (int j = 0; j < 8; j++) {
        float f = b2f(v[j]) * ab[c0 + j] + ab[C + c0 + j];
        o[j] = f2b(f > 0.f ? f : 0.f);
    }
    *reinterpret_cast<short8*>(y + base) = o;
}

// ---------- bnact2: two tensors in one launch ------------------------------
template<int C>
__global__ void bnact2(const short* __restrict__ xa, const float* __restrict__ aba,
                       short* __restrict__ ya,
                       const short* __restrict__ xb, const float* __restrict__ abb,
                       short* __restrict__ yb, long long n8) {
    long long i = (long long)blockIdx.x * blockDim.x + threadIdx.x;
    if (i >= 2 * n8) return;
    const short* x; const float* ab; short* y; long long ii;
    if (i < n8) { x = xa; ab = aba; y = ya; ii = i; }
    else        { x = xb; ab = abb; y = yb; ii = i - n8; }
    long long base = ii * 8;
    int c0 = (int)(base % C);
    short8 v = *reinterpret_cast<const short8*>(x + base);
    short8 o;
#pragma unroll
    for (int j = 0; j < 8; j++) {
        float f = b2f(v[j]) * ab[c0 + j] + ab[C + c0 + j];
        o[j] = f2b(f > 0.f ? f : 0.f);
    }
    *reinterpret_cast<short8*>(y + base) = o;
}

// ---------- final linear (bnf fused), bf16 in, f32 out ---------------------
__global__ void final_k(const short* __restrict__ x, const float* __restrict__ ab,
                        const float* __restrict__ lw, const float* __restrict__ lb,
                        float* __restrict__ out, int N) {
    long long r = (long long)blockIdx.x * blockDim.x + threadIdx.x;
    if (r >= N) return;
    float a0 = lb[0], a1 = lb[1];
#pragma unroll
    for (int j = 0; j < 4; j++) {
        short8 v = *reinterpret_cast<const short8*>(x + r * 32 + j * 8);
#pragma unroll
        for (int t = 0; t < 8; t++) {
            int ci = 8 * j + t;
            float u = b2f(v[t]) * ab[ci] + ab[32 + ci];
            u = u > 0.f ? u : 0.f;
            a0 += u * lw[ci * 2];
            a1 += u * lw[ci * 2 + 1];
        }
    }
    out[2 * r]     = a0;
    out[2 * r + 1] = a1;
}

extern "C" void kernel_launch(void* const* d_in, const int* in_sizes, int n_in,
                              void* d_out, int out_size, void* d_ws, size_t ws_size,
                              hipStream_t stream) {
    const long long N0 = in_sizes[0] / 3;
    const long long N1 = in_sizes[26] / 8;
    const long long N2 = in_sizes[27] / 8;
    const int P = 256;

    const float* feat = (const float*)d_in[0];
    const int* nbr0 = (const int*)d_in[23];
    const int* nbr1 = (const int*)d_in[24];
    const int* nbr2 = (const int*)d_in[25];
    const int* rb0  = (const int*)d_in[26];
    const int* rb1  = (const int*)d_in[27];

    // ---- arena ----
    char* p = (char*)d_ws;
    double* part = (double*)p;            p += (size_t)P * 256 * 8;     // 512 KB
    float*  ab   = (float*)p;             p += 12 * 256 * 4;
    float*  pst  = (float*)p;             p += (size_t)10 * 2048 * 4;
    unsigned* msk0 = (unsigned*)p;        p += ((size_t)N0 * 4 + 63) & ~(size_t)63;
    const int wLayer[9] = {3, 5, 7, 9, 11, 13, 15, 17, 19};
    const int wK[9]  = {27, 8, 27, 8, 27, 8, 27, 8, 27};
    const int wCI[9] = {32, 32, 64, 64, 96, 96, 128, 64, 64};
    const int wCO[9] = {32, 64, 64, 96, 96, 64, 64, 32, 32};
    short* wt[9];
    WPA wpa;
    int cum = 0;
    for (int i = 0; i < 9; i++) {
        wt[i] = (short*)p;
        int n = wK[i] * wCI[i] * wCO[i];
        p += (((size_t)n * 2 + 63) & ~(size_t)63);
        wpa.src[i] = (const float*)d_in[wLayer[i]];
        wpa.dst[i] = wt[i];
        wpa.CI[i] = wCI[i]; wpa.CO[i] = wCO[i];
        wpa.cum[i] = cum; cum += n;
    }
    wpa.cum[9] = cum;
    auto balloc = [&](long long elems) {
        short* q = (short*)p;
        p += (((size_t)elems * 2 + 63) & ~(size_t)63);
        return q;
    };
    short* R0 = balloc(N0 * 32);   // t0 / d0 / d1 / u1 / u0 (raw)
    short* R1 = balloc(N0 * 32);   // x0 raw (persist)
    short* R2 = balloc(N1 * 64);   // x1 raw (persist)
    short* R3 = balloc(N0 * 32);   // x2 / y1 / y0 (raw)
    short* Xb = balloc(N0 * 32);   // act out #1
    short* Yb = balloc(N0 * 32);   // act out #2

    wprep_all<<<(cum + 255) / 256, 256, 0, stream>>>(wpa, cum);
    zerok<<<(10 * 2048 + 255) / 256, 256, 0, stream>>>(pst, 10 * 2048);
    nbrmask_k<<<(int)((N0 + 255) / 256), 256, 0, stream>>>(nbr0, msk0, (int)N0);

#define AB(SL) (ab + (SL) * 256)
#define PS(SL) (pst + (SL) * 2048)
#define FINA(PSL, GBI, GBFULL, GOFF, SL, CH, NN)                                     \
    bn_fin_a<<<1, 128, 0, stream>>>(PS(PSL), (const float*)d_in[GBI], GBFULL, GOFF,  \
                                    AB(SL), CH, 1.0 / (double)(NN))
#define GB1(N_) (int)(((N_) + 63) / 64)
#define GB2(N_) (int)(((N_) + 127) / 128)
#define GK2(N_) (int)(((N_) + 31) / 32)       // ksplit MT=2 blocks (32 rows)
#define GK1(N_) (int)(((N_) + 15) / 16)       // ksplit MT=1 blocks (16 rows)

    // ---- level 0 ----
    conv_in<<<(int)((N0 + 255) / 256), 256, 0, stream>>>(
        feat, nbr0, (const float*)d_in[1], R0, (int)N0);                  // t0 -> R0
    bn_stats<32><<<P, 256, 0, stream>>>(R0, part, (int)N0);               // bn1_0
    bn_fin<<<1, 256, 0, stream>>>(part, (const float*)d_in[2], 32, 0,
                                  AB(0), 32, P, 1.0 / (double)N0);
    stencil0<32, 0, 32><<<GB2(N0), 256, 0, stream>>>(
        R0, nullptr, msk0, wt[0], R1, PS(0), AB(0), nullptr, (int)N0);    // x0 -> R1
    FINA(0, 4, 32, 0, 1, 32, N0);                                         // bnd_0
    FINA(0, 18, 64, 0, 9, 32, N0);                                        // bn2_0[x0]
    gmfma10<32, 0, 64, 8, 8, 2, true><<<GB2(N1), 256, 0, stream>>>(
        R1, nullptr, rb0, wt[1], R0, PS(1), AB(1), (int)N1);              // d0 -> R0
    FINA(1, 6, 64, 0, 2, 64, N1);                                         // bn1_1

    // ---- level 1 ----
    bnact<64><<<(int)((N1 * 64 / 8 + 255) / 256), 256, 0, stream>>>(
        R0, AB(2), Xb, N1 * 64 / 8);
    gksp<64, 0, 64, 27, 2><<<GK2(N1), 256, 0, stream>>>(
        Xb, nullptr, nbr1, wt[2], R2, PS(2), (int)N1);                    // x1 -> R2
    FINA(2, 8, 64, 0, 3, 64, N1);                                         // bnd_1
    FINA(2, 14, 128, 0, 6, 64, N1);                                       // bn2_1[x1]
    gmfma10<64, 0, 96, 8, 2, 1, true><<<GB1(N2), 256, 0, stream>>>(
        R2, nullptr, rb1, wt[3], R0, PS(3), AB(3), (int)N2);              // d1 -> R0
    FINA(3, 10, 96, 0, 4, 96, N2);                                        // bn1_2

    // ---- level 2 ----
    bnact<96><<<(int)((N2 * 96 / 8 + 255) / 256), 256, 0, stream>>>(
        R0, AB(4), Xb, N2 * 96 / 8);
    gksp<96, 0, 96, 27, 1><<<GK1(N2), 256, 0, stream>>>(
        Xb, nullptr, nbr2, wt[4], R3, PS(4), (int)N2);                    // x2 -> R3
    FINA(4, 12, 96, 0, 5, 96, N2);                                        // bnu_1

    // ---- up to level 1 ----
    upmfma10<96, 64, 2><<<GB1(N2), 256, 0, stream>>>(
        R3, rb1, wt[5], R0, PS(5), AB(5), (int)N2);                       // u1 -> R0
    FINA(5, 14, 128, 64, 7, 64, N1);                                      // bn2_1[u1]
    bnact2<64><<<(int)((2 * (N1 * 64 / 8) + 255) / 256), 256, 0, stream>>>(
        R2, AB(6), Xb, R0, AB(7), Yb, N1 * 64 / 8);
    gksp<64, 64, 64, 27, 2><<<GK2(N1), 256, 0, stream>>>(
        Xb, Yb, nbr1, wt[6], R3, PS(6), (int)N1);                         // y1 -> R3
    FINA(6, 16, 64, 0, 8, 64, N1);                                        // bnu_0

    // ---- up to level 0 ----
    upmfma10<64, 32, 4><<<GB1(N1), 256, 0, stream>>>(
        R3, rb0, wt[7], R0, PS(7), AB(8), (int)N1);                       // u0 -> R0
    FINA(7, 18, 64, 32, 10, 32, N0);                                      // bn2_0[u0]
    stencil0<32, 32, 32><<<GB2(N0), 256, 0, stream>>>(
        R1, R0, msk0, wt[8], R3, PS(8), AB(9), AB(10), (int)N0);          // y0 -> R3
    FINA(8, 20, 32, 0, 11, 32, N0);                                       // bnf

    final_k<<<(int)((N0 + 255) / 256), 256, 0, stream>>>(
        R3, AB(11), (const float*)d_in[21], (const float*)d_in[22],
        (float*)d_out, (int)N0);

#undef AB
#undef PS
#undef FINA
#undef GB1
#undef GB2
#undef GK2
#undef GK1
}

// Round 12
// 594.502 us; speedup vs baseline: 1.1463x; 1.0362x over previous
//
#include <hip/hip_runtime.h>
#include <hip/hip_bf16.h>

// ---------------------------------------------------------------------------
// Sparse 3-level U-Net — Round 28: R25 config + act-at-gather for x1/x2/y1.
// R27 post-mortem: gksp (K-split, B-direct) 112us > gmfma10 77us even at 31%
// occupancy -> B-direct refuted for gather convs; gmfma10 staged structure is
// the local optimum (6 variants, 77-122us). Reverted to R25 (566us measured).
// R28 addition: extend proven FACT (act fused into gather load, d0/d1) to
// BOTH inputs (FA/FB); apply to x1, x2, y1 -> drop bnact<64>, bnact<96>,
// bnact2<64> (3 launches + ~90MB traffic). VALU 10% -> 27x recompute free.
// Baseline R25: 566.0us. Prediction: 530-545us, conv times flat.
// ---------------------------------------------------------------------------

typedef __hip_bfloat16 hbf;
typedef __attribute__((ext_vector_type(8))) short short8;
typedef __attribute__((ext_vector_type(4))) float f32x4;
typedef const __attribute__((address_space(1))) short gas_short;
typedef __attribute__((address_space(3))) short las_short;

__device__ inline float b2f(short s) {
    unsigned u = ((unsigned)(unsigned short)s) << 16;
    float f; __builtin_memcpy(&f, &u, 4); return f;
}
__device__ inline short f2b(float f) {
    hbf h = __float2bfloat16(f);
    short s; __builtin_memcpy(&s, &h, 2); return s;
}

// ---------- weight prep: all 9 layers in one launch ------------------------
struct WPA {
    const float* src[9];
    short* dst[9];
    int CI[9], CO[9];
    int cum[10];
};
__global__ __launch_bounds__(256) void wprep_all(WPA a, int total) {
    int e0 = blockIdx.x * 256 + threadIdx.x;
    if (e0 >= total) return;
    int L = 0;
#pragma unroll
    for (int i = 1; i < 9; i++) L += (e0 >= a.cum[i]) ? 1 : 0;
    int e = e0 - a.cum[L];
    int CI = a.CI[L], CO = a.CO[L];
    int NT = CO >> 4, NCH = CI >> 5;
    int j    = e & 7;
    int lane = (e >> 3) & 63;
    int t    = (e >> 9) % NT;
    int c    = (e / (512 * NT)) % NCH;
    int k    = e / (512 * NT * NCH);
    int ci = c * 32 + (lane >> 4) * 8 + j;
    int co = t * 16 + (lane & 15);
    a.dst[L][e] = f2b(a.src[L][((long long)k * CI + ci) * CO + co]);
}

// ---------- zero the atomic-stats slots ------------------------------------
__global__ void zerok(float* p, int n) {
    int i = blockIdx.x * 256 + threadIdx.x;
    if (i < n) p[i] = 0.f;
}

// ---------- presence mask from nbr0 (27 bits/row) --------------------------
__global__ __launch_bounds__(256) void nbrmask_k(const int* __restrict__ nbr,
                                                 unsigned* __restrict__ msk, int N) {
    long long r = (long long)blockIdx.x * 256 + threadIdx.x;
    if (r >= N) return;
    unsigned mv = 0;
#pragma unroll
    for (int k = 0; k < 27; k++)
        mv |= (nbr[r * 27 + k] >= 0) ? (1u << k) : 0u;
    msk[r] = mv;
}

// ---------- input conv (CIN=3, f32 VALU, bf16 out) -------------------------
__global__ __launch_bounds__(256) void conv_in(
    const float* __restrict__ feat, const int* __restrict__ nbr,
    const float* __restrict__ W, short* __restrict__ out, int N) {
    __shared__ float sW[27 * 96];
    const int tid = threadIdx.x;
    for (int e = tid; e < 27 * 96; e += 256) sW[e] = W[e];
    __syncthreads();
    long long r = (long long)blockIdx.x * 256 + tid;
    if (r >= N) return;
    float acc[32];
#pragma unroll
    for (int c = 0; c < 32; c++) acc[c] = 0.f;
    for (int k = 0; k < 27; k++) {
        int idx = nbr[r * 27 + k];
        if (idx >= 0) {
            float f0 = feat[(long long)idx * 3];
            float f1 = feat[(long long)idx * 3 + 1];
            float f2 = feat[(long long)idx * 3 + 2];
            const float* w = sW + k * 96;
#pragma unroll
            for (int c = 0; c < 32; c++)
                acc[c] += f0 * w[c] + f1 * w[32 + c] + f2 * w[64 + c];
        }
    }
#pragma unroll
    for (int c = 0; c < 32; c++) out[r * 32 + c] = f2b(acc[c]);
}

// ---------- stencil conv for level 0 (dense 512x512 grid) ------------------
template<int CI1, int CI2, int COUT>
__global__ __launch_bounds__(256) void stencil0(
    const short* __restrict__ fA, const short* __restrict__ fB,
    const unsigned* __restrict__ msk, const short* __restrict__ Wf,
    short* __restrict__ out, float* __restrict__ pstat,
    const float* __restrict__ abA, const float* __restrict__ abB, int N) {
    constexpr int CIT  = CI1 + CI2;
    constexpr int NCH  = CIT / 32;
    constexpr int NT   = COUT / 16;
    constexpr int MT   = 2;
    constexpr int CIB  = CIT * 2;
    constexpr int ROWS = 130;
    constexpr int NC8  = CIT / 8;
    constexpr int SWB  = (CIB >= 128) ? 7 : 3;
    __shared__ __attribute__((aligned(16))) char sA[3 * ROWS * CIB];
    const int tid  = threadIdx.x;
    const int lane = tid & 63;
    const int wid  = tid >> 6;
    const int m    = lane & 15;
    const int quad = lane >> 4;
    const int bid  = blockIdx.x;
    const int xq     = bid >> 2;
    const int ystart = (bid & 3) << 7;
    const long long R = (long long)bid * 128;

    {
        const int c8 = tid % NC8;
        const bool isA = (c8 * 8) < CI1;
        const short* src  = isA ? fA : fB;
        const float* abp  = isA ? abA : abB;
        const int   srcCI = isA ? CI1 : CI2;
        const int   chb   = isA ? c8 * 8 : c8 * 8 - CI1;
        float s_[8], b_[8];
#pragma unroll
        for (int jj = 0; jj < 8; jj++) {
            s_[jj] = abp[chb + jj];
            b_[jj] = abp[srcCI + chb + jj];
        }
        for (int e = tid; e < 3 * ROWS * NC8; e += 256) {
            int rr = (e / NC8) % ROWS;
            int st = e / (NC8 * ROWS);
            long long gr = (long long)(xq - 1 + st) * 512 + (ystart - 1 + rr);
            long long grc = (gr < 0 || gr >= N) ? 0 : gr;
            short8 v = *reinterpret_cast<const short8*>(src + grc * srcCI + chb);
            short8 o;
#pragma unroll
            for (int jj = 0; jj < 8; jj++) {
                float f = b2f(v[jj]) * s_[jj] + b_[jj];
                o[jj] = f2b(f > 0.f ? f : 0.f);
            }
            int byte = (st * ROWS + rr) * CIB + c8 * 16;
            byte ^= ((rr & SWB) << 4);
            *reinterpret_cast<short8*>(sA + byte) = o;
        }
    }
    __syncthreads();

    f32x4 acc[MT][NT];
#pragma unroll
    for (int mt = 0; mt < MT; mt++)
#pragma unroll
        for (int t = 0; t < NT; t++) acc[mt][t] = (f32x4)0.f;

    unsigned mv[MT];
#pragma unroll
    for (int mt = 0; mt < MT; mt++) {
        long long r = R + wid * 32 + mt * 16 + m;
        mv[mt] = (r < N) ? msk[r] : 0u;
    }

#pragma unroll
    for (int s9 = 0; s9 < 9; s9++) {
        const int st = s9 / 3;
        const int dy = s9 % 3 - 1;
        short8 a[MT][NCH];
#pragma unroll
        for (int mt = 0; mt < MT; mt++) {
            int rl = 1 + wid * 32 + mt * 16 + m + dy;
#pragma unroll
            for (int c = 0; c < NCH; c++) {
                int byte = (st * ROWS + rl) * CIB + (c * 4 + quad) * 16;
                byte ^= ((rl & SWB) << 4);
                a[mt][c] = *reinterpret_cast<const short8*>(sA + byte);
            }
        }
#pragma unroll
        for (int z3 = 0; z3 < 3; z3++) {
            const int k = s9 * 3 + z3;
            unsigned anyb = (mv[0] >> k) & 1;
            if (MT > 1) anyb |= (mv[1] >> k) & 1;
            if (__any(anyb)) {
                short8 bf[NCH][NT];
#pragma unroll
                for (int c = 0; c < NCH; c++)
#pragma unroll
                    for (int t = 0; t < NT; t++)
                        bf[c][t] = *reinterpret_cast<const short8*>(
                            Wf + ((size_t)(k * NCH + c) * NT + t) * 512 + lane * 8);
#pragma unroll
                for (int mt = 0; mt < MT; mt++) {
                    const bool bb = (mv[mt] >> k) & 1;
                    short8 asel[NCH];
#pragma unroll
                    for (int c = 0; c < NCH; c++)
                        asel[c] = bb ? a[mt][c] : (short8)0;
#pragma unroll
                    for (int c = 0; c < NCH; c++)
#pragma unroll
                        for (int t = 0; t < NT; t++)
                            acc[mt][t] = __builtin_amdgcn_mfma_f32_16x16x32_bf16(
                                asel[c], bf[c][t], acc[mt][t], 0, 0, 0);
                }
            }
        }
    }

    float s[NT], q[NT];
#pragma unroll
    for (int t = 0; t < NT; t++) { s[t] = 0.f; q[t] = 0.f; }
#pragma unroll
    for (int mt = 0; mt < MT; mt++) {
#pragma unroll
        for (int g4 = 0; g4 < 4; g4++) {
            long long sr = R + wid * 32 + mt * 16 + quad * 4 + g4;
            if (sr < N) {
#pragma unroll
                for (int t = 0; t < NT; t++) {
                    float v = acc[mt][t][g4];
                    out[sr * COUT + t * 16 + m] = f2b(v);
                    s[t] += v; q[t] += v * v;
                }
            }
        }
    }
    float* pb = pstat + (blockIdx.x & 7) * 2 * COUT;
#pragma unroll
    for (int t = 0; t < NT; t++) {
        float sv = s[t], qv = q[t];
        sv += __shfl_xor(sv, 16); qv += __shfl_xor(qv, 16);
        sv += __shfl_xor(sv, 32); qv += __shfl_xor(qv, 32);
        if (quad == 0) {
            atomicAdd(&pb[t * 16 + m], sv);
            atomicAdd(&pb[COUT + t * 16 + m], qv);
        }
    }
}

// ---------- MFMA gather conv v12: R25 structure + dual fused act -----------
template<int CI1, int CI2, int COUT, int K, int G, int MT, bool FA, bool FB>
__global__ __launch_bounds__(256) void gmfma12(
    const short* __restrict__ fA, const short* __restrict__ fB,
    const int* __restrict__ nbr, const short* __restrict__ Wf,
    short* __restrict__ out, float* __restrict__ pstat,
    const float* __restrict__ abpA, const float* __restrict__ abpB, int N) {
    static_assert(K % G == 0, "G must divide K");
    constexpr int NT  = COUT / 16;
    constexpr int NC1 = CI1 / 32;
    constexpr int NC2 = CI2 / 32;
    constexpr int NCH = (CI1 + CI2) / 32;
    constexpr int PANEL = NCH * NT * 512;
    constexpr int GSH   = G * PANEL;
    constexpr int NPH   = K / G;
    constexpr int WCH   = GSH / 4;
    constexpr int S16   = (WCH * 2) / 1024;
    constexpr int S4    = ((WCH * 2) % 1024) / 256;
    __shared__ __attribute__((aligned(16))) short sB[GSH];
    const int tid  = threadIdx.x;
    const int lane = tid & 63;
    const int wid  = tid >> 6;
    const int m    = lane & 15;
    const int quad = lane >> 4;
    const long long tb0 = ((long long)blockIdx.x * 4 + wid) * (MT * 16);

    f32x4 acc[MT][NT];
#pragma unroll
    for (int mt = 0; mt < MT; mt++)
#pragma unroll
        for (int t = 0; t < NT; t++) acc[mt][t] = (f32x4)0.f;

#define STAGE(ph)                                                              \
    {                                                                          \
        const short* _src = Wf + (size_t)(ph) * GSH + wid * WCH;               \
        short* _dst = &sB[wid * WCH];                                          \
        _Pragma("unroll")                                                      \
        for (int i = 0; i < S16; i++)                                          \
            __builtin_amdgcn_global_load_lds(                                  \
                (gas_short*)(_src + i * 512 + lane * 8),                       \
                (las_short*)(_dst + i * 512), 16, 0, 0);                       \
        _Pragma("unroll")                                                      \
        for (int i = 0; i < S4; i++)                                           \
            __builtin_amdgcn_global_load_lds(                                  \
                (gas_short*)(_src + S16 * 512 + i * 128 + lane * 2),           \
                (las_short*)(_dst + S16 * 512 + i * 128), 4, 0, 0);            \
    }

    STAGE(0)
    __builtin_amdgcn_sched_barrier(0);

    int idxs[MT][K];
#pragma unroll
    for (int mt = 0; mt < MT; mt++) {
        long long r = tb0 + mt * 16 + m;
        bool rv = r < N;
#pragma unroll
        for (int k = 0; k < K; k++)
            idxs[mt][k] = rv ? nbr[r * K + k] : -1;
    }
    unsigned pmask[MT];
#pragma unroll
    for (int mt = 0; mt < MT; mt++) {
        unsigned pm = 0;
#pragma unroll
        for (int k = 0; k < K; k++)
            pm |= __any(idxs[mt][k] >= 0) ? (1u << k) : 0u;
        pmask[mt] = __builtin_amdgcn_readfirstlane(pm);
    }

    float aS1[FA ? NC1 * 8 : 1], aB1[FA ? NC1 * 8 : 1];
    if constexpr (FA) {
#pragma unroll
        for (int c = 0; c < NC1; c++)
#pragma unroll
            for (int jj = 0; jj < 8; jj++) {
                int ch = c * 32 + quad * 8 + jj;
                aS1[c * 8 + jj] = abpA[ch];
                aB1[c * 8 + jj] = abpA[CI1 + ch];
            }
    }
    float aS2[(FB && NC2 > 0) ? NC2 * 8 : 1], aB2[(FB && NC2 > 0) ? NC2 * 8 : 1];
    if constexpr (FB && NC2 > 0) {
#pragma unroll
        for (int c = 0; c < NC2; c++)
#pragma unroll
            for (int jj = 0; jj < 8; jj++) {
                int ch = c * 32 + quad * 8 + jj;
                aS2[c * 8 + jj] = abpB[ch];
                aB2[c * 8 + jj] = abpB[CI2 + ch];
            }
    }

    __builtin_amdgcn_sched_barrier(0);
    asm volatile("s_waitcnt vmcnt(0)" ::: "memory");
    __builtin_amdgcn_s_barrier();
    __builtin_amdgcn_sched_barrier(0);
    asm volatile("" ::: "memory");

    short8 S[3][NCH];

#define LOADS(sl, mt, kk)                                                      \
    {                                                                          \
        int _i = idxs[mt][kk];                                                 \
        long long _j = _i < 0 ? 0 : _i;                                        \
        _Pragma("unroll")                                                      \
        for (int c = 0; c < NC1; c++) {                                        \
            short8 _v = *reinterpret_cast<const short8*>(                      \
                fA + _j * CI1 + c * 32 + quad * 8);                            \
            if constexpr (FA) {                                                \
                short8 _o;                                                     \
                _Pragma("unroll")                                              \
                for (int jj = 0; jj < 8; jj++) {                               \
                    float _f = b2f(_v[jj]) * aS1[c * 8 + jj] + aB1[c * 8 + jj];\
                    _o[jj] = f2b(_f > 0.f ? _f : 0.f);                         \
                }                                                              \
                _v = _o;                                                       \
            }                                                                  \
            S[sl][c] = (_i >= 0) ? _v : (short8)0;                             \
        }                                                                      \
        if constexpr (NC2 > 0) {                                               \
            _Pragma("unroll")                                                  \
            for (int c = 0; c < NC2; c++) {                                    \
                short8 _v = *reinterpret_cast<const short8*>(                  \
                    fB + _j * CI2 + c * 32 + quad * 8);                        \
                if constexpr (FB) {                                            \
                    short8 _o;                                                 \
                    _Pragma("unroll")                                          \
                    for (int jj = 0; jj < 8; jj++) {                           \
                        float _f = b2f(_v[jj]) * aS2[c * 8 + jj] +             \
                                   aB2[c * 8 + jj];                            \
                        _o[jj] = f2b(_f > 0.f ? _f : 0.f);                     \
                    }                                                          \
                    _v = _o;                                                   \
                }                                                              \
                S[sl][NC1 + c] = (_i >= 0) ? _v : (short8)0;                   \
            }                                                                  \
        }                                                                      \
    }
#define MFMAS(sl, mt, jl)                                                      \
    {                                                                          \
        _Pragma("unroll")                                                      \
        for (int c = 0; c < NCH; c++) {                                        \
            _Pragma("unroll")                                                  \
            for (int t = 0; t < NT; t++) {                                     \
                short8 b = *reinterpret_cast<const short8*>(                   \
                    &sB[((jl) * NCH * NT + c * NT + t) * 512 + lane * 8]);     \
                acc[mt][t] = __builtin_amdgcn_mfma_f32_16x16x32_bf16(          \
                    S[sl][c], b, acc[mt][t], 0, 0, 0);                         \
            }                                                                  \
        }                                                                      \
    }

#pragma unroll
    for (int ph = 0; ph < NPH; ph++) {
#pragma unroll
        for (int mt = 0; mt < MT; mt++) {
            const unsigned mm = (pmask[mt] >> (ph * G)) & ((1u << G) - 1);
#pragma unroll
            for (int j = 0; j < G + 2; j++) {
                if (j < G)
                    if (mm & (1u << j)) LOADS(j % 3, mt, ph * G + j)
                if (j >= 2)
                    if (mm & (1u << (j - 2))) MFMAS((j - 2) % 3, mt, j - 2)
            }
        }
        if (ph + 1 < NPH) {
            __builtin_amdgcn_sched_barrier(0);
            asm volatile("s_waitcnt lgkmcnt(0)" ::: "memory");
            __builtin_amdgcn_s_barrier();
            __builtin_amdgcn_sched_barrier(0);
            STAGE(ph + 1)
            __builtin_amdgcn_sched_barrier(0);
            asm volatile("s_waitcnt vmcnt(0)" ::: "memory");
            __builtin_amdgcn_s_barrier();
            __builtin_amdgcn_sched_barrier(0);
            asm volatile("" ::: "memory");
        }
    }
#undef LOADS
#undef MFMAS
#undef STAGE
    float s[NT], q[NT];
#pragma unroll
    for (int t = 0; t < NT; t++) { s[t] = 0.f; q[t] = 0.f; }
#pragma unroll
    for (int mt = 0; mt < MT; mt++) {
#pragma unroll
        for (int g4 = 0; g4 < 4; g4++) {
            long long sr = tb0 + mt * 16 + quad * 4 + g4;
            if (sr < N) {
#pragma unroll
                for (int t = 0; t < NT; t++) {
                    float v = acc[mt][t][g4];
                    out[sr * COUT + t * 16 + m] = f2b(v);
                    s[t] += v; q[t] += v * v;
                }
            }
        }
    }
    float* pb = pstat + (blockIdx.x & 7) * 2 * COUT;
#pragma unroll
    for (int t = 0; t < NT; t++) {
        float sv = s[t], qv = q[t];
        sv += __shfl_xor(sv, 16); qv += __shfl_xor(qv, 16);
        sv += __shfl_xor(sv, 32); qv += __shfl_xor(qv, 32);
        if (quad == 0) {
            atomicAdd(&pb[t * 16 + m], sv);
            atomicAdd(&pb[COUT + t * 16 + m], qv);
        }
    }
}

// ---------- MFMA up conv v10 (R25, unchanged) ------------------------------
template<int CIN, int COUT, int G>
__global__ __launch_bounds__(256) void upmfma10(
    const short* __restrict__ f, const int* __restrict__ rb,
    const short* __restrict__ Wf, short* __restrict__ out,
    float* __restrict__ pstat, const float* __restrict__ abp, int N) {
    static_assert(8 % G == 0, "G must divide 8");
    constexpr int NT = COUT / 16;
    constexpr int NK = CIN / 32;
    constexpr int PANEL = NK * NT * 512;
    constexpr int GSH   = G * PANEL;
    constexpr int NPH   = 8 / G;
    constexpr int WCH   = GSH / 4;
    constexpr int S16   = (WCH * 2) / 1024;
    constexpr int S4    = ((WCH * 2) % 1024) / 256;
    __shared__ __attribute__((aligned(16))) short sB[GSH];
    const int tid  = threadIdx.x;
    const int lane = tid & 63;
    const int wid  = tid >> 6;
    const int m    = lane & 15;
    const int quad = lane >> 4;
    const long long row0 = ((long long)blockIdx.x * 4 + wid) * 16;
    const long long r = row0 + m;
    const bool rv = r < N;
    const long long rc = rv ? r : 0;

#define STAGE(ph)                                                              \
    {                                                                          \
        const short* _src = Wf + (size_t)(ph) * GSH + wid * WCH;               \
        short* _dst = &sB[wid * WCH];                                          \
        _Pragma("unroll")                                                      \
        for (int i = 0; i < S16; i++)                                          \
            __builtin_amdgcn_global_load_lds(                                  \
                (gas_short*)(_src + i * 512 + lane * 8),                       \
                (las_short*)(_dst + i * 512), 16, 0, 0);                       \
        _Pragma("unroll")                                                      \
        for (int i = 0; i < S4; i++)                                           \
            __builtin_amdgcn_global_load_lds(                                  \
                (gas_short*)(_src + S16 * 512 + i * 128 + lane * 2),           \
                (las_short*)(_dst + S16 * 512 + i * 128), 4, 0, 0);            \
    }
    STAGE(0)
    __builtin_amdgcn_sched_barrier(0);

    short8 af[NK];
#pragma unroll
    for (int kc = 0; kc < NK; kc++) {
        short8 v = *reinterpret_cast<const short8*>(
            f + rc * CIN + kc * 32 + quad * 8);
        short8 o;
#pragma unroll
        for (int jj = 0; jj < 8; jj++) {
            int ch = kc * 32 + quad * 8 + jj;
            float u = b2f(v[jj]) * abp[ch] + abp[CIN + ch];
            o[jj] = f2b(u > 0.f ? u : 0.f);
        }
        af[kc] = rv ? o : (short8)0;
    }
    int sidx[8][4];
#pragma unroll
    for (int g4 = 0; g4 < 4; g4++) {
        long long sr = row0 + quad * 4 + g4;
#pragma unroll
        for (int k = 0; k < 8; k++)
            sidx[k][g4] = (sr < N) ? rb[sr * 8 + k] : -1;
    }
    unsigned pm = 0;
#pragma unroll
    for (int k = 0; k < 8; k++) {
        int anyv = (sidx[k][0] >= 0) | (sidx[k][1] >= 0) |
                   (sidx[k][2] >= 0) | (sidx[k][3] >= 0);
        pm |= __any(anyv) ? (1u << k) : 0u;
    }
    pm = __builtin_amdgcn_readfirstlane(pm);

    float s[NT], q[NT];
#pragma unroll
    for (int t = 0; t < NT; t++) { s[t] = 0.f; q[t] = 0.f; }

    __builtin_amdgcn_sched_barrier(0);
    asm volatile("s_waitcnt vmcnt(0)" ::: "memory");
    __builtin_amdgcn_s_barrier();
    __builtin_amdgcn_sched_barrier(0);
    asm volatile("" ::: "memory");

#pragma unroll
    for (int ph = 0; ph < NPH; ph++) {
#pragma unroll
        for (int j = 0; j < G; j++) {
            const int k = ph * G + j;
            if (pm & (1u << k)) {
                f32x4 acc[NT];
#pragma unroll
                for (int t = 0; t < NT; t++) acc[t] = (f32x4)0.f;
#pragma unroll
                for (int kc = 0; kc < NK; kc++) {
#pragma unroll
                    for (int t = 0; t < NT; t++) {
                        short8 b = *reinterpret_cast<const short8*>(
                            &sB[(j * NK * NT + kc * NT + t) * 512 + lane * 8]);
                        acc[t] = __builtin_amdgcn_mfma_f32_16x16x32_bf16(
                            af[kc], b, acc[t], 0, 0, 0);
                    }
                }
#pragma unroll
                for (int g4 = 0; g4 < 4; g4++) {
                    if (sidx[k][g4] >= 0) {
#pragma unroll
                        for (int t = 0; t < NT; t++) {
                            float v = acc[t][g4];
                            out[(long long)sidx[k][g4] * COUT + t * 16 + m] =
                                f2b(v);
                            s[t] += v; q[t] += v * v;
                        }
                    }
                }
            }
        }
        if (ph + 1 < NPH) {
            __builtin_amdgcn_sched_barrier(0);
            asm volatile("s_waitcnt lgkmcnt(0)" ::: "memory");
            __builtin_amdgcn_s_barrier();
            __builtin_amdgcn_sched_barrier(0);
            STAGE(ph + 1)
            __builtin_amdgcn_sched_barrier(0);
            asm volatile("s_waitcnt vmcnt(0)" ::: "memory");
            __builtin_amdgcn_s_barrier();
            __builtin_amdgcn_sched_barrier(0);
            asm volatile("" ::: "memory");
        }
    }
#undef STAGE
    float* pb = pstat + (blockIdx.x & 7) * 2 * COUT;
#pragma unroll
    for (int t = 0; t < NT; t++) {
        float sv = s[t], qv = q[t];
        sv += __shfl_xor(sv, 16); qv += __shfl_xor(qv, 16);
        sv += __shfl_xor(sv, 32); qv += __shfl_xor(qv, 32);
        if (quad == 0) {
            atomicAdd(&pb[t * 16 + m], sv);
            atomicAdd(&pb[COUT + t * 16 + m], qv);
        }
    }
}

// ---------- BN stats (only for conv_in's output), f64 deterministic --------
template<int C>
__global__ void bn_stats(const short* __restrict__ x, double* __restrict__ part, int N) {
    constexpr int GR  = C / 8;
    constexpr int RPB = 256 / GR;
    constexpr int ACTIVE = GR * RPB;
    __shared__ double ls[256 * 8];
    __shared__ double lq[256 * 8];
    const int tid = threadIdx.x;
    const int g   = tid % GR;
    const int rr  = tid / GR;
    double s[8], q[8];
#pragma unroll
    for (int j = 0; j < 8; j++) { s[j] = 0.0; q[j] = 0.0; }
    if (tid < ACTIVE) {
        for (long long r = (long long)blockIdx.x * RPB + rr; r < N;
             r += (long long)gridDim.x * RPB) {
            short8 v = *reinterpret_cast<const short8*>(x + r * C + g * 8);
#pragma unroll
            for (int j = 0; j < 8; j++) {
                double f = (double)b2f(v[j]);
                s[j] += f; q[j] += f * f;
            }
        }
    }
#pragma unroll
    for (int j = 0; j < 8; j++) { ls[tid * 8 + j] = s[j]; lq[tid * 8 + j] = q[j]; }
    __syncthreads();
    if (tid < C) {
        int gg = tid / 8, jj = tid % 8;
        double S = 0.0, Q = 0.0;
        for (int r2 = 0; r2 < RPB; r2++) {
            S += ls[(r2 * GR + gg) * 8 + jj];
            Q += lq[(r2 * GR + gg) * 8 + jj];
        }
        part[blockIdx.x * 256 + tid]       = S;
        part[blockIdx.x * 256 + 128 + tid] = Q;
    }
}

__global__ void bn_fin(const double* __restrict__ part, const float* __restrict__ gb,
                       int gbfull, int goff, float* __restrict__ ab,
                       int C, int P, double invN) {
    __shared__ double ss[256], sq[256];
    const int tid = threadIdx.x;
    const int c   = tid % C;
    const int g   = tid / C;
    const int G   = 256 / C;
    double s = 0.0, q = 0.0;
    if (g < G) {
        for (int p = g; p < P; p += G) {
            s += part[p * 256 + c];
            q += part[p * 256 + 128 + c];
        }
    }
    ss[tid] = s; sq[tid] = q;
    __syncthreads();
    if (tid < C) {
        for (int j = 1; j < G; j++) { s += ss[j * C + c]; q += sq[j * C + c]; }
        double mu  = s * invN;
        double var = q * invN - mu * mu;
        double a   = (double)gb[goff + c] / sqrt(var + 1e-4);
        ab[c]     = (float)a;
        ab[C + c] = (float)((double)gb[gbfull + goff + c] - mu * a);
    }
}

// ---------- bn_fin_a: reduce 8 atomic banks -> ab --------------------------
__global__ void bn_fin_a(const float* __restrict__ pst, const float* __restrict__ gb,
                         int gbfull, int goff, float* __restrict__ ab,
                         int C, double invN) {
    int c = threadIdx.x;
    if (c >= C) return;
    double s = 0.0, q = 0.0;
#pragma unroll
    for (int b = 0; b < 8; b++) {
        s += (double)pst[b * 2 * C + c];
        q += (double)pst[b * 2 * C + C + c];
    }
    double mu  = s * invN;
    double var = q * invN - mu * mu;
    double a   = (double)gb[goff + c] / sqrt(var + 1e-4);
    ab[c]     = (float)a;
    ab[C + c] = (float)((double)gb[gbfull + goff + c] - mu * a);
}

// ---------- bnact: y = relu(x*a + b), bf16 -> bf16, 8 elems/thread ---------
template<int C>
__global__ void bnact(const short* __restrict__ x, const float* __restrict__ ab,
                      short* __restrict__ y, long long total8) {
    long long i = (long long)blockIdx.x * blockDim.x + threadIdx.x;
    if (i >= total8) return;
    long long base = i * 8;
    int c0 = (int)(base % C);
    short8 v = *reinterpret_cast<const short8*>(x + base);
    short8 o;
#pragma unroll
    for (int j = 0; j < 8; j++) {
        float f = b2f(v[j]) * ab[c0 + j] + ab[C + c0 + j];
        o[j] = f2b(f > 0.f ? f : 0.f);
    }
    *reinterpret_cast<short8*>(y + base) = o;
}

// ---------- final linear (bnf fused), bf16 in, f32 out ---------------------
__global__ void final_k(const short* __restrict__ x, const float* __restrict__ ab,
                        const float* __restrict__ lw, const float* __restrict__ lb,
                        float* __restrict__ out, int N) {
    long long r = (long long)blockIdx.x * blockDim.x + threadIdx.x;
    if (r >= N) return;
    float a0 = lb[0], a1 = lb[1];
#pragma unroll
    for (int j = 0; j < 4; j++) {
        short8 v = *reinterpret_cast<const short8*>(x + r * 32 + j * 8);
#pragma unroll
        for (int t = 0; t < 8; t++) {
            int ci = 8 * j + t;
            float u = b2f(v[t]) * ab[ci] + ab[32 + ci];
            u = u > 0.f ? u : 0.f;
            a0 += u * lw[ci * 2];
            a1 += u * lw[ci * 2 + 1];
        }
    }
    out[2 * r]     = a0;
    out[2 * r + 1] = a1;
}

extern "C" void kernel_launch(void* const* d_in, const int* in_sizes, int n_in,
                              void* d_out, int out_size, void* d_ws, size_t ws_size,
                              hipStream_t stream) {
    const long long N0 = in_sizes[0] / 3;
    const long long N1 = in_sizes[26] / 8;
    const long long N2 = in_sizes[27] / 8;
    const int P = 256;

    const float* feat = (const float*)d_in[0];
    const int* nbr0 = (const int*)d_in[23];
    const int* nbr1 = (const int*)d_in[24];
    const int* nbr2 = (const int*)d_in[25];
    const int* rb0  = (const int*)d_in[26];
    const int* rb1  = (const int*)d_in[27];

    // ---- arena ----
    char* p = (char*)d_ws;
    double* part = (double*)p;            p += (size_t)P * 256 * 8;     // 512 KB
    float*  ab   = (float*)p;             p += 12 * 256 * 4;
    float*  pst  = (float*)p;             p += (size_t)10 * 2048 * 4;
    unsigned* msk0 = (unsigned*)p;        p += ((size_t)N0 * 4 + 63) & ~(size_t)63;
    const int wLayer[9] = {3, 5, 7, 9, 11, 13, 15, 17, 19};
    const int wK[9]  = {27, 8, 27, 8, 27, 8, 27, 8, 27};
    const int wCI[9] = {32, 32, 64, 64, 96, 96, 128, 64, 64};
    const int wCO[9] = {32, 64, 64, 96, 96, 64, 64, 32, 32};
    short* wt[9];
    WPA wpa;
    int cum = 0;
    for (int i = 0; i < 9; i++) {
        wt[i] = (short*)p;
        int n = wK[i] * wCI[i] * wCO[i];
        p += (((size_t)n * 2 + 63) & ~(size_t)63);
        wpa.src[i] = (const float*)d_in[wLayer[i]];
        wpa.dst[i] = wt[i];
        wpa.CI[i] = wCI[i]; wpa.CO[i] = wCO[i];
        wpa.cum[i] = cum; cum += n;
    }
    wpa.cum[9] = cum;
    auto balloc = [&](long long elems) {
        short* q = (short*)p;
        p += (((size_t)elems * 2 + 63) & ~(size_t)63);
        return q;
    };
    short* R0 = balloc(N0 * 32);   // t0 / d0 / d1 / u1 / u0 (raw)
    short* R1 = balloc(N0 * 32);   // x0 raw (persist)
    short* R2 = balloc(N1 * 64);   // x1 raw (persist)
    short* R3 = balloc(N0 * 32);   // x2 / y1 / y0 (raw)
    short* Xb = balloc(N0 * 32);   // act out (only bn1_0 now)
    short* Yb = balloc(N0 * 32);   // unused (kept for arena stability)

    wprep_all<<<(cum + 255) / 256, 256, 0, stream>>>(wpa, cum);
    zerok<<<(10 * 2048 + 255) / 256, 256, 0, stream>>>(pst, 10 * 2048);
    nbrmask_k<<<(int)((N0 + 255) / 256), 256, 0, stream>>>(nbr0, msk0, (int)N0);

#define AB(SL) (ab + (SL) * 256)
#define PS(SL) (pst + (SL) * 2048)
#define FINA(PSL, GBI, GBFULL, GOFF, SL, CH, NN)                                     \
    bn_fin_a<<<1, 128, 0, stream>>>(PS(PSL), (const float*)d_in[GBI], GBFULL, GOFF,  \
                                    AB(SL), CH, 1.0 / (double)(NN))
#define GB1(N_) (int)(((N_) + 63) / 64)
#define GB2(N_) (int)(((N_) + 127) / 128)

    // ---- level 0 ----
    conv_in<<<(int)((N0 + 255) / 256), 256, 0, stream>>>(
        feat, nbr0, (const float*)d_in[1], R0, (int)N0);                  // t0 -> R0
    bn_stats<32><<<P, 256, 0, stream>>>(R0, part, (int)N0);               // bn1_0
    bn_fin<<<1, 256, 0, stream>>>(part, (const float*)d_in[2], 32, 0,
                                  AB(0), 32, P, 1.0 / (double)N0);
    stencil0<32, 0, 32><<<GB2(N0), 256, 0, stream>>>(
        R0, nullptr, msk0, wt[0], R1, PS(0), AB(0), nullptr, (int)N0);    // x0 -> R1
    FINA(0, 4, 32, 0, 1, 32, N0);                                         // bnd_0
    FINA(0, 18, 64, 0, 9, 32, N0);                                        // bn2_0[x0]
    gmfma12<32, 0, 64, 8, 8, 2, true, false><<<GB2(N1), 256, 0, stream>>>(
        R1, nullptr, rb0, wt[1], R0, PS(1), AB(1), nullptr, (int)N1);     // d0 -> R0
    FINA(1, 6, 64, 0, 2, 64, N1);                                         // bn1_1

    // ---- level 1 ----
    gmfma12<64, 0, 64, 27, 3, 2, true, false><<<GB2(N1), 256, 0, stream>>>(
        R0, nullptr, nbr1, wt[2], R2, PS(2), AB(2), nullptr, (int)N1);    // x1 -> R2
    FINA(2, 8, 64, 0, 3, 64, N1);                                         // bnd_1
    FINA(2, 14, 128, 0, 6, 64, N1);                                       // bn2_1[x1]
    gmfma12<64, 0, 96, 8, 2, 1, true, false><<<GB1(N2), 256, 0, stream>>>(
        R2, nullptr, rb1, wt[3], R0, PS(3), AB(3), nullptr, (int)N2);     // d1 -> R0
    FINA(3, 10, 96, 0, 4, 96, N2);                                        // bn1_2

    // ---- level 2 ----
    gmfma12<96, 0, 96, 27, 3, 1, true, false><<<GB1(N2), 256, 0, stream>>>(
        R0, nullptr, nbr2, wt[4], R3, PS(4), AB(4), nullptr, (int)N2);    // x2 -> R3
    FINA(4, 12, 96, 0, 5, 96, N2);                                        // bnu_1

    // ---- up to level 1 ----
    upmfma10<96, 64, 2><<<GB1(N2), 256, 0, stream>>>(
        R3, rb1, wt[5], R0, PS(5), AB(5), (int)N2);                       // u1 -> R0
    FINA(5, 14, 128, 64, 7, 64, N1);                                      // bn2_1[u1]
    gmfma12<64, 64, 64, 27, 3, 2, true, true><<<GB2(N1), 256, 0, stream>>>(
        R2, R0, nbr1, wt[6], R3, PS(6), AB(6), AB(7), (int)N1);           // y1 -> R3
    FINA(6, 16, 64, 0, 8, 64, N1);                                        // bnu_0

    // ---- up to level 0 ----
    upmfma10<64, 32, 4><<<GB1(N1), 256, 0, stream>>>(
        R3, rb0, wt[7], R0, PS(7), AB(8), (int)N1);                       // u0 -> R0
    FINA(7, 18, 64, 32, 10, 32, N0);                                      // bn2_0[u0]
    stencil0<32, 32, 32><<<GB2(N0), 256, 0, stream>>>(
        R1, R0, msk0, wt[8], R3, PS(8), AB(9), AB(10), (int)N0);          // y0 -> R3
    FINA(8, 20, 32, 0, 11, 32, N0);                                       // bnf

    final_k<<<(int)((N0 + 255) / 256), 256, 0, stream>>>(
        R3, AB(11), (const float*)d_in[21], (const float*)d_in[22],
        (float*)d_out, (int)N0);

#undef AB
#undef PS
#undef FINA
#undef GB1
#undef GB2
}

// Round 13
// 575.399 us; speedup vs baseline: 1.1844x; 1.0332x over previous
//
#include <hip/hip_runtime.h>
#include <hip/hip_bf16.h>

// ---------------------------------------------------------------------------
// Sparse 3-level U-Net — Round 29: R25 base + MT=1 x1/y1 + XCD swizzle.
// R28 post-mortem: act-at-gather on K=27 convs cost VGPR 80->112 (occ 19->14)
// and doubled VALU on the load chain -> 112us. Reverted to R25 (566us).
// R29 theory: x1/y1 grid-bound (560 blocks = 2.2/CU -> 27% occ ceiling).
//  (1) MT=1 for x1/y1: grid x2 (4.4 blk/CU; x1 ceiling 55%, y1 37.5%).
//  (2) bijective XCD-chunked block swizzle in gmfma10: neighbor tiles share
//      gather footprint -> local-L2 hits instead of L3 (latency-bound win).
// Inner conv loop untouched (local optimum per R19-R27 bracketing).
// Baseline R25: 566.0us (x1/y1 77). Prediction: 520-545us.
// ---------------------------------------------------------------------------

typedef __hip_bfloat16 hbf;
typedef __attribute__((ext_vector_type(8))) short short8;
typedef __attribute__((ext_vector_type(4))) float f32x4;
typedef const __attribute__((address_space(1))) short gas_short;
typedef __attribute__((address_space(3))) short las_short;

__device__ inline float b2f(short s) {
    unsigned u = ((unsigned)(unsigned short)s) << 16;
    float f; __builtin_memcpy(&f, &u, 4); return f;
}
__device__ inline short f2b(float f) {
    hbf h = __float2bfloat16(f);
    short s; __builtin_memcpy(&s, &h, 2); return s;
}
// bijective XCD-chunked swizzle (m204): same-XCD blocks get contiguous tiles
__device__ inline int xcd_swz(int orig, int nwg) {
    int xcd = orig & 7;
    int q = nwg >> 3, r = nwg & 7;
    int base = (xcd < r) ? xcd * (q + 1) : r * (q + 1) + (xcd - r) * q;
    return base + (orig >> 3);
}

// ---------- weight prep: all 9 layers in one launch ------------------------
struct WPA {
    const float* src[9];
    short* dst[9];
    int CI[9], CO[9];
    int cum[10];
};
__global__ __launch_bounds__(256) void wprep_all(WPA a, int total) {
    int e0 = blockIdx.x * 256 + threadIdx.x;
    if (e0 >= total) return;
    int L = 0;
#pragma unroll
    for (int i = 1; i < 9; i++) L += (e0 >= a.cum[i]) ? 1 : 0;
    int e = e0 - a.cum[L];
    int CI = a.CI[L], CO = a.CO[L];
    int NT = CO >> 4, NCH = CI >> 5;
    int j    = e & 7;
    int lane = (e >> 3) & 63;
    int t    = (e >> 9) % NT;
    int c    = (e / (512 * NT)) % NCH;
    int k    = e / (512 * NT * NCH);
    int ci = c * 32 + (lane >> 4) * 8 + j;
    int co = t * 16 + (lane & 15);
    a.dst[L][e] = f2b(a.src[L][((long long)k * CI + ci) * CO + co]);
}

// ---------- zero the atomic-stats slots ------------------------------------
__global__ void zerok(float* p, int n) {
    int i = blockIdx.x * 256 + threadIdx.x;
    if (i < n) p[i] = 0.f;
}

// ---------- presence mask from nbr0 (27 bits/row) --------------------------
__global__ __launch_bounds__(256) void nbrmask_k(const int* __restrict__ nbr,
                                                 unsigned* __restrict__ msk, int N) {
    long long r = (long long)blockIdx.x * 256 + threadIdx.x;
    if (r >= N) return;
    unsigned mv = 0;
#pragma unroll
    for (int k = 0; k < 27; k++)
        mv |= (nbr[r * 27 + k] >= 0) ? (1u << k) : 0u;
    msk[r] = mv;
}

// ---------- input conv (CIN=3, f32 VALU, bf16 out) -------------------------
__global__ __launch_bounds__(256) void conv_in(
    const float* __restrict__ feat, const int* __restrict__ nbr,
    const float* __restrict__ W, short* __restrict__ out, int N) {
    __shared__ float sW[27 * 96];
    const int tid = threadIdx.x;
    for (int e = tid; e < 27 * 96; e += 256) sW[e] = W[e];
    __syncthreads();
    long long r = (long long)blockIdx.x * 256 + tid;
    if (r >= N) return;
    float acc[32];
#pragma unroll
    for (int c = 0; c < 32; c++) acc[c] = 0.f;
    for (int k = 0; k < 27; k++) {
        int idx = nbr[r * 27 + k];
        if (idx >= 0) {
            float f0 = feat[(long long)idx * 3];
            float f1 = feat[(long long)idx * 3 + 1];
            float f2 = feat[(long long)idx * 3 + 2];
            const float* w = sW + k * 96;
#pragma unroll
            for (int c = 0; c < 32; c++)
                acc[c] += f0 * w[c] + f1 * w[32 + c] + f2 * w[64 + c];
        }
    }
#pragma unroll
    for (int c = 0; c < 32; c++) out[r * 32 + c] = f2b(acc[c]);
}

// ---------- stencil conv for level 0 (dense 512x512 grid) ------------------
template<int CI1, int CI2, int COUT>
__global__ __launch_bounds__(256) void stencil0(
    const short* __restrict__ fA, const short* __restrict__ fB,
    const unsigned* __restrict__ msk, const short* __restrict__ Wf,
    short* __restrict__ out, float* __restrict__ pstat,
    const float* __restrict__ abA, const float* __restrict__ abB, int N) {
    constexpr int CIT  = CI1 + CI2;
    constexpr int NCH  = CIT / 32;
    constexpr int NT   = COUT / 16;
    constexpr int MT   = 2;
    constexpr int CIB  = CIT * 2;
    constexpr int ROWS = 130;
    constexpr int NC8  = CIT / 8;
    constexpr int SWB  = (CIB >= 128) ? 7 : 3;
    __shared__ __attribute__((aligned(16))) char sA[3 * ROWS * CIB];
    const int tid  = threadIdx.x;
    const int lane = tid & 63;
    const int wid  = tid >> 6;
    const int m    = lane & 15;
    const int quad = lane >> 4;
    const int bid  = blockIdx.x;
    const int xq     = bid >> 2;
    const int ystart = (bid & 3) << 7;
    const long long R = (long long)bid * 128;

    {
        const int c8 = tid % NC8;
        const bool isA = (c8 * 8) < CI1;
        const short* src  = isA ? fA : fB;
        const float* abp  = isA ? abA : abB;
        const int   srcCI = isA ? CI1 : CI2;
        const int   chb   = isA ? c8 * 8 : c8 * 8 - CI1;
        float s_[8], b_[8];
#pragma unroll
        for (int jj = 0; jj < 8; jj++) {
            s_[jj] = abp[chb + jj];
            b_[jj] = abp[srcCI + chb + jj];
        }
        for (int e = tid; e < 3 * ROWS * NC8; e += 256) {
            int rr = (e / NC8) % ROWS;
            int st = e / (NC8 * ROWS);
            long long gr = (long long)(xq - 1 + st) * 512 + (ystart - 1 + rr);
            long long grc = (gr < 0 || gr >= N) ? 0 : gr;
            short8 v = *reinterpret_cast<const short8*>(src + grc * srcCI + chb);
            short8 o;
#pragma unroll
            for (int jj = 0; jj < 8; jj++) {
                float f = b2f(v[jj]) * s_[jj] + b_[jj];
                o[jj] = f2b(f > 0.f ? f : 0.f);
            }
            int byte = (st * ROWS + rr) * CIB + c8 * 16;
            byte ^= ((rr & SWB) << 4);
            *reinterpret_cast<short8*>(sA + byte) = o;
        }
    }
    __syncthreads();

    f32x4 acc[MT][NT];
#pragma unroll
    for (int mt = 0; mt < MT; mt++)
#pragma unroll
        for (int t = 0; t < NT; t++) acc[mt][t] = (f32x4)0.f;

    unsigned mv[MT];
#pragma unroll
    for (int mt = 0; mt < MT; mt++) {
        long long r = R + wid * 32 + mt * 16 + m;
        mv[mt] = (r < N) ? msk[r] : 0u;
    }

#pragma unroll
    for (int s9 = 0; s9 < 9; s9++) {
        const int st = s9 / 3;
        const int dy = s9 % 3 - 1;
        short8 a[MT][NCH];
#pragma unroll
        for (int mt = 0; mt < MT; mt++) {
            int rl = 1 + wid * 32 + mt * 16 + m + dy;
#pragma unroll
            for (int c = 0; c < NCH; c++) {
                int byte = (st * ROWS + rl) * CIB + (c * 4 + quad) * 16;
                byte ^= ((rl & SWB) << 4);
                a[mt][c] = *reinterpret_cast<const short8*>(sA + byte);
            }
        }
#pragma unroll
        for (int z3 = 0; z3 < 3; z3++) {
            const int k = s9 * 3 + z3;
            unsigned anyb = (mv[0] >> k) & 1;
            if (MT > 1) anyb |= (mv[1] >> k) & 1;
            if (__any(anyb)) {
                short8 bf[NCH][NT];
#pragma unroll
                for (int c = 0; c < NCH; c++)
#pragma unroll
                    for (int t = 0; t < NT; t++)
                        bf[c][t] = *reinterpret_cast<const short8*>(
                            Wf + ((size_t)(k * NCH + c) * NT + t) * 512 + lane * 8);
#pragma unroll
                for (int mt = 0; mt < MT; mt++) {
                    const bool bb = (mv[mt] >> k) & 1;
                    short8 asel[NCH];
#pragma unroll
                    for (int c = 0; c < NCH; c++)
                        asel[c] = bb ? a[mt][c] : (short8)0;
#pragma unroll
                    for (int c = 0; c < NCH; c++)
#pragma unroll
                        for (int t = 0; t < NT; t++)
                            acc[mt][t] = __builtin_amdgcn_mfma_f32_16x16x32_bf16(
                                asel[c], bf[c][t], acc[mt][t], 0, 0, 0);
                }
            }
        }
    }

    float s[NT], q[NT];
#pragma unroll
    for (int t = 0; t < NT; t++) { s[t] = 0.f; q[t] = 0.f; }
#pragma unroll
    for (int mt = 0; mt < MT; mt++) {
#pragma unroll
        for (int g4 = 0; g4 < 4; g4++) {
            long long sr = R + wid * 32 + mt * 16 + quad * 4 + g4;
            if (sr < N) {
#pragma unroll
                for (int t = 0; t < NT; t++) {
                    float v = acc[mt][t][g4];
                    out[sr * COUT + t * 16 + m] = f2b(v);
                    s[t] += v; q[t] += v * v;
                }
            }
        }
    }
    float* pb = pstat + (blockIdx.x & 7) * 2 * COUT;
#pragma unroll
    for (int t = 0; t < NT; t++) {
        float sv = s[t], qv = q[t];
        sv += __shfl_xor(sv, 16); qv += __shfl_xor(qv, 16);
        sv += __shfl_xor(sv, 32); qv += __shfl_xor(qv, 32);
        if (quad == 0) {
            atomicAdd(&pb[t * 16 + m], sv);
            atomicAdd(&pb[COUT + t * 16 + m], qv);
        }
    }
}

// ---------- MFMA gather conv v10 + XCD swizzle -----------------------------
template<int CI1, int CI2, int COUT, int K, int G, int MT, bool FACT>
__global__ __launch_bounds__(256) void gmfma10(
    const short* __restrict__ fA, const short* __restrict__ fB,
    const int* __restrict__ nbr, const short* __restrict__ Wf,
    short* __restrict__ out, float* __restrict__ pstat,
    const float* __restrict__ abp, int N) {
    static_assert(K % G == 0, "G must divide K");
    static_assert(!FACT || CI2 == 0, "fused act only for single input");
    constexpr int NT  = COUT / 16;
    constexpr int NC1 = CI1 / 32;
    constexpr int NC2 = CI2 / 32;
    constexpr int NCH = (CI1 + CI2) / 32;
    constexpr int PANEL = NCH * NT * 512;
    constexpr int GSH   = G * PANEL;
    constexpr int NPH   = K / G;
    constexpr int WCH   = GSH / 4;
    constexpr int S16   = (WCH * 2) / 1024;
    constexpr int S4    = ((WCH * 2) % 1024) / 256;
    __shared__ __attribute__((aligned(16))) short sB[GSH];
    const int tid  = threadIdx.x;
    const int lane = tid & 63;
    const int wid  = tid >> 6;
    const int m    = lane & 15;
    const int quad = lane >> 4;
    const int bid  = xcd_swz(blockIdx.x, gridDim.x);
    const long long tb0 = ((long long)bid * 4 + wid) * (MT * 16);

    f32x4 acc[MT][NT];
#pragma unroll
    for (int mt = 0; mt < MT; mt++)
#pragma unroll
        for (int t = 0; t < NT; t++) acc[mt][t] = (f32x4)0.f;

#define STAGE(ph)                                                              \
    {                                                                          \
        const short* _src = Wf + (size_t)(ph) * GSH + wid * WCH;               \
        short* _dst = &sB[wid * WCH];                                          \
        _Pragma("unroll")                                                      \
        for (int i = 0; i < S16; i++)                                          \
            __builtin_amdgcn_global_load_lds(                                  \
                (gas_short*)(_src + i * 512 + lane * 8),                       \
                (las_short*)(_dst + i * 512), 16, 0, 0);                       \
        _Pragma("unroll")                                                      \
        for (int i = 0; i < S4; i++)                                           \
            __builtin_amdgcn_global_load_lds(                                  \
                (gas_short*)(_src + S16 * 512 + i * 128 + lane * 2),           \
                (las_short*)(_dst + S16 * 512 + i * 128), 4, 0, 0);            \
    }

    STAGE(0)
    __builtin_amdgcn_sched_barrier(0);

    int idxs[MT][K];
#pragma unroll
    for (int mt = 0; mt < MT; mt++) {
        long long r = tb0 + mt * 16 + m;
        bool rv = r < N;
#pragma unroll
        for (int k = 0; k < K; k++)
            idxs[mt][k] = rv ? nbr[r * K + k] : -1;
    }
    unsigned pmask[MT];
#pragma unroll
    for (int mt = 0; mt < MT; mt++) {
        unsigned pm = 0;
#pragma unroll
        for (int k = 0; k < K; k++)
            pm |= __any(idxs[mt][k] >= 0) ? (1u << k) : 0u;
        pmask[mt] = __builtin_amdgcn_readfirstlane(pm);
    }

    float aS[FACT ? NC1 * 8 : 1], aBb[FACT ? NC1 * 8 : 1];
    if constexpr (FACT) {
#pragma unroll
        for (int c = 0; c < NC1; c++)
#pragma unroll
            for (int jj = 0; jj < 8; jj++) {
                int ch = c * 32 + quad * 8 + jj;
                aS[c * 8 + jj]  = abp[ch];
                aBb[c * 8 + jj] = abp[CI1 + ch];
            }
    }

    __builtin_amdgcn_sched_barrier(0);
    asm volatile("s_waitcnt vmcnt(0)" ::: "memory");
    __builtin_amdgcn_s_barrier();
    __builtin_amdgcn_sched_barrier(0);
    asm volatile("" ::: "memory");

    short8 S[3][NCH];

#define LOADS(sl, mt, kk)                                                      \
    {                                                                          \
        int _i = idxs[mt][kk];                                                 \
        long long _j = _i < 0 ? 0 : _i;                                        \
        _Pragma("unroll")                                                      \
        for (int c = 0; c < NC1; c++) {                                        \
            short8 _v = *reinterpret_cast<const short8*>(                      \
                fA + _j * CI1 + c * 32 + quad * 8);                            \
            if constexpr (FACT) {                                              \
                short8 _o;                                                     \
                _Pragma("unroll")                                              \
                for (int jj = 0; jj < 8; jj++) {                               \
                    float _f = b2f(_v[jj]) * aS[c * 8 + jj] + aBb[c * 8 + jj]; \
                    _o[jj] = f2b(_f > 0.f ? _f : 0.f);                         \
                }                                                              \
                _v = _o;                                                       \
            }                                                                  \
            S[sl][c] = (_i >= 0) ? _v : (short8)0;                             \
        }                                                                      \
        if constexpr (NC2 > 0) {                                               \
            _Pragma("unroll")                                                  \
            for (int c = 0; c < NC2; c++) {                                    \
                short8 _v = *reinterpret_cast<const short8*>(                  \
                    fB + _j * CI2 + c * 32 + quad * 8);                        \
                S[sl][NC1 + c] = (_i >= 0) ? _v : (short8)0;                   \
            }                                                                  \
        }                                                                      \
    }
#define MFMAS(sl, mt, jl)                                                      \
    {                                                                          \
        _Pragma("unroll")                                                      \
        for (int c = 0; c < NCH; c++) {                                        \
            _Pragma("unroll")                                                  \
            for (int t = 0; t < NT; t++) {                                     \
                short8 b = *reinterpret_cast<const short8*>(                   \
                    &sB[((jl) * NCH * NT + c * NT + t) * 512 + lane * 8]);     \
                acc[mt][t] = __builtin_amdgcn_mfma_f32_16x16x32_bf16(          \
                    S[sl][c], b, acc[mt][t], 0, 0, 0);                         \
            }                                                                  \
        }                                                                      \
    }

#pragma unroll
    for (int ph = 0; ph < NPH; ph++) {
#pragma unroll
        for (int mt = 0; mt < MT; mt++) {
            const unsigned mm = (pmask[mt] >> (ph * G)) & ((1u << G) - 1);
#pragma unroll
            for (int j = 0; j < G + 2; j++) {
                if (j < G)
                    if (mm & (1u << j)) LOADS(j % 3, mt, ph * G + j)
                if (j >= 2)
                    if (mm & (1u << (j - 2))) MFMAS((j - 2) % 3, mt, j - 2)
            }
        }
        if (ph + 1 < NPH) {
            __builtin_amdgcn_sched_barrier(0);
            asm volatile("s_waitcnt lgkmcnt(0)" ::: "memory");
            __builtin_amdgcn_s_barrier();
            __builtin_amdgcn_sched_barrier(0);
            STAGE(ph + 1)
            __builtin_amdgcn_sched_barrier(0);
            asm volatile("s_waitcnt vmcnt(0)" ::: "memory");
            __builtin_amdgcn_s_barrier();
            __builtin_amdgcn_sched_barrier(0);
            asm volatile("" ::: "memory");
        }
    }
#undef LOADS
#undef MFMAS
#undef STAGE
    float s[NT], q[NT];
#pragma unroll
    for (int t = 0; t < NT; t++) { s[t] = 0.f; q[t] = 0.f; }
#pragma unroll
    for (int mt = 0; mt < MT; mt++) {
#pragma unroll
        for (int g4 = 0; g4 < 4; g4++) {
            long long sr = tb0 + mt * 16 + quad * 4 + g4;
            if (sr < N) {
#pragma unroll
                for (int t = 0; t < NT; t++) {
                    float v = acc[mt][t][g4];
                    out[sr * COUT + t * 16 + m] = f2b(v);
                    s[t] += v; q[t] += v * v;
                }
            }
        }
    }
    float* pb = pstat + (bid & 7) * 2 * COUT;
#pragma unroll
    for (int t = 0; t < NT; t++) {
        float sv = s[t], qv = q[t];
        sv += __shfl_xor(sv, 16); qv += __shfl_xor(qv, 16);
        sv += __shfl_xor(sv, 32); qv += __shfl_xor(qv, 32);
        if (quad == 0) {
            atomicAdd(&pb[t * 16 + m], sv);
            atomicAdd(&pb[COUT + t * 16 + m], qv);
        }
    }
}

// ---------- MFMA up conv v10 (R25, unchanged) ------------------------------
template<int CIN, int COUT, int G>
__global__ __launch_bounds__(256) void upmfma10(
    const short* __restrict__ f, const int* __restrict__ rb,
    const short* __restrict__ Wf, short* __restrict__ out,
    float* __restrict__ pstat, const float* __restrict__ abp, int N) {
    static_assert(8 % G == 0, "G must divide 8");
    constexpr int NT = COUT / 16;
    constexpr int NK = CIN / 32;
    constexpr int PANEL = NK * NT * 512;
    constexpr int GSH   = G * PANEL;
    constexpr int NPH   = 8 / G;
    constexpr int WCH   = GSH / 4;
    constexpr int S16   = (WCH * 2) / 1024;
    constexpr int S4    = ((WCH * 2) % 1024) / 256;
    __shared__ __attribute__((aligned(16))) short sB[GSH];
    const int tid  = threadIdx.x;
    const int lane = tid & 63;
    const int wid  = tid >> 6;
    const int m    = lane & 15;
    const int quad = lane >> 4;
    const long long row0 = ((long long)blockIdx.x * 4 + wid) * 16;
    const long long r = row0 + m;
    const bool rv = r < N;
    const long long rc = rv ? r : 0;

#define STAGE(ph)                                                              \
    {                                                                          \
        const short* _src = Wf + (size_t)(ph) * GSH + wid * WCH;               \
        short* _dst = &sB[wid * WCH];                                          \
        _Pragma("unroll")                                                      \
        for (int i = 0; i < S16; i++)                                          \
            __builtin_amdgcn_global_load_lds(                                  \
                (gas_short*)(_src + i * 512 + lane * 8),                       \
                (las_short*)(_dst + i * 512), 16, 0, 0);                       \
        _Pragma("unroll")                                                      \
        for (int i = 0; i < S4; i++)                                           \
            __builtin_amdgcn_global_load_lds(                                  \
                (gas_short*)(_src + S16 * 512 + i * 128 + lane * 2),           \
                (las_short*)(_dst + S16 * 512 + i * 128), 4, 0, 0);            \
    }
    STAGE(0)
    __builtin_amdgcn_sched_barrier(0);

    short8 af[NK];
#pragma unroll
    for (int kc = 0; kc < NK; kc++) {
        short8 v = *reinterpret_cast<const short8*>(
            f + rc * CIN + kc * 32 + quad * 8);
        short8 o;
#pragma unroll
        for (int jj = 0; jj < 8; jj++) {
            int ch = kc * 32 + quad * 8 + jj;
            float u = b2f(v[jj]) * abp[ch] + abp[CIN + ch];
            o[jj] = f2b(u > 0.f ? u : 0.f);
        }
        af[kc] = rv ? o : (short8)0;
    }
    int sidx[8][4];
#pragma unroll
    for (int g4 = 0; g4 < 4; g4++) {
        long long sr = row0 + quad * 4 + g4;
#pragma unroll
        for (int k = 0; k < 8; k++)
            sidx[k][g4] = (sr < N) ? rb[sr * 8 + k] : -1;
    }
    unsigned pm = 0;
#pragma unroll
    for (int k = 0; k < 8; k++) {
        int anyv = (sidx[k][0] >= 0) | (sidx[k][1] >= 0) |
                   (sidx[k][2] >= 0) | (sidx[k][3] >= 0);
        pm |= __any(anyv) ? (1u << k) : 0u;
    }
    pm = __builtin_amdgcn_readfirstlane(pm);

    float s[NT], q[NT];
#pragma unroll
    for (int t = 0; t < NT; t++) { s[t] = 0.f; q[t] = 0.f; }

    __builtin_amdgcn_sched_barrier(0);
    asm volatile("s_waitcnt vmcnt(0)" ::: "memory");
    __builtin_amdgcn_s_barrier();
    __builtin_amdgcn_sched_barrier(0);
    asm volatile("" ::: "memory");

#pragma unroll
    for (int ph = 0; ph < NPH; ph++) {
#pragma unroll
        for (int j = 0; j < G; j++) {
            const int k = ph * G + j;
            if (pm & (1u << k)) {
                f32x4 acc[NT];
#pragma unroll
                for (int t = 0; t < NT; t++) acc[t] = (f32x4)0.f;
#pragma unroll
                for (int kc = 0; kc < NK; kc++) {
#pragma unroll
                    for (int t = 0; t < NT; t++) {
                        short8 b = *reinterpret_cast<const short8*>(
                            &sB[(j * NK * NT + kc * NT + t) * 512 + lane * 8]);
                        acc[t] = __builtin_amdgcn_mfma_f32_16x16x32_bf16(
                            af[kc], b, acc[t], 0, 0, 0);
                    }
                }
#pragma unroll
                for (int g4 = 0; g4 < 4; g4++) {
                    if (sidx[k][g4] >= 0) {
#pragma unroll
                        for (int t = 0; t < NT; t++) {
                            float v = acc[t][g4];
                            out[(long long)sidx[k][g4] * COUT + t * 16 + m] =
                                f2b(v);
                            s[t] += v; q[t] += v * v;
                        }
                    }
                }
            }
        }
        if (ph + 1 < NPH) {
            __builtin_amdgcn_sched_barrier(0);
            asm volatile("s_waitcnt lgkmcnt(0)" ::: "memory");
            __builtin_amdgcn_s_barrier();
            __builtin_amdgcn_sched_barrier(0);
            STAGE(ph + 1)
            __builtin_amdgcn_sched_barrier(0);
            asm volatile("s_waitcnt vmcnt(0)" ::: "memory");
            __builtin_amdgcn_s_barrier();
            __builtin_amdgcn_sched_barrier(0);
            asm volatile("" ::: "memory");
        }
    }
#undef STAGE
    float* pb = pstat + (blockIdx.x & 7) * 2 * COUT;
#pragma unroll
    for (int t = 0; t < NT; t++) {
        float sv = s[t], qv = q[t];
        sv += __shfl_xor(sv, 16); qv += __shfl_xor(qv, 16);
        sv += __shfl_xor(sv, 32); qv += __shfl_xor(qv, 32);
        if (quad == 0) {
            atomicAdd(&pb[t * 16 + m], sv);
            atomicAdd(&pb[COUT + t * 16 + m], qv);
        }
    }
}

// ---------- BN stats (only for conv_in's output), f64 deterministic --------
template<int C>
__global__ void bn_stats(const short* __restrict__ x, double* __restrict__ part, int N) {
    constexpr int GR  = C / 8;
    constexpr int RPB = 256 / GR;
    constexpr int ACTIVE = GR * RPB;
    __shared__ double ls[256 * 8];
    __shared__ double lq[256 * 8];
    const int tid = threadIdx.x;
    const int g   = tid % GR;
    const int rr  = tid / GR;
    double s[8], q[8];
#pragma unroll
    for (int j = 0; j < 8; j++) { s[j] = 0.0; q[j] = 0.0; }
    if (tid < ACTIVE) {
        for (long long r = (long long)blockIdx.x * RPB + rr; r < N;
             r += (long long)gridDim.x * RPB) {
            short8 v = *reinterpret_cast<const short8*>(x + r * C + g * 8);
#pragma unroll
            for (int j = 0; j < 8; j++) {
                double f = (double)b2f(v[j]);
                s[j] += f; q[j] += f * f;
            }
        }
    }
#pragma unroll
    for (int j = 0; j < 8; j++) { ls[tid * 8 + j] = s[j]; lq[tid * 8 + j] = q[j]; }
    __syncthreads();
    if (tid < C) {
        int gg = tid / 8, jj = tid % 8;
        double S = 0.0, Q = 0.0;
        for (int r2 = 0; r2 < RPB; r2++) {
            S += ls[(r2 * GR + gg) * 8 + jj];
            Q += lq[(r2 * GR + gg) * 8 + jj];
        }
        part[blockIdx.x * 256 + tid]       = S;
        part[blockIdx.x * 256 + 128 + tid] = Q;
    }
}

__global__ void bn_fin(const double* __restrict__ part, const float* __restrict__ gb,
                       int gbfull, int goff, float* __restrict__ ab,
                       int C, int P, double invN) {
    __shared__ double ss[256], sq[256];
    const int tid = threadIdx.x;
    const int c   = tid % C;
    const int g   = tid / C;
    const int G   = 256 / C;
    double s = 0.0, q = 0.0;
    if (g < G) {
        for (int p = g; p < P; p += G) {
            s += part[p * 256 + c];
            q += part[p * 256 + 128 + c];
        }
    }
    ss[tid] = s; sq[tid] = q;
    __syncthreads();
    if (tid < C) {
        for (int j = 1; j < G; j++) { s += ss[j * C + c]; q += sq[j * C + c]; }
        double mu  = s * invN;
        double var = q * invN - mu * mu;
        double a   = (double)gb[goff + c] / sqrt(var + 1e-4);
        ab[c]     = (float)a;
        ab[C + c] = (float)((double)gb[gbfull + goff + c] - mu * a);
    }
}

// ---------- bn_fin_a: reduce 8 atomic banks -> ab --------------------------
__global__ void bn_fin_a(const float* __restrict__ pst, const float* __restrict__ gb,
                         int gbfull, int goff, float* __restrict__ ab,
                         int C, double invN) {
    int c = threadIdx.x;
    if (c >= C) return;
    double s = 0.0, q = 0.0;
#pragma unroll
    for (int b = 0; b < 8; b++) {
        s += (double)pst[b * 2 * C + c];
        q += (double)pst[b * 2 * C + C + c];
    }
    double mu  = s * invN;
    double var = q * invN - mu * mu;
    double a   = (double)gb[goff + c] / sqrt(var + 1e-4);
    ab[c]     = (float)a;
    ab[C + c] = (float)((double)gb[gbfull + goff + c] - mu * a);
}

// ---------- bnact: y = relu(x*a + b), bf16 -> bf16, 8 elems/thread ---------
template<int C>
__global__ void bnact(const short* __restrict__ x, const float* __restrict__ ab,
                      short* __restrict__ y, long long total8) {
    long long i = (long long)blockIdx.x * blockDim.x + threadIdx.x;
    if (i >= total8) return;
    long long base = i * 8;
    int c0 = (int)(base % C);
    short8 v = *reinterpret_cast<const short8*>(x + base);
    short8 o;
#pragma unroll
    for (int j = 0; j < 8; j++) {
        float f = b2f(v[j]) * ab[c0 + j] + ab[C + c0 + j];
        o[j] = f2b(f > 0.f ? f : 0.f);
    }
    *reinterpret_cast<short8*>(y + base) = o;
}

// ---------- bnact2: two tensors in one launch ------------------------------
template<int C>
__global__ void bnact2(const short* __restrict__ xa, const float* __restrict__ aba,
                       short* __restrict__ ya,
                       const short* __restrict__ xb, const float* __restrict__ abb,
                       short* __restrict__ yb, long long n8) {
    long long i = (long long)blockIdx.x * blockDim.x + threadIdx.x;
    if (i >= 2 * n8) return;
    const short* x; const float* ab; short* y; long long ii;
    if (i < n8) { x = xa; ab = aba; y = ya; ii = i; }
    else        { x = xb; ab = abb; y = yb; ii = i - n8; }
    long long base = ii * 8;
    int c0 = (int)(base % C);
    short8 v = *reinterpret_cast<const short8*>(x + base);
    short8 o;
#pragma unroll
    for (int j = 0; j < 8; j++) {
        float f = b2f(v[j]) * ab[c0 + j] + ab[C + c0 + j];
        o[j] = f2b(f > 0.f ? f : 0.f);
    }
    *reinterpret_cast<short8*>(y + base) = o;
}

// ---------- final linear (bnf fused), bf16 in, f32 out ---------------------
__global__ void final_k(const short* __restrict__ x, const float* __restrict__ ab,
                        const float* __restrict__ lw, const float* __restrict__ lb,
                        float* __restrict__ out, int N) {
    long long r = (long long)blockIdx.x * blockDim.x + threadIdx.x;
    if (r >= N) return;
    float a0 = lb[0], a1 = lb[1];
#pragma unroll
    for (int j = 0; j < 4; j++) {
        short8 v = *reinterpret_cast<const short8*>(x + r * 32 + j * 8);
#pragma unroll
        for (int t = 0; t < 8; t++) {
            int ci = 8 * j + t;
            float u = b2f(v[t]) * ab[ci] + ab[32 + ci];
            u = u > 0.f ? u : 0.f;
            a0 += u * lw[ci * 2];
            a1 += u * lw[ci * 2 + 1];
        }
    }
    out[2 * r]     = a0;
    out[2 * r + 1] = a1;
}

extern "C" void kernel_launch(void* const* d_in, const int* in_sizes, int n_in,
                              void* d_out, int out_size, void* d_ws, size_t ws_size,
                              hipStream_t stream) {
    const long long N0 = in_sizes[0] / 3;
    const long long N1 = in_sizes[26] / 8;
    const long long N2 = in_sizes[27] / 8;
    const int P = 256;

    const float* feat = (const float*)d_in[0];
    const int* nbr0 = (const int*)d_in[23];
    const int* nbr1 = (const int*)d_in[24];
    const int* nbr2 = (const int*)d_in[25];
    const int* rb0  = (const int*)d_in[26];
    const int* rb1  = (const int*)d_in[27];

    // ---- arena ----
    char* p = (char*)d_ws;
    double* part = (double*)p;            p += (size_t)P * 256 * 8;     // 512 KB
    float*  ab   = (float*)p;             p += 12 * 256 * 4;
    float*  pst  = (float*)p;             p += (size_t)10 * 2048 * 4;
    unsigned* msk0 = (unsigned*)p;        p += ((size_t)N0 * 4 + 63) & ~(size_t)63;
    const int wLayer[9] = {3, 5, 7, 9, 11, 13, 15, 17, 19};
    const int wK[9]  = {27, 8, 27, 8, 27, 8, 27, 8, 27};
    const int wCI[9] = {32, 32, 64, 64, 96, 96, 128, 64, 64};
    const int wCO[9] = {32, 64, 64, 96, 96, 64, 64, 32, 32};
    short* wt[9];
    WPA wpa;
    int cum = 0;
    for (int i = 0; i < 9; i++) {
        wt[i] = (short*)p;
        int n = wK[i] * wCI[i] * wCO[i];
        p += (((size_t)n * 2 + 63) & ~(size_t)63);
        wpa.src[i] = (const float*)d_in[wLayer[i]];
        wpa.dst[i] = wt[i];
        wpa.CI[i] = wCI[i]; wpa.CO[i] = wCO[i];
        wpa.cum[i] = cum; cum += n;
    }
    wpa.cum[9] = cum;
    auto balloc = [&](long long elems) {
        short* q = (short*)p;
        p += (((size_t)elems * 2 + 63) & ~(size_t)63);
        return q;
    };
    short* R0 = balloc(N0 * 32);   // t0 / d0 / d1 / u1 / u0 (raw)
    short* R1 = balloc(N0 * 32);   // x0 raw (persist)
    short* R2 = balloc(N1 * 64);   // x1 raw (persist)
    short* R3 = balloc(N0 * 32);   // x2 / y1 / y0 (raw)
    short* Xb = balloc(N0 * 32);   // act out #1
    short* Yb = balloc(N0 * 32);   // act out #2

    wprep_all<<<(cum + 255) / 256, 256, 0, stream>>>(wpa, cum);
    zerok<<<(10 * 2048 + 255) / 256, 256, 0, stream>>>(pst, 10 * 2048);
    nbrmask_k<<<(int)((N0 + 255) / 256), 256, 0, stream>>>(nbr0, msk0, (int)N0);

#define AB(SL) (ab + (SL) * 256)
#define PS(SL) (pst + (SL) * 2048)
#define FINA(PSL, GBI, GBFULL, GOFF, SL, CH, NN)                                     \
    bn_fin_a<<<1, 128, 0, stream>>>(PS(PSL), (const float*)d_in[GBI], GBFULL, GOFF,  \
                                    AB(SL), CH, 1.0 / (double)(NN))
#define GB1(N_) (int)(((N_) + 63) / 64)
#define GB2(N_) (int)(((N_) + 127) / 128)

    // ---- level 0 ----
    conv_in<<<(int)((N0 + 255) / 256), 256, 0, stream>>>(
        feat, nbr0, (const float*)d_in[1], R0, (int)N0);                  // t0 -> R0
    bn_stats<32><<<P, 256, 0, stream>>>(R0, part, (int)N0);               // bn1_0
    bn_fin<<<1, 256, 0, stream>>>(part, (const float*)d_in[2], 32, 0,
                                  AB(0), 32, P, 1.0 / (double)N0);
    stencil0<32, 0, 32><<<GB2(N0), 256, 0, stream>>>(
        R0, nullptr, msk0, wt[0], R1, PS(0), AB(0), nullptr, (int)N0);    // x0 -> R1
    FINA(0, 4, 32, 0, 1, 32, N0);                                         // bnd_0
    FINA(0, 18, 64, 0, 9, 32, N0);                                        // bn2_0[x0]
    gmfma10<32, 0, 64, 8, 8, 2, true><<<GB2(N1), 256, 0, stream>>>(
        R1, nullptr, rb0, wt[1], R0, PS(1), AB(1), (int)N1);              // d0 -> R0
    FINA(1, 6, 64, 0, 2, 64, N1);                                         // bn1_1

    // ---- level 1 ----
    bnact<64><<<(int)((N1 * 64 / 8 + 255) / 256), 256, 0, stream>>>(
        R0, AB(2), Xb, N1 * 64 / 8);
    gmfma10<64, 0, 64, 27, 3, 1, false><<<GB1(N1), 256, 0, stream>>>(
        Xb, nullptr, nbr1, wt[2], R2, PS(2), nullptr, (int)N1);           // x1 -> R2
    FINA(2, 8, 64, 0, 3, 64, N1);                                         // bnd_1
    FINA(2, 14, 128, 0, 6, 64, N1);                                       // bn2_1[x1]
    gmfma10<64, 0, 96, 8, 2, 1, true><<<GB1(N2), 256, 0, stream>>>(
        R2, nullptr, rb1, wt[3], R0, PS(3), AB(3), (int)N2);              // d1 -> R0
    FINA(3, 10, 96, 0, 4, 96, N2);                                        // bn1_2

    // ---- level 2 ----
    bnact<96><<<(int)((N2 * 96 / 8 + 255) / 256), 256, 0, stream>>>(
        R0, AB(4), Xb, N2 * 96 / 8);
    gmfma10<96, 0, 96, 27, 3, 1, false><<<GB1(N2), 256, 0, stream>>>(
        Xb, nullptr, nbr2, wt[4], R3, PS(4), nullptr, (int)N2);           // x2 -> R3
    FINA(4, 12, 96, 0, 5, 96, N2);                                        // bnu_1

    // ---- up to level 1 ----
    upmfma10<96, 64, 2><<<GB1(N2), 256, 0, stream>>>(
        R3, rb1, wt[5], R0, PS(5), AB(5), (int)N2);                       // u1 -> R0
    FINA(5, 14, 128, 64, 7, 64, N1);                                      // bn2_1[u1]
    bnact2<64><<<(int)((2 * (N1 * 64 / 8) + 255) / 256), 256, 0, stream>>>(
        R2, AB(6), Xb, R0, AB(7), Yb, N1 * 64 / 8);
    gmfma10<64, 64, 64, 27, 3, 1, false><<<GB1(N1), 256, 0, stream>>>(
        Xb, Yb, nbr1, wt[6], R3, PS(6), nullptr, (int)N1);                // y1 -> R3
    FINA(6, 16, 64, 0, 8, 64, N1);                                        // bnu_0

    // ---- up to level 0 ----
    upmfma10<64, 32, 4><<<GB1(N1), 256, 0, stream>>>(
        R3, rb0, wt[7], R0, PS(7), AB(8), (int)N1);                       // u0 -> R0
    FINA(7, 18, 64, 32, 10, 32, N0);                                      // bn2_0[u0]
    stencil0<32, 32, 32><<<GB2(N0), 256, 0, stream>>>(
        R1, R0, msk0, wt[8], R3, PS(8), AB(9), AB(10), (int)N0);          // y0 -> R3
    FINA(8, 20, 32, 0, 11, 32, N0);                                       // bnf

    final_k<<<(int)((N0 + 255) / 256), 256, 0, stream>>>(
        R3, AB(11), (const float*)d_in[21], (const float*)d_in[22],
        (float*)d_out, (int)N0);

#undef AB
#undef PS
#undef FINA
#undef GB1
#undef GB2
}

// Round 14
// 556.783 us; speedup vs baseline: 1.2240x; 1.0334x over previous
//
#include <hip/hip_runtime.h>
#include <hip/hip_bf16.h>

// ---------------------------------------------------------------------------
// Sparse 3-level U-Net — Round 30: R25 config + stencilized conv_in.
// R29 post-mortem: XCD swizzle halved FETCH (36->16GB) but conv time rose ->
// convs are serial-chain bound, not locality bound; MT=1 halved B-reuse.
// Both reverted: R25 geometry (566us) confirmed optimal over 8 variants.
// R30: conv_in (est 30-60us, latency-bound 27-gather at dense level 0) gets
// the proven stencil0 transform: 256-row blocks, LDS-stage 3 strips x 258
// rows x 3 floats of feat + weights, per-row 27-bit mask walk, zero gathers.
// Baseline R25: 566.0us. Prediction: 520-540us.
// ---------------------------------------------------------------------------

typedef __hip_bfloat16 hbf;
typedef __attribute__((ext_vector_type(8))) short short8;
typedef __attribute__((ext_vector_type(4))) float f32x4;
typedef const __attribute__((address_space(1))) short gas_short;
typedef __attribute__((address_space(3))) short las_short;

__device__ inline float b2f(short s) {
    unsigned u = ((unsigned)(unsigned short)s) << 16;
    float f; __builtin_memcpy(&f, &u, 4); return f;
}
__device__ inline short f2b(float f) {
    hbf h = __float2bfloat16(f);
    short s; __builtin_memcpy(&s, &h, 2); return s;
}

// ---------- weight prep: all 9 layers in one launch ------------------------
struct WPA {
    const float* src[9];
    short* dst[9];
    int CI[9], CO[9];
    int cum[10];
};
__global__ __launch_bounds__(256) void wprep_all(WPA a, int total) {
    int e0 = blockIdx.x * 256 + threadIdx.x;
    if (e0 >= total) return;
    int L = 0;
#pragma unroll
    for (int i = 1; i < 9; i++) L += (e0 >= a.cum[i]) ? 1 : 0;
    int e = e0 - a.cum[L];
    int CI = a.CI[L], CO = a.CO[L];
    int NT = CO >> 4, NCH = CI >> 5;
    int j    = e & 7;
    int lane = (e >> 3) & 63;
    int t    = (e >> 9) % NT;
    int c    = (e / (512 * NT)) % NCH;
    int k    = e / (512 * NT * NCH);
    int ci = c * 32 + (lane >> 4) * 8 + j;
    int co = t * 16 + (lane & 15);
    a.dst[L][e] = f2b(a.src[L][((long long)k * CI + ci) * CO + co]);
}

// ---------- zero the atomic-stats slots ------------------------------------
__global__ void zerok(float* p, int n) {
    int i = blockIdx.x * 256 + threadIdx.x;
    if (i < n) p[i] = 0.f;
}

// ---------- presence mask from nbr0 (27 bits/row) --------------------------
__global__ __launch_bounds__(256) void nbrmask_k(const int* __restrict__ nbr,
                                                 unsigned* __restrict__ msk, int N) {
    long long r = (long long)blockIdx.x * 256 + threadIdx.x;
    if (r >= N) return;
    unsigned mv = 0;
#pragma unroll
    for (int k = 0; k < 27; k++)
        mv |= (nbr[r * 27 + k] >= 0) ? (1u << k) : 0u;
    msk[r] = mv;
}

// ---------- input conv, STENCILIZED (dense level-0 grid) -------------------
// Block = 256 consecutive rows (one x line, half the y range).
// LDS: 3 x-strips x 258 rows x 3 floats of feat; weights 27x96 f32.
__global__ __launch_bounds__(256) void conv_in_st(
    const float* __restrict__ feat, const unsigned* __restrict__ msk,
    const float* __restrict__ W, short* __restrict__ out, int N) {
    __shared__ float sW[27 * 96];
    __shared__ float sF[3][258][3];
    const int tid = threadIdx.x;
    const int bid = blockIdx.x;
    const int xq     = bid >> 1;
    const int ystart = (bid & 1) << 8;
    const long long R = (long long)bid * 256;

    for (int e = tid; e < 27 * 96; e += 256) sW[e] = W[e];
    for (int e = tid; e < 3 * 258; e += 256) {
        int rr = e % 258, st = e / 258;
        long long gr = (long long)(xq - 1 + st) * 512 + (ystart - 1 + rr);
        long long grc = (gr < 0 || gr >= N) ? 0 : gr;   // fault-safe; masked
        sF[st][rr][0] = feat[grc * 3];
        sF[st][rr][1] = feat[grc * 3 + 1];
        sF[st][rr][2] = feat[grc * 3 + 2];
    }
    __syncthreads();

    long long r = R + tid;
    unsigned mv = (r < N) ? msk[r] : 0u;
    float acc[32];
#pragma unroll
    for (int c = 0; c < 32; c++) acc[c] = 0.f;
#pragma unroll
    for (int k = 0; k < 27; k++) {
        if (mv & (1u << k)) {
            const int st = k / 9;               // dx+1
            const int dy = (k / 3) % 3 - 1;
            const int rl = 1 + tid + dy;
            float f0 = sF[st][rl][0];
            float f1 = sF[st][rl][1];
            float f2 = sF[st][rl][2];
            const float* w = sW + k * 96;
#pragma unroll
            for (int c = 0; c < 32; c++)
                acc[c] += f0 * w[c] + f1 * w[32 + c] + f2 * w[64 + c];
        }
    }
    if (r < N) {
#pragma unroll
        for (int c = 0; c < 32; c++) out[r * 32 + c] = f2b(acc[c]);
    }
}

// ---------- stencil conv for level 0 (dense 512x512 grid) ------------------
template<int CI1, int CI2, int COUT>
__global__ __launch_bounds__(256) void stencil0(
    const short* __restrict__ fA, const short* __restrict__ fB,
    const unsigned* __restrict__ msk, const short* __restrict__ Wf,
    short* __restrict__ out, float* __restrict__ pstat,
    const float* __restrict__ abA, const float* __restrict__ abB, int N) {
    constexpr int CIT  = CI1 + CI2;
    constexpr int NCH  = CIT / 32;
    constexpr int NT   = COUT / 16;
    constexpr int MT   = 2;
    constexpr int CIB  = CIT * 2;
    constexpr int ROWS = 130;
    constexpr int NC8  = CIT / 8;
    constexpr int SWB  = (CIB >= 128) ? 7 : 3;
    __shared__ __attribute__((aligned(16))) char sA[3 * ROWS * CIB];
    const int tid  = threadIdx.x;
    const int lane = tid & 63;
    const int wid  = tid >> 6;
    const int m    = lane & 15;
    const int quad = lane >> 4;
    const int bid  = blockIdx.x;
    const int xq     = bid >> 2;
    const int ystart = (bid & 3) << 7;
    const long long R = (long long)bid * 128;

    {
        const int c8 = tid % NC8;
        const bool isA = (c8 * 8) < CI1;
        const short* src  = isA ? fA : fB;
        const float* abp  = isA ? abA : abB;
        const int   srcCI = isA ? CI1 : CI2;
        const int   chb   = isA ? c8 * 8 : c8 * 8 - CI1;
        float s_[8], b_[8];
#pragma unroll
        for (int jj = 0; jj < 8; jj++) {
            s_[jj] = abp[chb + jj];
            b_[jj] = abp[srcCI + chb + jj];
        }
        for (int e = tid; e < 3 * ROWS * NC8; e += 256) {
            int rr = (e / NC8) % ROWS;
            int st = e / (NC8 * ROWS);
            long long gr = (long long)(xq - 1 + st) * 512 + (ystart - 1 + rr);
            long long grc = (gr < 0 || gr >= N) ? 0 : gr;
            short8 v = *reinterpret_cast<const short8*>(src + grc * srcCI + chb);
            short8 o;
#pragma unroll
            for (int jj = 0; jj < 8; jj++) {
                float f = b2f(v[jj]) * s_[jj] + b_[jj];
                o[jj] = f2b(f > 0.f ? f : 0.f);
            }
            int byte = (st * ROWS + rr) * CIB + c8 * 16;
            byte ^= ((rr & SWB) << 4);
            *reinterpret_cast<short8*>(sA + byte) = o;
        }
    }
    __syncthreads();

    f32x4 acc[MT][NT];
#pragma unroll
    for (int mt = 0; mt < MT; mt++)
#pragma unroll
        for (int t = 0; t < NT; t++) acc[mt][t] = (f32x4)0.f;

    unsigned mv[MT];
#pragma unroll
    for (int mt = 0; mt < MT; mt++) {
        long long r = R + wid * 32 + mt * 16 + m;
        mv[mt] = (r < N) ? msk[r] : 0u;
    }

#pragma unroll
    for (int s9 = 0; s9 < 9; s9++) {
        const int st = s9 / 3;
        const int dy = s9 % 3 - 1;
        short8 a[MT][NCH];
#pragma unroll
        for (int mt = 0; mt < MT; mt++) {
            int rl = 1 + wid * 32 + mt * 16 + m + dy;
#pragma unroll
            for (int c = 0; c < NCH; c++) {
                int byte = (st * ROWS + rl) * CIB + (c * 4 + quad) * 16;
                byte ^= ((rl & SWB) << 4);
                a[mt][c] = *reinterpret_cast<const short8*>(sA + byte);
            }
        }
#pragma unroll
        for (int z3 = 0; z3 < 3; z3++) {
            const int k = s9 * 3 + z3;
            unsigned anyb = (mv[0] >> k) & 1;
            if (MT > 1) anyb |= (mv[1] >> k) & 1;
            if (__any(anyb)) {
                short8 bf[NCH][NT];
#pragma unroll
                for (int c = 0; c < NCH; c++)
#pragma unroll
                    for (int t = 0; t < NT; t++)
                        bf[c][t] = *reinterpret_cast<const short8*>(
                            Wf + ((size_t)(k * NCH + c) * NT + t) * 512 + lane * 8);
#pragma unroll
                for (int mt = 0; mt < MT; mt++) {
                    const bool bb = (mv[mt] >> k) & 1;
                    short8 asel[NCH];
#pragma unroll
                    for (int c = 0; c < NCH; c++)
                        asel[c] = bb ? a[mt][c] : (short8)0;
#pragma unroll
                    for (int c = 0; c < NCH; c++)
#pragma unroll
                        for (int t = 0; t < NT; t++)
                            acc[mt][t] = __builtin_amdgcn_mfma_f32_16x16x32_bf16(
                                asel[c], bf[c][t], acc[mt][t], 0, 0, 0);
                }
            }
        }
    }

    float s[NT], q[NT];
#pragma unroll
    for (int t = 0; t < NT; t++) { s[t] = 0.f; q[t] = 0.f; }
#pragma unroll
    for (int mt = 0; mt < MT; mt++) {
#pragma unroll
        for (int g4 = 0; g4 < 4; g4++) {
            long long sr = R + wid * 32 + mt * 16 + quad * 4 + g4;
            if (sr < N) {
#pragma unroll
                for (int t = 0; t < NT; t++) {
                    float v = acc[mt][t][g4];
                    out[sr * COUT + t * 16 + m] = f2b(v);
                    s[t] += v; q[t] += v * v;
                }
            }
        }
    }
    float* pb = pstat + (blockIdx.x & 7) * 2 * COUT;
#pragma unroll
    for (int t = 0; t < NT; t++) {
        float sv = s[t], qv = q[t];
        sv += __shfl_xor(sv, 16); qv += __shfl_xor(qv, 16);
        sv += __shfl_xor(sv, 32); qv += __shfl_xor(qv, 32);
        if (quad == 0) {
            atomicAdd(&pb[t * 16 + m], sv);
            atomicAdd(&pb[COUT + t * 16 + m], qv);
        }
    }
}

// ---------- MFMA gather conv v10 (R25, unchanged) --------------------------
template<int CI1, int CI2, int COUT, int K, int G, int MT, bool FACT>
__global__ __launch_bounds__(256) void gmfma10(
    const short* __restrict__ fA, const short* __restrict__ fB,
    const int* __restrict__ nbr, const short* __restrict__ Wf,
    short* __restrict__ out, float* __restrict__ pstat,
    const float* __restrict__ abp, int N) {
    static_assert(K % G == 0, "G must divide K");
    static_assert(!FACT || CI2 == 0, "fused act only for single input");
    constexpr int NT  = COUT / 16;
    constexpr int NC1 = CI1 / 32;
    constexpr int NC2 = CI2 / 32;
    constexpr int NCH = (CI1 + CI2) / 32;
    constexpr int PANEL = NCH * NT * 512;
    constexpr int GSH   = G * PANEL;
    constexpr int NPH   = K / G;
    constexpr int WCH   = GSH / 4;
    constexpr int S16   = (WCH * 2) / 1024;
    constexpr int S4    = ((WCH * 2) % 1024) / 256;
    __shared__ __attribute__((aligned(16))) short sB[GSH];
    const int tid  = threadIdx.x;
    const int lane = tid & 63;
    const int wid  = tid >> 6;
    const int m    = lane & 15;
    const int quad = lane >> 4;
    const long long tb0 = ((long long)blockIdx.x * 4 + wid) * (MT * 16);

    f32x4 acc[MT][NT];
#pragma unroll
    for (int mt = 0; mt < MT; mt++)
#pragma unroll
        for (int t = 0; t < NT; t++) acc[mt][t] = (f32x4)0.f;

#define STAGE(ph)                                                              \
    {                                                                          \
        const short* _src = Wf + (size_t)(ph) * GSH + wid * WCH;               \
        short* _dst = &sB[wid * WCH];                                          \
        _Pragma("unroll")                                                      \
        for (int i = 0; i < S16; i++)                                          \
            __builtin_amdgcn_global_load_lds(                                  \
                (gas_short*)(_src + i * 512 + lane * 8),                       \
                (las_short*)(_dst + i * 512), 16, 0, 0);                       \
        _Pragma("unroll")                                                      \
        for (int i = 0; i < S4; i++)                                           \
            __builtin_amdgcn_global_load_lds(                                  \
                (gas_short*)(_src + S16 * 512 + i * 128 + lane * 2),           \
                (las_short*)(_dst + S16 * 512 + i * 128), 4, 0, 0);            \
    }

    STAGE(0)
    __builtin_amdgcn_sched_barrier(0);

    int idxs[MT][K];
#pragma unroll
    for (int mt = 0; mt < MT; mt++) {
        long long r = tb0 + mt * 16 + m;
        bool rv = r < N;
#pragma unroll
        for (int k = 0; k < K; k++)
            idxs[mt][k] = rv ? nbr[r * K + k] : -1;
    }
    unsigned pmask[MT];
#pragma unroll
    for (int mt = 0; mt < MT; mt++) {
        unsigned pm = 0;
#pragma unroll
        for (int k = 0; k < K; k++)
            pm |= __any(idxs[mt][k] >= 0) ? (1u << k) : 0u;
        pmask[mt] = __builtin_amdgcn_readfirstlane(pm);
    }

    float aS[FACT ? NC1 * 8 : 1], aBb[FACT ? NC1 * 8 : 1];
    if constexpr (FACT) {
#pragma unroll
        for (int c = 0; c < NC1; c++)
#pragma unroll
            for (int jj = 0; jj < 8; jj++) {
                int ch = c * 32 + quad * 8 + jj;
                aS[c * 8 + jj]  = abp[ch];
                aBb[c * 8 + jj] = abp[CI1 + ch];
            }
    }

    __builtin_amdgcn_sched_barrier(0);
    asm volatile("s_waitcnt vmcnt(0)" ::: "memory");
    __builtin_amdgcn_s_barrier();
    __builtin_amdgcn_sched_barrier(0);
    asm volatile("" ::: "memory");

    short8 S[3][NCH];

#define LOADS(sl, mt, kk)                                                      \
    {                                                                          \
        int _i = idxs[mt][kk];                                                 \
        long long _j = _i < 0 ? 0 : _i;                                        \
        _Pragma("unroll")                                                      \
        for (int c = 0; c < NC1; c++) {                                        \
            short8 _v = *reinterpret_cast<const short8*>(                      \
                fA + _j * CI1 + c * 32 + quad * 8);                            \
            if constexpr (FACT) {                                              \
                short8 _o;                                                     \
                _Pragma("unroll")                                              \
                for (int jj = 0; jj < 8; jj++) {                               \
                    float _f = b2f(_v[jj]) * aS[c * 8 + jj] + aBb[c * 8 + jj]; \
                    _o[jj] = f2b(_f > 0.f ? _f : 0.f);                         \
                }                                                              \
                _v = _o;                                                       \
            }                                                                  \
            S[sl][c] = (_i >= 0) ? _v : (short8)0;                             \
        }                                                                      \
        if constexpr (NC2 > 0) {                                               \
            _Pragma("unroll")                                                  \
            for (int c = 0; c < NC2; c++) {                                    \
                short8 _v = *reinterpret_cast<const short8*>(                  \
                    fB + _j * CI2 + c * 32 + quad * 8);                        \
                S[sl][NC1 + c] = (_i >= 0) ? _v : (short8)0;                   \
            }                                                                  \
        }                                                                      \
    }
#define MFMAS(sl, mt, jl)                                                      \
    {                                                                          \
        _Pragma("unroll")                                                      \
        for (int c = 0; c < NCH; c++) {                                        \
            _Pragma("unroll")                                                  \
            for (int t = 0; t < NT; t++) {                                     \
                short8 b = *reinterpret_cast<const short8*>(                   \
                    &sB[((jl) * NCH * NT + c * NT + t) * 512 + lane * 8]);     \
                acc[mt][t] = __builtin_amdgcn_mfma_f32_16x16x32_bf16(          \
                    S[sl][c], b, acc[mt][t], 0, 0, 0);                         \
            }                                                                  \
        }                                                                      \
    }

#pragma unroll
    for (int ph = 0; ph < NPH; ph++) {
#pragma unroll
        for (int mt = 0; mt < MT; mt++) {
            const unsigned mm = (pmask[mt] >> (ph * G)) & ((1u << G) - 1);
#pragma unroll
            for (int j = 0; j < G + 2; j++) {
                if (j < G)
                    if (mm & (1u << j)) LOADS(j % 3, mt, ph * G + j)
                if (j >= 2)
                    if (mm & (1u << (j - 2))) MFMAS((j - 2) % 3, mt, j - 2)
            }
        }
        if (ph + 1 < NPH) {
            __builtin_amdgcn_sched_barrier(0);
            asm volatile("s_waitcnt lgkmcnt(0)" ::: "memory");
            __builtin_amdgcn_s_barrier();
            __builtin_amdgcn_sched_barrier(0);
            STAGE(ph + 1)
            __builtin_amdgcn_sched_barrier(0);
            asm volatile("s_waitcnt vmcnt(0)" ::: "memory");
            __builtin_amdgcn_s_barrier();
            __builtin_amdgcn_sched_barrier(0);
            asm volatile("" ::: "memory");
        }
    }
#undef LOADS
#undef MFMAS
#undef STAGE
    float s[NT], q[NT];
#pragma unroll
    for (int t = 0; t < NT; t++) { s[t] = 0.f; q[t] = 0.f; }
#pragma unroll
    for (int mt = 0; mt < MT; mt++) {
#pragma unroll
        for (int g4 = 0; g4 < 4; g4++) {
            long long sr = tb0 + mt * 16 + quad * 4 + g4;
            if (sr < N) {
#pragma unroll
                for (int t = 0; t < NT; t++) {
                    float v = acc[mt][t][g4];
                    out[sr * COUT + t * 16 + m] = f2b(v);
                    s[t] += v; q[t] += v * v;
                }
            }
        }
    }
    float* pb = pstat + (blockIdx.x & 7) * 2 * COUT;
#pragma unroll
    for (int t = 0; t < NT; t++) {
        float sv = s[t], qv = q[t];
        sv += __shfl_xor(sv, 16); qv += __shfl_xor(qv, 16);
        sv += __shfl_xor(sv, 32); qv += __shfl_xor(qv, 32);
        if (quad == 0) {
            atomicAdd(&pb[t * 16 + m], sv);
            atomicAdd(&pb[COUT + t * 16 + m], qv);
        }
    }
}

// ---------- MFMA up conv v10 (R25, unchanged) ------------------------------
template<int CIN, int COUT, int G>
__global__ __launch_bounds__(256) void upmfma10(
    const short* __restrict__ f, const int* __restrict__ rb,
    const short* __restrict__ Wf, short* __restrict__ out,
    float* __restrict__ pstat, const float* __restrict__ abp, int N) {
    static_assert(8 % G == 0, "G must divide 8");
    constexpr int NT = COUT / 16;
    constexpr int NK = CIN / 32;
    constexpr int PANEL = NK * NT * 512;
    constexpr int GSH   = G * PANEL;
    constexpr int NPH   = 8 / G;
    constexpr int WCH   = GSH / 4;
    constexpr int S16   = (WCH * 2) / 1024;
    constexpr int S4    = ((WCH * 2) % 1024) / 256;
    __shared__ __attribute__((aligned(16))) short sB[GSH];
    const int tid  = threadIdx.x;
    const int lane = tid & 63;
    const int wid  = tid >> 6;
    const int m    = lane & 15;
    const int quad = lane >> 4;
    const long long row0 = ((long long)blockIdx.x * 4 + wid) * 16;
    const long long r = row0 + m;
    const bool rv = r < N;
    const long long rc = rv ? r : 0;

#define STAGE(ph)                                                              \
    {                                                                          \
        const short* _src = Wf + (size_t)(ph) * GSH + wid * WCH;               \
        short* _dst = &sB[wid * WCH];                                          \
        _Pragma("unroll")                                                      \
        for (int i = 0; i < S16; i++)                                          \
            __builtin_amdgcn_global_load_lds(                                  \
                (gas_short*)(_src + i * 512 + lane * 8),                       \
                (las_short*)(_dst + i * 512), 16, 0, 0);                       \
        _Pragma("unroll")                                                      \
        for (int i = 0; i < S4; i++)                                           \
            __builtin_amdgcn_global_load_lds(                                  \
                (gas_short*)(_src + S16 * 512 + i * 128 + lane * 2),           \
                (las_short*)(_dst + S16 * 512 + i * 128), 4, 0, 0);            \
    }
    STAGE(0)
    __builtin_amdgcn_sched_barrier(0);

    short8 af[NK];
#pragma unroll
    for (int kc = 0; kc < NK; kc++) {
        short8 v = *reinterpret_cast<const short8*>(
            f + rc * CIN + kc * 32 + quad * 8);
        short8 o;
#pragma unroll
        for (int jj = 0; jj < 8; jj++) {
            int ch = kc * 32 + quad * 8 + jj;
            float u = b2f(v[jj]) * abp[ch] + abp[CIN + ch];
            o[jj] = f2b(u > 0.f ? u : 0.f);
        }
        af[kc] = rv ? o : (short8)0;
    }
    int sidx[8][4];
#pragma unroll
    for (int g4 = 0; g4 < 4; g4++) {
        long long sr = row0 + quad * 4 + g4;
#pragma unroll
        for (int k = 0; k < 8; k++)
            sidx[k][g4] = (sr < N) ? rb[sr * 8 + k] : -1;
    }
    unsigned pm = 0;
#pragma unroll
    for (int k = 0; k < 8; k++) {
        int anyv = (sidx[k][0] >= 0) | (sidx[k][1] >= 0) |
                   (sidx[k][2] >= 0) | (sidx[k][3] >= 0);
        pm |= __any(anyv) ? (1u << k) : 0u;
    }
    pm = __builtin_amdgcn_readfirstlane(pm);

    float s[NT], q[NT];
#pragma unroll
    for (int t = 0; t < NT; t++) { s[t] = 0.f; q[t] = 0.f; }

    __builtin_amdgcn_sched_barrier(0);
    asm volatile("s_waitcnt vmcnt(0)" ::: "memory");
    __builtin_amdgcn_s_barrier();
    __builtin_amdgcn_sched_barrier(0);
    asm volatile("" ::: "memory");

#pragma unroll
    for (int ph = 0; ph < NPH; ph++) {
#pragma unroll
        for (int j = 0; j < G; j++) {
            const int k = ph * G + j;
            if (pm & (1u << k)) {
                f32x4 acc[NT];
#pragma unroll
                for (int t = 0; t < NT; t++) acc[t] = (f32x4)0.f;
#pragma unroll
                for (int kc = 0; kc < NK; kc++) {
#pragma unroll
                    for (int t = 0; t < NT; t++) {
                        short8 b = *reinterpret_cast<const short8*>(
                            &sB[(j * NK * NT + kc * NT + t) * 512 + lane * 8]);
                        acc[t] = __builtin_amdgcn_mfma_f32_16x16x32_bf16(
                            af[kc], b, acc[t], 0, 0, 0);
                    }
                }
#pragma unroll
                for (int g4 = 0; g4 < 4; g4++) {
                    if (sidx[k][g4] >= 0) {
#pragma unroll
                        for (int t = 0; t < NT; t++) {
                            float v = acc[t][g4];
                            out[(long long)sidx[k][g4] * COUT + t * 16 + m] =
                                f2b(v);
                            s[t] += v; q[t] += v * v;
                        }
                    }
                }
            }
        }
        if (ph + 1 < NPH) {
            __builtin_amdgcn_sched_barrier(0);
            asm volatile("s_waitcnt lgkmcnt(0)" ::: "memory");
            __builtin_amdgcn_s_barrier();
            __builtin_amdgcn_sched_barrier(0);
            STAGE(ph + 1)
            __builtin_amdgcn_sched_barrier(0);
            asm volatile("s_waitcnt vmcnt(0)" ::: "memory");
            __builtin_amdgcn_s_barrier();
            __builtin_amdgcn_sched_barrier(0);
            asm volatile("" ::: "memory");
        }
    }
#undef STAGE
    float* pb = pstat + (blockIdx.x & 7) * 2 * COUT;
#pragma unroll
    for (int t = 0; t < NT; t++) {
        float sv = s[t], qv = q[t];
        sv += __shfl_xor(sv, 16); qv += __shfl_xor(qv, 16);
        sv += __shfl_xor(sv, 32); qv += __shfl_xor(qv, 32);
        if (quad == 0) {
            atomicAdd(&pb[t * 16 + m], sv);
            atomicAdd(&pb[COUT + t * 16 + m], qv);
        }
    }
}

// ---------- BN stats (only for conv_in's output), f64 deterministic --------
template<int C>
__global__ void bn_stats(const short* __restrict__ x, double* __restrict__ part, int N) {
    constexpr int GR  = C / 8;
    constexpr int RPB = 256 / GR;
    constexpr int ACTIVE = GR * RPB;
    __shared__ double ls[256 * 8];
    __shared__ double lq[256 * 8];
    const int tid = threadIdx.x;
    const int g   = tid % GR;
    const int rr  = tid / GR;
    double s[8], q[8];
#pragma unroll
    for (int j = 0; j < 8; j++) { s[j] = 0.0; q[j] = 0.0; }
    if (tid < ACTIVE) {
        for (long long r = (long long)blockIdx.x * RPB + rr; r < N;
             r += (long long)gridDim.x * RPB) {
            short8 v = *reinterpret_cast<const short8*>(x + r * C + g * 8);
#pragma unroll
            for (int j = 0; j < 8; j++) {
                double f = (double)b2f(v[j]);
                s[j] += f; q[j] += f * f;
            }
        }
    }
#pragma unroll
    for (int j = 0; j < 8; j++) { ls[tid * 8 + j] = s[j]; lq[tid * 8 + j] = q[j]; }
    __syncthreads();
    if (tid < C) {
        int gg = tid / 8, jj = tid % 8;
        double S = 0.0, Q = 0.0;
        for (int r2 = 0; r2 < RPB; r2++) {
            S += ls[(r2 * GR + gg) * 8 + jj];
            Q += lq[(r2 * GR + gg) * 8 + jj];
        }
        part[blockIdx.x * 256 + tid]       = S;
        part[blockIdx.x * 256 + 128 + tid] = Q;
    }
}

__global__ void bn_fin(const double* __restrict__ part, const float* __restrict__ gb,
                       int gbfull, int goff, float* __restrict__ ab,
                       int C, int P, double invN) {
    __shared__ double ss[256], sq[256];
    const int tid = threadIdx.x;
    const int c   = tid % C;
    const int g   = tid / C;
    const int G   = 256 / C;
    double s = 0.0, q = 0.0;
    if (g < G) {
        for (int p = g; p < P; p += G) {
            s += part[p * 256 + c];
            q += part[p * 256 + 128 + c];
        }
    }
    ss[tid] = s; sq[tid] = q;
    __syncthreads();
    if (tid < C) {
        for (int j = 1; j < G; j++) { s += ss[j * C + c]; q += sq[j * C + c]; }
        double mu  = s * invN;
        double var = q * invN - mu * mu;
        double a   = (double)gb[goff + c] / sqrt(var + 1e-4);
        ab[c]     = (float)a;
        ab[C + c] = (float)((double)gb[gbfull + goff + c] - mu * a);
    }
}

// ---------- bn_fin_a: reduce 8 atomic banks -> ab --------------------------
__global__ void bn_fin_a(const float* __restrict__ pst, const float* __restrict__ gb,
                         int gbfull, int goff, float* __restrict__ ab,
                         int C, double invN) {
    int c = threadIdx.x;
    if (c >= C) return;
    double s = 0.0, q = 0.0;
#pragma unroll
    for (int b = 0; b < 8; b++) {
        s += (double)pst[b * 2 * C + c];
        q += (double)pst[b * 2 * C + C + c];
    }
    double mu  = s * invN;
    double var = q * invN - mu * mu;
    double a   = (double)gb[goff + c] / sqrt(var + 1e-4);
    ab[c]     = (float)a;
    ab[C + c] = (float)((double)gb[gbfull + goff + c] - mu * a);
}

// ---------- bnact: y = relu(x*a + b), bf16 -> bf16, 8 elems/thread ---------
template<int C>
__global__ void bnact(const short* __restrict__ x, const float* __restrict__ ab,
                      short* __restrict__ y, long long total8) {
    long long i = (long long)blockIdx.x * blockDim.x + threadIdx.x;
    if (i >= total8) return;
    long long base = i * 8;
    int c0 = (int)(base % C);
    short8 v = *reinterpret_cast<const short8*>(x + base);
    short8 o;
#pragma unroll
    for (int j = 0; j < 8; j++) {
        float f = b2f(v[j]) * ab[c0 + j] + ab[C + c0 + j];
        o[j] = f2b(f > 0.f ? f : 0.f);
    }
    *reinterpret_cast<short8*>(y + base) = o;
}

// ---------- bnact2: two tensors in one launch ------------------------------
template<int C>
__global__ void bnact2(const short* __restrict__ xa, const float* __restrict__ aba,
                       short* __restrict__ ya,
                       const short* __restrict__ xb, const float* __restrict__ abb,
                       short* __restrict__ yb, long long n8) {
    long long i = (long long)blockIdx.x * blockDim.x + threadIdx.x;
    if (i >= 2 * n8) return;
    const short* x; const float* ab; short* y; long long ii;
    if (i < n8) { x = xa; ab = aba; y = ya; ii = i; }
    else        { x = xb; ab = abb; y = yb; ii = i - n8; }
    long long base = ii * 8;
    int c0 = (int)(base % C);
    short8 v = *reinterpret_cast<const short8*>(x + base);
    short8 o;
#pragma unroll
    for (int j = 0; j < 8; j++) {
        float f = b2f(v[j]) * ab[c0 + j] + ab[C + c0 + j];
        o[j] = f2b(f > 0.f ? f : 0.f);
    }
    *reinterpret_cast<short8*>(y + base) = o;
}

// ---------- final linear (bnf fused), bf16 in, f32 out ---------------------
__global__ void final_k(const short* __restrict__ x, const float* __restrict__ ab,
                        const float* __restrict__ lw, const float* __restrict__ lb,
                        float* __restrict__ out, int N) {
    long long r = (long long)blockIdx.x * blockDim.x + threadIdx.x;
    if (r >= N) return;
    float a0 = lb[0], a1 = lb[1];
#pragma unroll
    for (int j = 0; j < 4; j++) {
        short8 v = *reinterpret_cast<const short8*>(x + r * 32 + j * 8);
#pragma unroll
        for (int t = 0; t < 8; t++) {
            int ci = 8 * j + t;
            float u = b2f(v[t]) * ab[ci] + ab[32 + ci];
            u = u > 0.f ? u : 0.f;
            a0 += u * lw[ci * 2];
            a1 += u * lw[ci * 2 + 1];
        }
    }
    out[2 * r]     = a0;
    out[2 * r + 1] = a1;
}

extern "C" void kernel_launch(void* const* d_in, const int* in_sizes, int n_in,
                              void* d_out, int out_size, void* d_ws, size_t ws_size,
                              hipStream_t stream) {
    const long long N0 = in_sizes[0] / 3;
    const long long N1 = in_sizes[26] / 8;
    const long long N2 = in_sizes[27] / 8;
    const int P = 256;

    const float* feat = (const float*)d_in[0];
    const int* nbr0 = (const int*)d_in[23];
    const int* nbr1 = (const int*)d_in[24];
    const int* nbr2 = (const int*)d_in[25];
    const int* rb0  = (const int*)d_in[26];
    const int* rb1  = (const int*)d_in[27];

    // ---- arena ----
    char* p = (char*)d_ws;
    double* part = (double*)p;            p += (size_t)P * 256 * 8;     // 512 KB
    float*  ab   = (float*)p;             p += 12 * 256 * 4;
    float*  pst  = (float*)p;             p += (size_t)10 * 2048 * 4;
    unsigned* msk0 = (unsigned*)p;        p += ((size_t)N0 * 4 + 63) & ~(size_t)63;
    const int wLayer[9] = {3, 5, 7, 9, 11, 13, 15, 17, 19};
    const int wK[9]  = {27, 8, 27, 8, 27, 8, 27, 8, 27};
    const int wCI[9] = {32, 32, 64, 64, 96, 96, 128, 64, 64};
    const int wCO[9] = {32, 64, 64, 96, 96, 64, 64, 32, 32};
    short* wt[9];
    WPA wpa;
    int cum = 0;
    for (int i = 0; i < 9; i++) {
        wt[i] = (short*)p;
        int n = wK[i] * wCI[i] * wCO[i];
        p += (((size_t)n * 2 + 63) & ~(size_t)63);
        wpa.src[i] = (const float*)d_in[wLayer[i]];
        wpa.dst[i] = wt[i];
        wpa.CI[i] = wCI[i]; wpa.CO[i] = wCO[i];
        wpa.cum[i] = cum; cum += n;
    }
    wpa.cum[9] = cum;
    auto balloc = [&](long long elems) {
        short* q = (short*)p;
        p += (((size_t)elems * 2 + 63) & ~(size_t)63);
        return q;
    };
    short* R0 = balloc(N0 * 32);   // t0 / d0 / d1 / u1 / u0 (raw)
    short* R1 = balloc(N0 * 32);   // x0 raw (persist)
    short* R2 = balloc(N1 * 64);   // x1 raw (persist)
    short* R3 = balloc(N0 * 32);   // x2 / y1 / y0 (raw)
    short* Xb = balloc(N0 * 32);   // act out #1
    short* Yb = balloc(N0 * 32);   // act out #2

    wprep_all<<<(cum + 255) / 256, 256, 0, stream>>>(wpa, cum);
    zerok<<<(10 * 2048 + 255) / 256, 256, 0, stream>>>(pst, 10 * 2048);
    nbrmask_k<<<(int)((N0 + 255) / 256), 256, 0, stream>>>(nbr0, msk0, (int)N0);

#define AB(SL) (ab + (SL) * 256)
#define PS(SL) (pst + (SL) * 2048)
#define FINA(PSL, GBI, GBFULL, GOFF, SL, CH, NN)                                     \
    bn_fin_a<<<1, 128, 0, stream>>>(PS(PSL), (const float*)d_in[GBI], GBFULL, GOFF,  \
                                    AB(SL), CH, 1.0 / (double)(NN))
#define GB1(N_) (int)(((N_) + 63) / 64)
#define GB2(N_) (int)(((N_) + 127) / 128)

    // ---- level 0 ----
    conv_in_st<<<(int)((N0 + 255) / 256), 256, 0, stream>>>(
        feat, msk0, (const float*)d_in[1], R0, (int)N0);                  // t0 -> R0
    bn_stats<32><<<P, 256, 0, stream>>>(R0, part, (int)N0);               // bn1_0
    bn_fin<<<1, 256, 0, stream>>>(part, (const float*)d_in[2], 32, 0,
                                  AB(0), 32, P, 1.0 / (double)N0);
    stencil0<32, 0, 32><<<GB2(N0), 256, 0, stream>>>(
        R0, nullptr, msk0, wt[0], R1, PS(0), AB(0), nullptr, (int)N0);    // x0 -> R1
    FINA(0, 4, 32, 0, 1, 32, N0);                                         // bnd_0
    FINA(0, 18, 64, 0, 9, 32, N0);                                        // bn2_0[x0]
    gmfma10<32, 0, 64, 8, 8, 2, true><<<GB2(N1), 256, 0, stream>>>(
        R1, nullptr, rb0, wt[1], R0, PS(1), AB(1), (int)N1);              // d0 -> R0
    FINA(1, 6, 64, 0, 2, 64, N1);                                         // bn1_1

    // ---- level 1 ----
    bnact<64><<<(int)((N1 * 64 / 8 + 255) / 256), 256, 0, stream>>>(
        R0, AB(2), Xb, N1 * 64 / 8);
    gmfma10<64, 0, 64, 27, 3, 2, false><<<GB2(N1), 256, 0, stream>>>(
        Xb, nullptr, nbr1, wt[2], R2, PS(2), nullptr, (int)N1);           // x1 -> R2
    FINA(2, 8, 64, 0, 3, 64, N1);                                         // bnd_1
    FINA(2, 14, 128, 0, 6, 64, N1);                                       // bn2_1[x1]
    gmfma10<64, 0, 96, 8, 2, 1, true><<<GB1(N2), 256, 0, stream>>>(
        R2, nullptr, rb1, wt[3], R0, PS(3), AB(3), (int)N2);              // d1 -> R0
    FINA(3, 10, 96, 0, 4, 96, N2);                                        // bn1_2

    // ---- level 2 ----
    bnact<96><<<(int)((N2 * 96 / 8 + 255) / 256), 256, 0, stream>>>(
        R0, AB(4), Xb, N2 * 96 / 8);
    gmfma10<96, 0, 96, 27, 3, 1, false><<<GB1(N2), 256, 0, stream>>>(
        Xb, nullptr, nbr2, wt[4], R3, PS(4), nullptr, (int)N2);           // x2 -> R3
    FINA(4, 12, 96, 0, 5, 96, N2);                                        // bnu_1

    // ---- up to level 1 ----
    upmfma10<96, 64, 2><<<GB1(N2), 256, 0, stream>>>(
        R3, rb1, wt[5], R0, PS(5), AB(5), (int)N2);                       // u1 -> R0
    FINA(5, 14, 128, 64, 7, 64, N1);                                      // bn2_1[u1]
    bnact2<64><<<(int)((2 * (N1 * 64 / 8) + 255) / 256), 256, 0, stream>>>(
        R2, AB(6), Xb, R0, AB(7), Yb, N1 * 64 / 8);
    gmfma10<64, 64, 64, 27, 3, 2, false><<<GB2(N1), 256, 0, stream>>>(
        Xb, Yb, nbr1, wt[6], R3, PS(6), nullptr, (int)N1);                // y1 -> R3
    FINA(6, 16, 64, 0, 8, 64, N1);                                        // bnu_0

    // ---- up to level 0 ----
    upmfma10<64, 32, 4><<<GB1(N1), 256, 0, stream>>>(
        R3, rb0, wt[7], R0, PS(7), AB(8), (int)N1);                       // u0 -> R0
    FINA(7, 18, 64, 32, 10, 32, N0);                                      // bn2_0[u0]
    stencil0<32, 32, 32><<<GB2(N0), 256, 0, stream>>>(
        R1, R0, msk0, wt[8], R3, PS(8), AB(9), AB(10), (int)N0);          // y0 -> R3
    FINA(8, 20, 32, 0, 11, 32, N0);                                       // bnf

    final_k<<<(int)((N0 + 255) / 256), 256, 0, stream>>>(
        R3, AB(11), (const float*)d_in[21], (const float*)d_in[22],
        (float*)d_out, (int)N0);

#undef AB
#undef PS
#undef FINA
#undef GB1
#undef GB2
}

// Round 15
// 536.645 us; speedup vs baseline: 1.2699x; 1.0375x over previous
//
#include <hip/hip_runtime.h>
#include <hip/hip_bf16.h>

// ---------------------------------------------------------------------------
// Sparse 3-level U-Net — Round 31: inline BN-finalize (launch-count cut).
// R30 (556.8us, best): conv structure final; x1/y1 ~76us resist 8 variants.
// Remaining tax: ~30 launches, 12 of them 1-block FINA kernels on the
// critical path (~2-4us gap each = 30-45us serialization).
// R31: consumers recompute (a,b) from pst 8-bank sums inline (first C
// threads, f64 identical to bn_fin_a -> bit-identical), LDS + 1 barrier.
// Launches 30 -> 18. zerok merged into nbrmask. bn_fin kept only for
// conv_in's f64 stats path (stencil0 x0 takes direct-ab).
// Baseline R30: 556.8us. Prediction: 515-535us.
// ---------------------------------------------------------------------------

typedef __hip_bfloat16 hbf;
typedef __attribute__((ext_vector_type(8))) short short8;
typedef __attribute__((ext_vector_type(4))) float f32x4;
typedef const __attribute__((address_space(1))) short gas_short;
typedef __attribute__((address_space(3))) short las_short;

__device__ inline float b2f(short s) {
    unsigned u = ((unsigned)(unsigned short)s) << 16;
    float f; __builtin_memcpy(&f, &u, 4); return f;
}
__device__ inline short f2b(float f) {
    hbf h = __float2bfloat16(f);
    short s; __builtin_memcpy(&s, &h, 2); return s;
}

// ---------- inline BN finalize params --------------------------------------
struct BNP {
    const float* pst;   // 8-bank sums (or null -> use abd)
    const float* abd;   // precomputed ab (used if pst == null)
    const float* gb;    // gamma/beta (2,C') flattened
    int gbfull, goff;
    double invN;
};
// first C threads fill lab[0..2C): a then b. Bit-identical to bn_fin_a.
__device__ inline void bn_load(const BNP& p, int C, float* lab, int tid) {
    if (tid < C) {
        if (p.pst) {
            double s = 0.0, q = 0.0;
#pragma unroll
            for (int b = 0; b < 8; b++) {
                s += (double)p.pst[b * 2 * C + tid];
                q += (double)p.pst[b * 2 * C + C + tid];
            }
            double mu  = s * p.invN;
            double var = q * p.invN - mu * mu;
            double a   = (double)p.gb[p.goff + tid] / sqrt(var + 1e-4);
            lab[tid]     = (float)a;
            lab[C + tid] = (float)((double)p.gb[p.gbfull + p.goff + tid] - mu * a);
        } else {
            lab[tid]     = p.abd[tid];
            lab[C + tid] = p.abd[C + tid];
        }
    }
}

// ---------- weight prep: all 9 layers in one launch ------------------------
struct WPA {
    const float* src[9];
    short* dst[9];
    int CI[9], CO[9];
    int cum[10];
};
__global__ __launch_bounds__(256) void wprep_all(WPA a, int total) {
    int e0 = blockIdx.x * 256 + threadIdx.x;
    if (e0 >= total) return;
    int L = 0;
#pragma unroll
    for (int i = 1; i < 9; i++) L += (e0 >= a.cum[i]) ? 1 : 0;
    int e = e0 - a.cum[L];
    int CI = a.CI[L], CO = a.CO[L];
    int NT = CO >> 4, NCH = CI >> 5;
    int j    = e & 7;
    int lane = (e >> 3) & 63;
    int t    = (e >> 9) % NT;
    int c    = (e / (512 * NT)) % NCH;
    int k    = e / (512 * NT * NCH);
    int ci = c * 32 + (lane >> 4) * 8 + j;
    int co = t * 16 + (lane & 15);
    a.dst[L][e] = f2b(a.src[L][((long long)k * CI + ci) * CO + co]);
}

// ---------- presence mask from nbr0 + zero the atomic-stats slots ----------
__global__ __launch_bounds__(256) void nbrmask_k(const int* __restrict__ nbr,
                                                 unsigned* __restrict__ msk,
                                                 float* __restrict__ pst, int N) {
    long long r = (long long)blockIdx.x * 256 + threadIdx.x;
    if (r < 10 * 2048) pst[r] = 0.f;
    if (r >= N) return;
    unsigned mv = 0;
#pragma unroll
    for (int k = 0; k < 27; k++)
        mv |= (nbr[r * 27 + k] >= 0) ? (1u << k) : 0u;
    msk[r] = mv;
}

// ---------- input conv, STENCILIZED (dense level-0 grid) -------------------
__global__ __launch_bounds__(256) void conv_in_st(
    const float* __restrict__ feat, const unsigned* __restrict__ msk,
    const float* __restrict__ W, short* __restrict__ out, int N) {
    __shared__ float sW[27 * 96];
    __shared__ float sF[3][258][3];
    const int tid = threadIdx.x;
    const int bid = blockIdx.x;
    const int xq     = bid >> 1;
    const int ystart = (bid & 1) << 8;
    const long long R = (long long)bid * 256;

    for (int e = tid; e < 27 * 96; e += 256) sW[e] = W[e];
    for (int e = tid; e < 3 * 258; e += 256) {
        int rr = e % 258, st = e / 258;
        long long gr = (long long)(xq - 1 + st) * 512 + (ystart - 1 + rr);
        long long grc = (gr < 0 || gr >= N) ? 0 : gr;
        sF[st][rr][0] = feat[grc * 3];
        sF[st][rr][1] = feat[grc * 3 + 1];
        sF[st][rr][2] = feat[grc * 3 + 2];
    }
    __syncthreads();

    long long r = R + tid;
    unsigned mv = (r < N) ? msk[r] : 0u;
    float acc[32];
#pragma unroll
    for (int c = 0; c < 32; c++) acc[c] = 0.f;
#pragma unroll
    for (int k = 0; k < 27; k++) {
        if (mv & (1u << k)) {
            const int st = k / 9;
            const int dy = (k / 3) % 3 - 1;
            const int rl = 1 + tid + dy;
            float f0 = sF[st][rl][0];
            float f1 = sF[st][rl][1];
            float f2 = sF[st][rl][2];
            const float* w = sW + k * 96;
#pragma unroll
            for (int c = 0; c < 32; c++)
                acc[c] += f0 * w[c] + f1 * w[32 + c] + f2 * w[64 + c];
        }
    }
    if (r < N) {
#pragma unroll
        for (int c = 0; c < 32; c++) out[r * 32 + c] = f2b(acc[c]);
    }
}

// ---------- stencil conv for level 0, inline BN ----------------------------
template<int CI1, int CI2, int COUT>
__global__ __launch_bounds__(256) void stencil0(
    const short* __restrict__ fA, const short* __restrict__ fB,
    const unsigned* __restrict__ msk, const short* __restrict__ Wf,
    short* __restrict__ out, float* __restrict__ pstat,
    BNP pA, BNP pB, int N) {
    constexpr int CIT  = CI1 + CI2;
    constexpr int NCH  = CIT / 32;
    constexpr int NT   = COUT / 16;
    constexpr int MT   = 2;
    constexpr int CIB  = CIT * 2;
    constexpr int ROWS = 130;
    constexpr int NC8  = CIT / 8;
    constexpr int SWB  = (CIB >= 128) ? 7 : 3;
    __shared__ __attribute__((aligned(16))) char sA[3 * ROWS * CIB];
    __shared__ float labA[2 * CI1];
    __shared__ float labB[CI2 > 0 ? 2 * CI2 : 1];
    const int tid  = threadIdx.x;
    const int lane = tid & 63;
    const int wid  = tid >> 6;
    const int m    = lane & 15;
    const int quad = lane >> 4;
    const int bid  = blockIdx.x;
    const int xq     = bid >> 2;
    const int ystart = (bid & 3) << 7;
    const long long R = (long long)bid * 128;

    bn_load(pA, CI1, labA, tid);
    if constexpr (CI2 > 0) bn_load(pB, CI2, labB, tid);
    __syncthreads();

    {
        const int c8 = tid % NC8;
        const bool isA = (c8 * 8) < CI1;
        const short* src  = isA ? fA : fB;
        const float* lab  = isA ? labA : labB;
        const int   srcCI = isA ? CI1 : CI2;
        const int   chb   = isA ? c8 * 8 : c8 * 8 - CI1;
        float s_[8], b_[8];
#pragma unroll
        for (int jj = 0; jj < 8; jj++) {
            s_[jj] = lab[chb + jj];
            b_[jj] = lab[srcCI + chb + jj];
        }
        for (int e = tid; e < 3 * ROWS * NC8; e += 256) {
            int rr = (e / NC8) % ROWS;
            int st = e / (NC8 * ROWS);
            long long gr = (long long)(xq - 1 + st) * 512 + (ystart - 1 + rr);
            long long grc = (gr < 0 || gr >= N) ? 0 : gr;
            short8 v = *reinterpret_cast<const short8*>(src + grc * srcCI + chb);
            short8 o;
#pragma unroll
            for (int jj = 0; jj < 8; jj++) {
                float f = b2f(v[jj]) * s_[jj] + b_[jj];
                o[jj] = f2b(f > 0.f ? f : 0.f);
            }
            int byte = (st * ROWS + rr) * CIB + c8 * 16;
            byte ^= ((rr & SWB) << 4);
            *reinterpret_cast<short8*>(sA + byte) = o;
        }
    }
    __syncthreads();

    f32x4 acc[MT][NT];
#pragma unroll
    for (int mt = 0; mt < MT; mt++)
#pragma unroll
        for (int t = 0; t < NT; t++) acc[mt][t] = (f32x4)0.f;

    unsigned mv[MT];
#pragma unroll
    for (int mt = 0; mt < MT; mt++) {
        long long r = R + wid * 32 + mt * 16 + m;
        mv[mt] = (r < N) ? msk[r] : 0u;
    }

#pragma unroll
    for (int s9 = 0; s9 < 9; s9++) {
        const int st = s9 / 3;
        const int dy = s9 % 3 - 1;
        short8 a[MT][NCH];
#pragma unroll
        for (int mt = 0; mt < MT; mt++) {
            int rl = 1 + wid * 32 + mt * 16 + m + dy;
#pragma unroll
            for (int c = 0; c < NCH; c++) {
                int byte = (st * ROWS + rl) * CIB + (c * 4 + quad) * 16;
                byte ^= ((rl & SWB) << 4);
                a[mt][c] = *reinterpret_cast<const short8*>(sA + byte);
            }
        }
#pragma unroll
        for (int z3 = 0; z3 < 3; z3++) {
            const int k = s9 * 3 + z3;
            unsigned anyb = (mv[0] >> k) & 1;
            if (MT > 1) anyb |= (mv[1] >> k) & 1;
            if (__any(anyb)) {
                short8 bf[NCH][NT];
#pragma unroll
                for (int c = 0; c < NCH; c++)
#pragma unroll
                    for (int t = 0; t < NT; t++)
                        bf[c][t] = *reinterpret_cast<const short8*>(
                            Wf + ((size_t)(k * NCH + c) * NT + t) * 512 + lane * 8);
#pragma unroll
                for (int mt = 0; mt < MT; mt++) {
                    const bool bb = (mv[mt] >> k) & 1;
                    short8 asel[NCH];
#pragma unroll
                    for (int c = 0; c < NCH; c++)
                        asel[c] = bb ? a[mt][c] : (short8)0;
#pragma unroll
                    for (int c = 0; c < NCH; c++)
#pragma unroll
                        for (int t = 0; t < NT; t++)
                            acc[mt][t] = __builtin_amdgcn_mfma_f32_16x16x32_bf16(
                                asel[c], bf[c][t], acc[mt][t], 0, 0, 0);
                }
            }
        }
    }

    float s[NT], q[NT];
#pragma unroll
    for (int t = 0; t < NT; t++) { s[t] = 0.f; q[t] = 0.f; }
#pragma unroll
    for (int mt = 0; mt < MT; mt++) {
#pragma unroll
        for (int g4 = 0; g4 < 4; g4++) {
            long long sr = R + wid * 32 + mt * 16 + quad * 4 + g4;
            if (sr < N) {
#pragma unroll
                for (int t = 0; t < NT; t++) {
                    float v = acc[mt][t][g4];
                    out[sr * COUT + t * 16 + m] = f2b(v);
                    s[t] += v; q[t] += v * v;
                }
            }
        }
    }
    float* pb = pstat + (blockIdx.x & 7) * 2 * COUT;
#pragma unroll
    for (int t = 0; t < NT; t++) {
        float sv = s[t], qv = q[t];
        sv += __shfl_xor(sv, 16); qv += __shfl_xor(qv, 16);
        sv += __shfl_xor(sv, 32); qv += __shfl_xor(qv, 32);
        if (quad == 0) {
            atomicAdd(&pb[t * 16 + m], sv);
            atomicAdd(&pb[COUT + t * 16 + m], qv);
        }
    }
}

// ---------- MFMA gather conv v10 + inline-BN FACT --------------------------
template<int CI1, int CI2, int COUT, int K, int G, int MT, bool FACT>
__global__ __launch_bounds__(256) void gmfma10(
    const short* __restrict__ fA, const short* __restrict__ fB,
    const int* __restrict__ nbr, const short* __restrict__ Wf,
    short* __restrict__ out, float* __restrict__ pstat, BNP pF, int N) {
    static_assert(K % G == 0, "G must divide K");
    static_assert(!FACT || CI2 == 0, "fused act only for single input");
    constexpr int NT  = COUT / 16;
    constexpr int NC1 = CI1 / 32;
    constexpr int NC2 = CI2 / 32;
    constexpr int NCH = (CI1 + CI2) / 32;
    constexpr int PANEL = NCH * NT * 512;
    constexpr int GSH   = G * PANEL;
    constexpr int NPH   = K / G;
    constexpr int WCH   = GSH / 4;
    constexpr int S16   = (WCH * 2) / 1024;
    constexpr int S4    = ((WCH * 2) % 1024) / 256;
    __shared__ __attribute__((aligned(16))) short sB[GSH];
    __shared__ float labF[FACT ? 2 * CI1 : 1];
    const int tid  = threadIdx.x;
    const int lane = tid & 63;
    const int wid  = tid >> 6;
    const int m    = lane & 15;
    const int quad = lane >> 4;
    const long long tb0 = ((long long)blockIdx.x * 4 + wid) * (MT * 16);

    f32x4 acc[MT][NT];
#pragma unroll
    for (int mt = 0; mt < MT; mt++)
#pragma unroll
        for (int t = 0; t < NT; t++) acc[mt][t] = (f32x4)0.f;

    float aS[FACT ? NC1 * 8 : 1], aBb[FACT ? NC1 * 8 : 1];
    if constexpr (FACT) {
        bn_load(pF, CI1, labF, tid);
        __syncthreads();
#pragma unroll
        for (int c = 0; c < NC1; c++)
#pragma unroll
            for (int jj = 0; jj < 8; jj++) {
                int ch = c * 32 + quad * 8 + jj;
                aS[c * 8 + jj]  = labF[ch];
                aBb[c * 8 + jj] = labF[CI1 + ch];
            }
    }

#define STAGE(ph)                                                              \
    {                                                                          \
        const short* _src = Wf + (size_t)(ph) * GSH + wid * WCH;               \
        short* _dst = &sB[wid * WCH];                                          \
        _Pragma("unroll")                                                      \
        for (int i = 0; i < S16; i++)                                          \
            __builtin_amdgcn_global_load_lds(                                  \
                (gas_short*)(_src + i * 512 + lane * 8),                       \
                (las_short*)(_dst + i * 512), 16, 0, 0);                       \
        _Pragma("unroll")                                                      \
        for (int i = 0; i < S4; i++)                                           \
            __builtin_amdgcn_global_load_lds(                                  \
                (gas_short*)(_src + S16 * 512 + i * 128 + lane * 2),           \
                (las_short*)(_dst + S16 * 512 + i * 128), 4, 0, 0);            \
    }

    STAGE(0)
    __builtin_amdgcn_sched_barrier(0);

    int idxs[MT][K];
#pragma unroll
    for (int mt = 0; mt < MT; mt++) {
        long long r = tb0 + mt * 16 + m;
        bool rv = r < N;
#pragma unroll
        for (int k = 0; k < K; k++)
            idxs[mt][k] = rv ? nbr[r * K + k] : -1;
    }
    unsigned pmask[MT];
#pragma unroll
    for (int mt = 0; mt < MT; mt++) {
        unsigned pm = 0;
#pragma unroll
        for (int k = 0; k < K; k++)
            pm |= __any(idxs[mt][k] >= 0) ? (1u << k) : 0u;
        pmask[mt] = __builtin_amdgcn_readfirstlane(pm);
    }

    __builtin_amdgcn_sched_barrier(0);
    asm volatile("s_waitcnt vmcnt(0)" ::: "memory");
    __builtin_amdgcn_s_barrier();
    __builtin_amdgcn_sched_barrier(0);
    asm volatile("" ::: "memory");

    short8 S[3][NCH];

#define LOADS(sl, mt, kk)                                                      \
    {                                                                          \
        int _i = idxs[mt][kk];                                                 \
        long long _j = _i < 0 ? 0 : _i;                                        \
        _Pragma("unroll")                                                      \
        for (int c = 0; c < NC1; c++) {                                        \
            short8 _v = *reinterpret_cast<const short8*>(                      \
                fA + _j * CI1 + c * 32 + quad * 8);                            \
            if constexpr (FACT) {                                              \
                short8 _o;                                                     \
                _Pragma("unroll")                                              \
                for (int jj = 0; jj < 8; jj++) {                               \
                    float _f = b2f(_v[jj]) * aS[c * 8 + jj] + aBb[c * 8 + jj]; \
                    _o[jj] = f2b(_f > 0.f ? _f : 0.f);                         \
                }                                                              \
                _v = _o;                                                       \
            }                                                                  \
            S[sl][c] = (_i >= 0) ? _v : (short8)0;                             \
        }                                                                      \
        if constexpr (NC2 > 0) {                                               \
            _Pragma("unroll")                                                  \
            for (int c = 0; c < NC2; c++) {                                    \
                short8 _v = *reinterpret_cast<const short8*>(                  \
                    fB + _j * CI2 + c * 32 + quad * 8);                        \
                S[sl][NC1 + c] = (_i >= 0) ? _v : (short8)0;                   \
            }                                                                  \
        }                                                                      \
    }
#define MFMAS(sl, mt, jl)                                                      \
    {                                                                          \
        _Pragma("unroll")                                                      \
        for (int c = 0; c < NCH; c++) {                                        \
            _Pragma("unroll")                                                  \
            for (int t = 0; t < NT; t++) {                                     \
                short8 b = *reinterpret_cast<const short8*>(                   \
                    &sB[((jl) * NCH * NT + c * NT + t) * 512 + lane * 8]);     \
                acc[mt][t] = __builtin_amdgcn_mfma_f32_16x16x32_bf16(          \
                    S[sl][c], b, acc[mt][t], 0, 0, 0);                         \
            }                                                                  \
        }                                                                      \
    }

#pragma unroll
    for (int ph = 0; ph < NPH; ph++) {
#pragma unroll
        for (int mt = 0; mt < MT; mt++) {
            const unsigned mm = (pmask[mt] >> (ph * G)) & ((1u << G) - 1);
#pragma unroll
            for (int j = 0; j < G + 2; j++) {
                if (j < G)
                    if (mm & (1u << j)) LOADS(j % 3, mt, ph * G + j)
                if (j >= 2)
                    if (mm & (1u << (j - 2))) MFMAS((j - 2) % 3, mt, j - 2)
            }
        }
        if (ph + 1 < NPH) {
            __builtin_amdgcn_sched_barrier(0);
            asm volatile("s_waitcnt lgkmcnt(0)" ::: "memory");
            __builtin_amdgcn_s_barrier();
            __builtin_amdgcn_sched_barrier(0);
            STAGE(ph + 1)
            __builtin_amdgcn_sched_barrier(0);
            asm volatile("s_waitcnt vmcnt(0)" ::: "memory");
            __builtin_amdgcn_s_barrier();
            __builtin_amdgcn_sched_barrier(0);
            asm volatile("" ::: "memory");
        }
    }
#undef LOADS
#undef MFMAS
#undef STAGE
    float s[NT], q[NT];
#pragma unroll
    for (int t = 0; t < NT; t++) { s[t] = 0.f; q[t] = 0.f; }
#pragma unroll
    for (int mt = 0; mt < MT; mt++) {
#pragma unroll
        for (int g4 = 0; g4 < 4; g4++) {
            long long sr = tb0 + mt * 16 + quad * 4 + g4;
            if (sr < N) {
#pragma unroll
                for (int t = 0; t < NT; t++) {
                    float v = acc[mt][t][g4];
                    out[sr * COUT + t * 16 + m] = f2b(v);
                    s[t] += v; q[t] += v * v;
                }
            }
        }
    }
    float* pb = pstat + (blockIdx.x & 7) * 2 * COUT;
#pragma unroll
    for (int t = 0; t < NT; t++) {
        float sv = s[t], qv = q[t];
        sv += __shfl_xor(sv, 16); qv += __shfl_xor(qv, 16);
        sv += __shfl_xor(sv, 32); qv += __shfl_xor(qv, 32);
        if (quad == 0) {
            atomicAdd(&pb[t * 16 + m], sv);
            atomicAdd(&pb[COUT + t * 16 + m], qv);
        }
    }
}

// ---------- MFMA up conv v10 + inline-BN input act -------------------------
template<int CIN, int COUT, int G>
__global__ __launch_bounds__(256) void upmfma10(
    const short* __restrict__ f, const int* __restrict__ rb,
    const short* __restrict__ Wf, short* __restrict__ out,
    float* __restrict__ pstat, BNP pF, int N) {
    static_assert(8 % G == 0, "G must divide 8");
    constexpr int NT = COUT / 16;
    constexpr int NK = CIN / 32;
    constexpr int PANEL = NK * NT * 512;
    constexpr int GSH   = G * PANEL;
    constexpr int NPH   = 8 / G;
    constexpr int WCH   = GSH / 4;
    constexpr int S16   = (WCH * 2) / 1024;
    constexpr int S4    = ((WCH * 2) % 1024) / 256;
    __shared__ __attribute__((aligned(16))) short sB[GSH];
    __shared__ float labF[2 * CIN];
    const int tid  = threadIdx.x;
    const int lane = tid & 63;
    const int wid  = tid >> 6;
    const int m    = lane & 15;
    const int quad = lane >> 4;
    const long long row0 = ((long long)blockIdx.x * 4 + wid) * 16;
    const long long r = row0 + m;
    const bool rv = r < N;
    const long long rc = rv ? r : 0;

    bn_load(pF, CIN, labF, tid);
    __syncthreads();

#define STAGE(ph)                                                              \
    {                                                                          \
        const short* _src = Wf + (size_t)(ph) * GSH + wid * WCH;               \
        short* _dst = &sB[wid * WCH];                                          \
        _Pragma("unroll")                                                      \
        for (int i = 0; i < S16; i++)                                          \
            __builtin_amdgcn_global_load_lds(                                  \
                (gas_short*)(_src + i * 512 + lane * 8),                       \
                (las_short*)(_dst + i * 512), 16, 0, 0);                       \
        _Pragma("unroll")                                                      \
        for (int i = 0; i < S4; i++)                                           \
            __builtin_amdgcn_global_load_lds(                                  \
                (gas_short*)(_src + S16 * 512 + i * 128 + lane * 2),           \
                (las_short*)(_dst + S16 * 512 + i * 128), 4, 0, 0);            \
    }
    STAGE(0)
    __builtin_amdgcn_sched_barrier(0);

    short8 af[NK];
#pragma unroll
    for (int kc = 0; kc < NK; kc++) {
        short8 v = *reinterpret_cast<const short8*>(
            f + rc * CIN + kc * 32 + quad * 8);
        short8 o;
#pragma unroll
        for (int jj = 0; jj < 8; jj++) {
            int ch = kc * 32 + quad * 8 + jj;
            float u = b2f(v[jj]) * labF[ch] + labF[CIN + ch];
            o[jj] = f2b(u > 0.f ? u : 0.f);
        }
        af[kc] = rv ? o : (short8)0;
    }
    int sidx[8][4];
#pragma unroll
    for (int g4 = 0; g4 < 4; g4++) {
        long long sr = row0 + quad * 4 + g4;
#pragma unroll
        for (int k = 0; k < 8; k++)
            sidx[k][g4] = (sr < N) ? rb[sr * 8 + k] : -1;
    }
    unsigned pm = 0;
#pragma unroll
    for (int k = 0; k < 8; k++) {
        int anyv = (sidx[k][0] >= 0) | (sidx[k][1] >= 0) |
                   (sidx[k][2] >= 0) | (sidx[k][3] >= 0);
        pm |= __any(anyv) ? (1u << k) : 0u;
    }
    pm = __builtin_amdgcn_readfirstlane(pm);

    float s[NT], q[NT];
#pragma unroll
    for (int t = 0; t < NT; t++) { s[t] = 0.f; q[t] = 0.f; }

    __builtin_amdgcn_sched_barrier(0);
    asm volatile("s_waitcnt vmcnt(0)" ::: "memory");
    __builtin_amdgcn_s_barrier();
    __builtin_amdgcn_sched_barrier(0);
    asm volatile("" ::: "memory");

#pragma unroll
    for (int ph = 0; ph < NPH; ph++) {
#pragma unroll
        for (int j = 0; j < G; j++) {
            const int k = ph * G + j;
            if (pm & (1u << k)) {
                f32x4 acc[NT];
#pragma unroll
                for (int t = 0; t < NT; t++) acc[t] = (f32x4)0.f;
#pragma unroll
                for (int kc = 0; kc < NK; kc++) {
#pragma unroll
                    for (int t = 0; t < NT; t++) {
                        short8 b = *reinterpret_cast<const short8*>(
                            &sB[(j * NK * NT + kc * NT + t) * 512 + lane * 8]);
                        acc[t] = __builtin_amdgcn_mfma_f32_16x16x32_bf16(
                            af[kc], b, acc[t], 0, 0, 0);
                    }
                }
#pragma unroll
                for (int g4 = 0; g4 < 4; g4++) {
                    if (sidx[k][g4] >= 0) {
#pragma unroll
                        for (int t = 0; t < NT; t++) {
                            float v = acc[t][g4];
                            out[(long long)sidx[k][g4] * COUT + t * 16 + m] =
                                f2b(v);
                            s[t] += v; q[t] += v * v;
                        }
                    }
                }
            }
        }
        if (ph + 1 < NPH) {
            __builtin_amdgcn_sched_barrier(0);
            asm volatile("s_waitcnt lgkmcnt(0)" ::: "memory");
            __builtin_amdgcn_s_barrier();
            __builtin_amdgcn_sched_barrier(0);
            STAGE(ph + 1)
            __builtin_amdgcn_sched_barrier(0);
            asm volatile("s_waitcnt vmcnt(0)" ::: "memory");
            __builtin_amdgcn_s_barrier();
            __builtin_amdgcn_sched_barrier(0);
            asm volatile("" ::: "memory");
        }
    }
#undef STAGE
    float* pb = pstat + (blockIdx.x & 7) * 2 * COUT;
#pragma unroll
    for (int t = 0; t < NT; t++) {
        float sv = s[t], qv = q[t];
        sv += __shfl_xor(sv, 16); qv += __shfl_xor(qv, 16);
        sv += __shfl_xor(sv, 32); qv += __shfl_xor(qv, 32);
        if (quad == 0) {
            atomicAdd(&pb[t * 16 + m], sv);
            atomicAdd(&pb[COUT + t * 16 + m], qv);
        }
    }
}

// ---------- BN stats (only for conv_in's output), f64 deterministic --------
template<int C>
__global__ void bn_stats(const short* __restrict__ x, double* __restrict__ part, int N) {
    constexpr int GR  = C / 8;
    constexpr int RPB = 256 / GR;
    constexpr int ACTIVE = GR * RPB;
    __shared__ double ls[256 * 8];
    __shared__ double lq[256 * 8];
    const int tid = threadIdx.x;
    const int g   = tid % GR;
    const int rr  = tid / GR;
    double s[8], q[8];
#pragma unroll
    for (int j = 0; j < 8; j++) { s[j] = 0.0; q[j] = 0.0; }
    if (tid < ACTIVE) {
        for (long long r = (long long)blockIdx.x * RPB + rr; r < N;
             r += (long long)gridDim.x * RPB) {
            short8 v = *reinterpret_cast<const short8*>(x + r * C + g * 8);
#pragma unroll
            for (int j = 0; j < 8; j++) {
                double f = (double)b2f(v[j]);
                s[j] += f; q[j] += f * f;
            }
        }
    }
#pragma unroll
    for (int j = 0; j < 8; j++) { ls[tid * 8 + j] = s[j]; lq[tid * 8 + j] = q[j]; }
    __syncthreads();
    if (tid < C) {
        int gg = tid / 8, jj = tid % 8;
        double S = 0.0, Q = 0.0;
        for (int r2 = 0; r2 < RPB; r2++) {
            S += ls[(r2 * GR + gg) * 8 + jj];
            Q += lq[(r2 * GR + gg) * 8 + jj];
        }
        part[blockIdx.x * 256 + tid]       = S;
        part[blockIdx.x * 256 + 128 + tid] = Q;
    }
}

__global__ void bn_fin(const double* __restrict__ part, const float* __restrict__ gb,
                       int gbfull, int goff, float* __restrict__ ab,
                       int C, int P, double invN) {
    __shared__ double ss[256], sq[256];
    const int tid = threadIdx.x;
    const int c   = tid % C;
    const int g   = tid / C;
    const int G   = 256 / C;
    double s = 0.0, q = 0.0;
    if (g < G) {
        for (int p = g; p < P; p += G) {
            s += part[p * 256 + c];
            q += part[p * 256 + 128 + c];
        }
    }
    ss[tid] = s; sq[tid] = q;
    __syncthreads();
    if (tid < C) {
        for (int j = 1; j < G; j++) { s += ss[j * C + c]; q += sq[j * C + c]; }
        double mu  = s * invN;
        double var = q * invN - mu * mu;
        double a   = (double)gb[goff + c] / sqrt(var + 1e-4);
        ab[c]     = (float)a;
        ab[C + c] = (float)((double)gb[gbfull + goff + c] - mu * a);
    }
}

// ---------- bnact_i: inline-BN relu pass -----------------------------------
template<int C>
__global__ __launch_bounds__(256) void bnact_i(
    const short* __restrict__ x, BNP p, short* __restrict__ y, long long total8) {
    __shared__ float lab[2 * C];
    const int tid = threadIdx.x;
    bn_load(p, C, lab, tid);
    __syncthreads();
    long long i = (long long)blockIdx.x * 256 + tid;
    if (i >= total8) return;
    long long base = i * 8;
    int c0 = (int)(base % C);
    short8 v = *reinterpret_cast<const short8*>(x + base);
    short8 o;
#pragma unroll
    for (int j = 0; j < 8; j++) {
        float f = b2f(v[j]) * lab[c0 + j] + lab[C + c0 + j];
        o[j] = f2b(f > 0.f ? f : 0.f);
    }
    *reinterpret_cast<short8*>(y + base) = o;
}

// ---------- bnact2_i: two tensors, inline BN -------------------------------
template<int C>
__global__ __launch_bounds__(256) void bnact2_i(
    const short* __restrict__ xa, BNP pa, short* __restrict__ ya,
    const short* __restrict__ xb, BNP pb, short* __restrict__ yb, long long n8) {
    __shared__ float la[2 * C], lb[2 * C];
    const int tid = threadIdx.x;
    bn_load(pa, C, la, tid);
    bn_load(pb, C, lb, tid);
    __syncthreads();
    long long i = (long long)blockIdx.x * 256 + tid;
    if (i >= 2 * n8) return;
    const short* x; const float* lab; short* y; long long ii;
    if (i < n8) { x = xa; lab = la; y = ya; ii = i; }
    else        { x = xb; lab = lb; y = yb; ii = i - n8; }
    long long base = ii * 8;
    int c0 = (int)(base % C);
    short8 v = *reinterpret_cast<const short8*>(x + base);
    short8 o;
#pragma unroll
    for (int j = 0; j < 8; j++) {
        float f = b2f(v[j]) * lab[c0 + j] + lab[C + c0 + j];
        o[j] = f2b(f > 0.f ? f : 0.f);
    }
    *reinterpret_cast<short8*>(y + base) = o;
}

// ---------- final linear (inline bnf), bf16 in, f32 out --------------------
__global__ __launch_bounds__(256) void final_k_i(
    const short* __restrict__ x, BNP p,
    const float* __restrict__ lw, const float* __restrict__ lb,
    float* __restrict__ out, int N) {
    __shared__ float lab[64];
    const int tid = threadIdx.x;
    bn_load(p, 32, lab, tid);
    __syncthreads();
    long long r = (long long)blockIdx.x * 256 + tid;
    if (r >= N) return;
    float a0 = lb[0], a1 = lb[1];
#pragma unroll
    for (int j = 0; j < 4; j++) {
        short8 v = *reinterpret_cast<const short8*>(x + r * 32 + j * 8);
#pragma unroll
        for (int t = 0; t < 8; t++) {
            int ci = 8 * j + t;
            float u = b2f(v[t]) * lab[ci] + lab[32 + ci];
            u = u > 0.f ? u : 0.f;
            a0 += u * lw[ci * 2];
            a1 += u * lw[ci * 2 + 1];
        }
    }
    out[2 * r]     = a0;
    out[2 * r + 1] = a1;
}

extern "C" void kernel_launch(void* const* d_in, const int* in_sizes, int n_in,
                              void* d_out, int out_size, void* d_ws, size_t ws_size,
                              hipStream_t stream) {
    const long long N0 = in_sizes[0] / 3;
    const long long N1 = in_sizes[26] / 8;
    const long long N2 = in_sizes[27] / 8;
    const int P = 256;

    const float* feat = (const float*)d_in[0];
    const int* nbr0 = (const int*)d_in[23];
    const int* nbr1 = (const int*)d_in[24];
    const int* nbr2 = (const int*)d_in[25];
    const int* rb0  = (const int*)d_in[26];
    const int* rb1  = (const int*)d_in[27];

    // ---- arena ----
    char* p = (char*)d_ws;
    double* part = (double*)p;            p += (size_t)P * 256 * 8;     // 512 KB
    float*  ab   = (float*)p;             p += 12 * 256 * 4;
    float*  pst  = (float*)p;             p += (size_t)10 * 2048 * 4;
    unsigned* msk0 = (unsigned*)p;        p += ((size_t)N0 * 4 + 63) & ~(size_t)63;
    const int wLayer[9] = {3, 5, 7, 9, 11, 13, 15, 17, 19};
    const int wK[9]  = {27, 8, 27, 8, 27, 8, 27, 8, 27};
    const int wCI[9] = {32, 32, 64, 64, 96, 96, 128, 64, 64};
    const int wCO[9] = {32, 64, 64, 96, 96, 64, 64, 32, 32};
    short* wt[9];
    WPA wpa;
    int cum = 0;
    for (int i = 0; i < 9; i++) {
        wt[i] = (short*)p;
        int n = wK[i] * wCI[i] * wCO[i];
        p += (((size_t)n * 2 + 63) & ~(size_t)63);
        wpa.src[i] = (const float*)d_in[wLayer[i]];
        wpa.dst[i] = wt[i];
        wpa.CI[i] = wCI[i]; wpa.CO[i] = wCO[i];
        wpa.cum[i] = cum; cum += n;
    }
    wpa.cum[9] = cum;
    auto balloc = [&](long long elems) {
        short* q = (short*)p;
        p += (((size_t)elems * 2 + 63) & ~(size_t)63);
        return q;
    };
    short* R0 = balloc(N0 * 32);   // t0 / d0 / d1 / u1 / u0 (raw)
    short* R1 = balloc(N0 * 32);   // x0 raw (persist)
    short* R2 = balloc(N1 * 64);   // x1 raw (persist)
    short* R3 = balloc(N0 * 32);   // x2 / y1 / y0 (raw)
    short* Xb = balloc(N0 * 32);   // act out #1
    short* Yb = balloc(N0 * 32);   // act out #2

    wprep_all<<<(cum + 255) / 256, 256, 0, stream>>>(wpa, cum);
    nbrmask_k<<<(int)((N0 + 255) / 256), 256, 0, stream>>>(nbr0, msk0, pst, (int)N0);

#define AB(SL) (ab + (SL) * 256)
#define PS(SL) (pst + (SL) * 2048)
#define GB1(N_) (int)(((N_) + 63) / 64)
#define GB2(N_) (int)(((N_) + 127) / 128)

    auto mkp = [&](float* pstp, const float* abd, int gbi, int gbfull, int goff,
                   double invN) {
        BNP b;
        b.pst = pstp; b.abd = abd;
        b.gb = (gbi >= 0) ? (const float*)d_in[gbi] : nullptr;
        b.gbfull = gbfull; b.goff = goff; b.invN = invN;
        return b;
    };
    BNP dummy = mkp(nullptr, nullptr, -1, 0, 0, 0.0);

    // ---- level 0 ----
    conv_in_st<<<(int)((N0 + 255) / 256), 256, 0, stream>>>(
        feat, msk0, (const float*)d_in[1], R0, (int)N0);                  // t0 -> R0
    bn_stats<32><<<P, 256, 0, stream>>>(R0, part, (int)N0);               // bn1_0
    bn_fin<<<1, 256, 0, stream>>>(part, (const float*)d_in[2], 32, 0,
                                  AB(0), 32, P, 1.0 / (double)N0);
    stencil0<32, 0, 32><<<GB2(N0), 256, 0, stream>>>(
        R0, nullptr, msk0, wt[0], R1, PS(0),
        mkp(nullptr, AB(0), -1, 0, 0, 0.0), dummy, (int)N0);              // x0 -> R1
    gmfma10<32, 0, 64, 8, 8, 2, true><<<GB2(N1), 256, 0, stream>>>(
        R1, nullptr, rb0, wt[1], R0, PS(1),
        mkp(PS(0), nullptr, 4, 32, 0, 1.0 / (double)N0), (int)N1);        // d0 -> R0

    // ---- level 1 ----
    bnact_i<64><<<(int)((N1 * 64 / 8 + 255) / 256), 256, 0, stream>>>(
        R0, mkp(PS(1), nullptr, 6, 64, 0, 1.0 / (double)N1), Xb, N1 * 64 / 8);
    gmfma10<64, 0, 64, 27, 3, 2, false><<<GB2(N1), 256, 0, stream>>>(
        Xb, nullptr, nbr1, wt[2], R2, PS(2), dummy, (int)N1);             // x1 -> R2
    gmfma10<64, 0, 96, 8, 2, 1, true><<<GB1(N2), 256, 0, stream>>>(
        R2, nullptr, rb1, wt[3], R0, PS(3),
        mkp(PS(2), nullptr, 8, 64, 0, 1.0 / (double)N1), (int)N2);        // d1 -> R0

    // ---- level 2 ----
    bnact_i<96><<<(int)((N2 * 96 / 8 + 255) / 256), 256, 0, stream>>>(
        R0, mkp(PS(3), nullptr, 10, 96, 0, 1.0 / (double)N2), Xb, N2 * 96 / 8);
    gmfma10<96, 0, 96, 27, 3, 1, false><<<GB1(N2), 256, 0, stream>>>(
        Xb, nullptr, nbr2, wt[4], R3, PS(4), dummy, (int)N2);             // x2 -> R3

    // ---- up to level 1 ----
    upmfma10<96, 64, 2><<<GB1(N2), 256, 0, stream>>>(
        R3, rb1, wt[5], R0, PS(5),
        mkp(PS(4), nullptr, 12, 96, 0, 1.0 / (double)N2), (int)N2);       // u1 -> R0
    bnact2_i<64><<<(int)((2 * (N1 * 64 / 8) + 255) / 256), 256, 0, stream>>>(
        R2, mkp(PS(2), nullptr, 14, 128, 0, 1.0 / (double)N1), Xb,
        R0, mkp(PS(5), nullptr, 14, 128, 64, 1.0 / (double)N1), Yb, N1 * 64 / 8);
    gmfma10<64, 64, 64, 27, 3, 2, false><<<GB2(N1), 256, 0, stream>>>(
        Xb, Yb, nbr1, wt[6], R3, PS(6), dummy, (int)N1);                  // y1 -> R3

    // ---- up to level 0 ----
    upmfma10<64, 32, 4><<<GB1(N1), 256, 0, stream>>>(
        R3, rb0, wt[7], R0, PS(7),
        mkp(PS(6), nullptr, 16, 64, 0, 1.0 / (double)N1), (int)N1);       // u0 -> R0
    stencil0<32, 32, 32><<<GB2(N0), 256, 0, stream>>>(
        R1, R0, msk0, wt[8], R3, PS(8),
        mkp(PS(0), nullptr, 18, 64, 0, 1.0 / (double)N0),
        mkp(PS(7), nullptr, 18, 64, 32, 1.0 / (double)N0), (int)N0);      // y0 -> R3

    final_k_i<<<(int)((N0 + 255) / 256), 256, 0, stream>>>(
        R3, mkp(PS(8), nullptr, 20, 32, 0, 1.0 / (double)N0),
        (const float*)d_in[21], (const float*)d_in[22],
        (float*)d_out, (int)N0);

#undef AB
#undef PS
#undef GB1
#undef GB2
}

// Round 16
// 533.425 us; speedup vs baseline: 1.2776x; 1.0060x over previous
//
#include <hip/hip_runtime.h>
#include <hip/hip_bf16.h>

// ---------------------------------------------------------------------------
// Sparse 3-level U-Net — Round 32: conv_in stats fusion + prologue merge.
// R31 (536.6us, best): inline BN-finalize validated (bit-stable absmax).
// R32: (a) conv_in_st epilogue computes bn1_0 stats inline (wave shfl
// butterfly + 4-wave LDS combine + banked atomics -> PS(9)); removes
// bn_stats + bn_fin (last separate-stats path). (b) wprep_all + nbrmask_k
// merged into one prologue launch. Launches 18 -> 16.
// x1/y1 (76.5us each) accepted: 8 structural variants all >= this.
// Baseline R31: 536.6us. Prediction: 515-525us.
// ---------------------------------------------------------------------------

typedef __hip_bfloat16 hbf;
typedef __attribute__((ext_vector_type(8))) short short8;
typedef __attribute__((ext_vector_type(4))) float f32x4;
typedef const __attribute__((address_space(1))) short gas_short;
typedef __attribute__((address_space(3))) short las_short;

__device__ inline float b2f(short s) {
    unsigned u = ((unsigned)(unsigned short)s) << 16;
    float f; __builtin_memcpy(&f, &u, 4); return f;
}
__device__ inline short f2b(float f) {
    hbf h = __float2bfloat16(f);
    short s; __builtin_memcpy(&s, &h, 2); return s;
}

// ---------- inline BN finalize params --------------------------------------
struct BNP {
    const float* pst;   // 8-bank sums (or null -> use abd)
    const float* abd;   // precomputed ab (used if pst == null)
    const float* gb;    // gamma/beta (2,C') flattened
    int gbfull, goff;
    double invN;
};
__device__ inline void bn_load(const BNP& p, int C, float* lab, int tid) {
    if (tid < C) {
        if (p.pst) {
            double s = 0.0, q = 0.0;
#pragma unroll
            for (int b = 0; b < 8; b++) {
                s += (double)p.pst[b * 2 * C + tid];
                q += (double)p.pst[b * 2 * C + C + tid];
            }
            double mu  = s * p.invN;
            double var = q * p.invN - mu * mu;
            double a   = (double)p.gb[p.goff + tid] / sqrt(var + 1e-4);
            lab[tid]     = (float)a;
            lab[C + tid] = (float)((double)p.gb[p.gbfull + p.goff + tid] - mu * a);
        } else {
            lab[tid]     = p.abd[tid];
            lab[C + tid] = p.abd[C + tid];
        }
    }
}

// ---------- merged prologue: weight prep + nbr mask + pst zero -------------
struct WPA {
    const float* src[9];
    short* dst[9];
    int CI[9], CO[9];
    int cum[10];
};
__global__ __launch_bounds__(256) void prep_all(WPA a, int total, int wb,
                                                const int* __restrict__ nbr,
                                                unsigned* __restrict__ msk,
                                                float* __restrict__ pst, int N) {
    const int b = blockIdx.x;
    if (b < wb) {
        int e0 = b * 256 + threadIdx.x;
        if (e0 >= total) return;
        int L = 0;
#pragma unroll
        for (int i = 1; i < 9; i++) L += (e0 >= a.cum[i]) ? 1 : 0;
        int e = e0 - a.cum[L];
        int CI = a.CI[L], CO = a.CO[L];
        int NT = CO >> 4, NCH = CI >> 5;
        int j    = e & 7;
        int lane = (e >> 3) & 63;
        int t    = (e >> 9) % NT;
        int c    = (e / (512 * NT)) % NCH;
        int k    = e / (512 * NT * NCH);
        int ci = c * 32 + (lane >> 4) * 8 + j;
        int co = t * 16 + (lane & 15);
        a.dst[L][e] = f2b(a.src[L][((long long)k * CI + ci) * CO + co]);
    } else {
        long long r = (long long)(b - wb) * 256 + threadIdx.x;
        if (r < 10 * 2048) pst[r] = 0.f;
        if (r >= N) return;
        unsigned mv = 0;
#pragma unroll
        for (int k = 0; k < 27; k++)
            mv |= (nbr[r * 27 + k] >= 0) ? (1u << k) : 0u;
        msk[r] = mv;
    }
}

// ---------- input conv, STENCILIZED + fused bn1_0 stats --------------------
__global__ __launch_bounds__(256) void conv_in_st(
    const float* __restrict__ feat, const unsigned* __restrict__ msk,
    const float* __restrict__ W, short* __restrict__ out,
    float* __restrict__ pstat, int N) {
    __shared__ float sW[27 * 96];
    __shared__ float sF[3][258][3];
    __shared__ float ws[4][64];
    const int tid = threadIdx.x;
    const int bid = blockIdx.x;
    const int xq     = bid >> 1;
    const int ystart = (bid & 1) << 8;
    const long long R = (long long)bid * 256;

    for (int e = tid; e < 27 * 96; e += 256) sW[e] = W[e];
    for (int e = tid; e < 3 * 258; e += 256) {
        int rr = e % 258, st = e / 258;
        long long gr = (long long)(xq - 1 + st) * 512 + (ystart - 1 + rr);
        long long grc = (gr < 0 || gr >= N) ? 0 : gr;
        sF[st][rr][0] = feat[grc * 3];
        sF[st][rr][1] = feat[grc * 3 + 1];
        sF[st][rr][2] = feat[grc * 3 + 2];
    }
    __syncthreads();

    long long r = R + tid;
    unsigned mv = (r < N) ? msk[r] : 0u;
    float acc[32];
#pragma unroll
    for (int c = 0; c < 32; c++) acc[c] = 0.f;
#pragma unroll
    for (int k = 0; k < 27; k++) {
        if (mv & (1u << k)) {
            const int st = k / 9;
            const int dy = (k / 3) % 3 - 1;
            const int rl = 1 + tid + dy;
            float f0 = sF[st][rl][0];
            float f1 = sF[st][rl][1];
            float f2 = sF[st][rl][2];
            const float* w = sW + k * 96;
#pragma unroll
            for (int c = 0; c < 32; c++)
                acc[c] += f0 * w[c] + f1 * w[32 + c] + f2 * w[64 + c];
        }
    }
    // store (bf16-rounded) and accumulate stats from rounded values
    float qst[32];
#pragma unroll
    for (int c = 0; c < 32; c++) { qst[c] = 0.f; }
    if (r < N) {
#pragma unroll
        for (int c = 0; c < 32; c++) {
            short sv = f2b(acc[c]);
            out[r * 32 + c] = sv;
            float v = b2f(sv);
            acc[c] = v; qst[c] = v * v;
        }
    } else {
#pragma unroll
        for (int c = 0; c < 32; c++) acc[c] = 0.f;
    }
    // wave butterfly reduce (64 lanes), all 32 channels
#pragma unroll
    for (int off = 1; off < 64; off <<= 1) {
#pragma unroll
        for (int c = 0; c < 32; c++) {
            acc[c] += __shfl_xor(acc[c], off);
            qst[c] += __shfl_xor(qst[c], off);
        }
    }
    const int wid = tid >> 6, lane = tid & 63;
    if (lane == 0) {
#pragma unroll
        for (int c = 0; c < 32; c++) {
            ws[wid][c]      = acc[c];
            ws[wid][32 + c] = qst[c];
        }
    }
    __syncthreads();
    if (tid < 64) {
        float v = ws[0][tid] + ws[1][tid] + ws[2][tid] + ws[3][tid];
        atomicAdd(&pstat[(bid & 7) * 64 + tid], v);
    }
}

// ---------- stencil conv for level 0, inline BN ----------------------------
template<int CI1, int CI2, int COUT>
__global__ __launch_bounds__(256) void stencil0(
    const short* __restrict__ fA, const short* __restrict__ fB,
    const unsigned* __restrict__ msk, const short* __restrict__ Wf,
    short* __restrict__ out, float* __restrict__ pstat,
    BNP pA, BNP pB, int N) {
    constexpr int CIT  = CI1 + CI2;
    constexpr int NCH  = CIT / 32;
    constexpr int NT   = COUT / 16;
    constexpr int MT   = 2;
    constexpr int CIB  = CIT * 2;
    constexpr int ROWS = 130;
    constexpr int NC8  = CIT / 8;
    constexpr int SWB  = (CIB >= 128) ? 7 : 3;
    __shared__ __attribute__((aligned(16))) char sA[3 * ROWS * CIB];
    __shared__ float labA[2 * CI1];
    __shared__ float labB[CI2 > 0 ? 2 * CI2 : 1];
    const int tid  = threadIdx.x;
    const int lane = tid & 63;
    const int wid  = tid >> 6;
    const int m    = lane & 15;
    const int quad = lane >> 4;
    const int bid  = blockIdx.x;
    const int xq     = bid >> 2;
    const int ystart = (bid & 3) << 7;
    const long long R = (long long)bid * 128;

    bn_load(pA, CI1, labA, tid);
    if constexpr (CI2 > 0) bn_load(pB, CI2, labB, tid);
    __syncthreads();

    {
        const int c8 = tid % NC8;
        const bool isA = (c8 * 8) < CI1;
        const short* src  = isA ? fA : fB;
        const float* lab  = isA ? labA : labB;
        const int   srcCI = isA ? CI1 : CI2;
        const int   chb   = isA ? c8 * 8 : c8 * 8 - CI1;
        float s_[8], b_[8];
#pragma unroll
        for (int jj = 0; jj < 8; jj++) {
            s_[jj] = lab[chb + jj];
            b_[jj] = lab[srcCI + chb + jj];
        }
        for (int e = tid; e < 3 * ROWS * NC8; e += 256) {
            int rr = (e / NC8) % ROWS;
            int st = e / (NC8 * ROWS);
            long long gr = (long long)(xq - 1 + st) * 512 + (ystart - 1 + rr);
            long long grc = (gr < 0 || gr >= N) ? 0 : gr;
            short8 v = *reinterpret_cast<const short8*>(src + grc * srcCI + chb);
            short8 o;
#pragma unroll
            for (int jj = 0; jj < 8; jj++) {
                float f = b2f(v[jj]) * s_[jj] + b_[jj];
                o[jj] = f2b(f > 0.f ? f : 0.f);
            }
            int byte = (st * ROWS + rr) * CIB + c8 * 16;
            byte ^= ((rr & SWB) << 4);
            *reinterpret_cast<short8*>(sA + byte) = o;
        }
    }
    __syncthreads();

    f32x4 acc[MT][NT];
#pragma unroll
    for (int mt = 0; mt < MT; mt++)
#pragma unroll
        for (int t = 0; t < NT; t++) acc[mt][t] = (f32x4)0.f;

    unsigned mv[MT];
#pragma unroll
    for (int mt = 0; mt < MT; mt++) {
        long long r = R + wid * 32 + mt * 16 + m;
        mv[mt] = (r < N) ? msk[r] : 0u;
    }

#pragma unroll
    for (int s9 = 0; s9 < 9; s9++) {
        const int st = s9 / 3;
        const int dy = s9 % 3 - 1;
        short8 a[MT][NCH];
#pragma unroll
        for (int mt = 0; mt < MT; mt++) {
            int rl = 1 + wid * 32 + mt * 16 + m + dy;
#pragma unroll
            for (int c = 0; c < NCH; c++) {
                int byte = (st * ROWS + rl) * CIB + (c * 4 + quad) * 16;
                byte ^= ((rl & SWB) << 4);
                a[mt][c] = *reinterpret_cast<const short8*>(sA + byte);
            }
        }
#pragma unroll
        for (int z3 = 0; z3 < 3; z3++) {
            const int k = s9 * 3 + z3;
            unsigned anyb = (mv[0] >> k) & 1;
            if (MT > 1) anyb |= (mv[1] >> k) & 1;
            if (__any(anyb)) {
                short8 bf[NCH][NT];
#pragma unroll
                for (int c = 0; c < NCH; c++)
#pragma unroll
                    for (int t = 0; t < NT; t++)
                        bf[c][t] = *reinterpret_cast<const short8*>(
                            Wf + ((size_t)(k * NCH + c) * NT + t) * 512 + lane * 8);
#pragma unroll
                for (int mt = 0; mt < MT; mt++) {
                    const bool bb = (mv[mt] >> k) & 1;
                    short8 asel[NCH];
#pragma unroll
                    for (int c = 0; c < NCH; c++)
                        asel[c] = bb ? a[mt][c] : (short8)0;
#pragma unroll
                    for (int c = 0; c < NCH; c++)
#pragma unroll
                        for (int t = 0; t < NT; t++)
                            acc[mt][t] = __builtin_amdgcn_mfma_f32_16x16x32_bf16(
                                asel[c], bf[c][t], acc[mt][t], 0, 0, 0);
                }
            }
        }
    }

    float s[NT], q[NT];
#pragma unroll
    for (int t = 0; t < NT; t++) { s[t] = 0.f; q[t] = 0.f; }
#pragma unroll
    for (int mt = 0; mt < MT; mt++) {
#pragma unroll
        for (int g4 = 0; g4 < 4; g4++) {
            long long sr = R + wid * 32 + mt * 16 + quad * 4 + g4;
            if (sr < N) {
#pragma unroll
                for (int t = 0; t < NT; t++) {
                    float v = acc[mt][t][g4];
                    out[sr * COUT + t * 16 + m] = f2b(v);
                    s[t] += v; q[t] += v * v;
                }
            }
        }
    }
    float* pb = pstat + (blockIdx.x & 7) * 2 * COUT;
#pragma unroll
    for (int t = 0; t < NT; t++) {
        float sv = s[t], qv = q[t];
        sv += __shfl_xor(sv, 16); qv += __shfl_xor(qv, 16);
        sv += __shfl_xor(sv, 32); qv += __shfl_xor(qv, 32);
        if (quad == 0) {
            atomicAdd(&pb[t * 16 + m], sv);
            atomicAdd(&pb[COUT + t * 16 + m], qv);
        }
    }
}

// ---------- MFMA gather conv v10 + inline-BN FACT --------------------------
template<int CI1, int CI2, int COUT, int K, int G, int MT, bool FACT>
__global__ __launch_bounds__(256) void gmfma10(
    const short* __restrict__ fA, const short* __restrict__ fB,
    const int* __restrict__ nbr, const short* __restrict__ Wf,
    short* __restrict__ out, float* __restrict__ pstat, BNP pF, int N) {
    static_assert(K % G == 0, "G must divide K");
    static_assert(!FACT || CI2 == 0, "fused act only for single input");
    constexpr int NT  = COUT / 16;
    constexpr int NC1 = CI1 / 32;
    constexpr int NC2 = CI2 / 32;
    constexpr int NCH = (CI1 + CI2) / 32;
    constexpr int PANEL = NCH * NT * 512;
    constexpr int GSH   = G * PANEL;
    constexpr int NPH   = K / G;
    constexpr int WCH   = GSH / 4;
    constexpr int S16   = (WCH * 2) / 1024;
    constexpr int S4    = ((WCH * 2) % 1024) / 256;
    __shared__ __attribute__((aligned(16))) short sB[GSH];
    __shared__ float labF[FACT ? 2 * CI1 : 1];
    const int tid  = threadIdx.x;
    const int lane = tid & 63;
    const int wid  = tid >> 6;
    const int m    = lane & 15;
    const int quad = lane >> 4;
    const long long tb0 = ((long long)blockIdx.x * 4 + wid) * (MT * 16);

    f32x4 acc[MT][NT];
#pragma unroll
    for (int mt = 0; mt < MT; mt++)
#pragma unroll
        for (int t = 0; t < NT; t++) acc[mt][t] = (f32x4)0.f;

    float aS[FACT ? NC1 * 8 : 1], aBb[FACT ? NC1 * 8 : 1];
    if constexpr (FACT) {
        bn_load(pF, CI1, labF, tid);
        __syncthreads();
#pragma unroll
        for (int c = 0; c < NC1; c++)
#pragma unroll
            for (int jj = 0; jj < 8; jj++) {
                int ch = c * 32 + quad * 8 + jj;
                aS[c * 8 + jj]  = labF[ch];
                aBb[c * 8 + jj] = labF[CI1 + ch];
            }
    }

#define STAGE(ph)                                                              \
    {                                                                          \
        const short* _src = Wf + (size_t)(ph) * GSH + wid * WCH;               \
        short* _dst = &sB[wid * WCH];                                          \
        _Pragma("unroll")                                                      \
        for (int i = 0; i < S16; i++)                                          \
            __builtin_amdgcn_global_load_lds(                                  \
                (gas_short*)(_src + i * 512 + lane * 8),                       \
                (las_short*)(_dst + i * 512), 16, 0, 0);                       \
        _Pragma("unroll")                                                      \
        for (int i = 0; i < S4; i++)                                           \
            __builtin_amdgcn_global_load_lds(                                  \
                (gas_short*)(_src + S16 * 512 + i * 128 + lane * 2),           \
                (las_short*)(_dst + S16 * 512 + i * 128), 4, 0, 0);            \
    }

    STAGE(0)
    __builtin_amdgcn_sched_barrier(0);

    int idxs[MT][K];
#pragma unroll
    for (int mt = 0; mt < MT; mt++) {
        long long r = tb0 + mt * 16 + m;
        bool rv = r < N;
#pragma unroll
        for (int k = 0; k < K; k++)
            idxs[mt][k] = rv ? nbr[r * K + k] : -1;
    }
    unsigned pmask[MT];
#pragma unroll
    for (int mt = 0; mt < MT; mt++) {
        unsigned pm = 0;
#pragma unroll
        for (int k = 0; k < K; k++)
            pm |= __any(idxs[mt][k] >= 0) ? (1u << k) : 0u;
        pmask[mt] = __builtin_amdgcn_readfirstlane(pm);
    }

    __builtin_amdgcn_sched_barrier(0);
    asm volatile("s_waitcnt vmcnt(0)" ::: "memory");
    __builtin_amdgcn_s_barrier();
    __builtin_amdgcn_sched_barrier(0);
    asm volatile("" ::: "memory");

    short8 S[3][NCH];

#define LOADS(sl, mt, kk)                                                      \
    {                                                                          \
        int _i = idxs[mt][kk];                                                 \
        long long _j = _i < 0 ? 0 : _i;                                        \
        _Pragma("unroll")                                                      \
        for (int c = 0; c < NC1; c++) {                                        \
            short8 _v = *reinterpret_cast<const short8*>(                      \
                fA + _j * CI1 + c * 32 + quad * 8);                            \
            if constexpr (FACT) {                                              \
                short8 _o;                                                     \
                _Pragma("unroll")                                              \
                for (int jj = 0; jj < 8; jj++) {                               \
                    float _f = b2f(_v[jj]) * aS[c * 8 + jj] + aBb[c * 8 + jj]; \
                    _o[jj] = f2b(_f > 0.f ? _f : 0.f);                         \
                }                                                              \
                _v = _o;                                                       \
            }                                                                  \
            S[sl][c] = (_i >= 0) ? _v : (short8)0;                             \
        }                                                                      \
        if constexpr (NC2 > 0) {                                               \
            _Pragma("unroll")                                                  \
            for (int c = 0; c < NC2; c++) {                                    \
                short8 _v = *reinterpret_cast<const short8*>(                  \
                    fB + _j * CI2 + c * 32 + quad * 8);                        \
                S[sl][NC1 + c] = (_i >= 0) ? _v : (short8)0;                   \
            }                                                                  \
        }                                                                      \
    }
#define MFMAS(sl, mt, jl)                                                      \
    {                                                                          \
        _Pragma("unroll")                                                      \
        for (int c = 0; c < NCH; c++) {                                        \
            _Pragma("unroll")                                                  \
            for (int t = 0; t < NT; t++) {                                     \
                short8 b = *reinterpret_cast<const short8*>(                   \
                    &sB[((jl) * NCH * NT + c * NT + t) * 512 + lane * 8]);     \
                acc[mt][t] = __builtin_amdgcn_mfma_f32_16x16x32_bf16(          \
                    S[sl][c], b, acc[mt][t], 0, 0, 0);                         \
            }                                                                  \
        }                                                                      \
    }

#pragma unroll
    for (int ph = 0; ph < NPH; ph++) {
#pragma unroll
        for (int mt = 0; mt < MT; mt++) {
            const unsigned mm = (pmask[mt] >> (ph * G)) & ((1u << G) - 1);
#pragma unroll
            for (int j = 0; j < G + 2; j++) {
                if (j < G)
                    if (mm & (1u << j)) LOADS(j % 3, mt, ph * G + j)
                if (j >= 2)
                    if (mm & (1u << (j - 2))) MFMAS((j - 2) % 3, mt, j - 2)
            }
        }
        if (ph + 1 < NPH) {
            __builtin_amdgcn_sched_barrier(0);
            asm volatile("s_waitcnt lgkmcnt(0)" ::: "memory");
            __builtin_amdgcn_s_barrier();
            __builtin_amdgcn_sched_barrier(0);
            STAGE(ph + 1)
            __builtin_amdgcn_sched_barrier(0);
            asm volatile("s_waitcnt vmcnt(0)" ::: "memory");
            __builtin_amdgcn_s_barrier();
            __builtin_amdgcn_sched_barrier(0);
            asm volatile("" ::: "memory");
        }
    }
#undef LOADS
#undef MFMAS
#undef STAGE
    float s[NT], q[NT];
#pragma unroll
    for (int t = 0; t < NT; t++) { s[t] = 0.f; q[t] = 0.f; }
#pragma unroll
    for (int mt = 0; mt < MT; mt++) {
#pragma unroll
        for (int g4 = 0; g4 < 4; g4++) {
            long long sr = tb0 + mt * 16 + quad * 4 + g4;
            if (sr < N) {
#pragma unroll
                for (int t = 0; t < NT; t++) {
                    float v = acc[mt][t][g4];
                    out[sr * COUT + t * 16 + m] = f2b(v);
                    s[t] += v; q[t] += v * v;
                }
            }
        }
    }
    float* pb = pstat + (blockIdx.x & 7) * 2 * COUT;
#pragma unroll
    for (int t = 0; t < NT; t++) {
        float sv = s[t], qv = q[t];
        sv += __shfl_xor(sv, 16); qv += __shfl_xor(qv, 16);
        sv += __shfl_xor(sv, 32); qv += __shfl_xor(qv, 32);
        if (quad == 0) {
            atomicAdd(&pb[t * 16 + m], sv);
            atomicAdd(&pb[COUT + t * 16 + m], qv);
        }
    }
}

// ---------- MFMA up conv v10 + inline-BN input act -------------------------
template<int CIN, int COUT, int G>
__global__ __launch_bounds__(256) void upmfma10(
    const short* __restrict__ f, const int* __restrict__ rb,
    const short* __restrict__ Wf, short* __restrict__ out,
    float* __restrict__ pstat, BNP pF, int N) {
    static_assert(8 % G == 0, "G must divide 8");
    constexpr int NT = COUT / 16;
    constexpr int NK = CIN / 32;
    constexpr int PANEL = NK * NT * 512;
    constexpr int GSH   = G * PANEL;
    constexpr int NPH   = 8 / G;
    constexpr int WCH   = GSH / 4;
    constexpr int S16   = (WCH * 2) / 1024;
    constexpr int S4    = ((WCH * 2) % 1024) / 256;
    __shared__ __attribute__((aligned(16))) short sB[GSH];
    __shared__ float labF[2 * CIN];
    const int tid  = threadIdx.x;
    const int lane = tid & 63;
    const int wid  = tid >> 6;
    const int m    = lane & 15;
    const int quad = lane >> 4;
    const long long row0 = ((long long)blockIdx.x * 4 + wid) * 16;
    const long long r = row0 + m;
    const bool rv = r < N;
    const long long rc = rv ? r : 0;

    bn_load(pF, CIN, labF, tid);
    __syncthreads();

#define STAGE(ph)                                                              \
    {                                                                          \
        const short* _src = Wf + (size_t)(ph) * GSH + wid * WCH;               \
        short* _dst = &sB[wid * WCH];                                          \
        _Pragma("unroll")                                                      \
        for (int i = 0; i < S16; i++)                                          \
            __builtin_amdgcn_global_load_lds(                                  \
                (gas_short*)(_src + i * 512 + lane * 8),                       \
                (las_short*)(_dst + i * 512), 16, 0, 0);                       \
        _Pragma("unroll")                                                      \
        for (int i = 0; i < S4; i++)                                           \
            __builtin_amdgcn_global_load_lds(                                  \
                (gas_short*)(_src + S16 * 512 + i * 128 + lane * 2),           \
                (las_short*)(_dst + S16 * 512 + i * 128), 4, 0, 0);            \
    }
    STAGE(0)
    __builtin_amdgcn_sched_barrier(0);

    short8 af[NK];
#pragma unroll
    for (int kc = 0; kc < NK; kc++) {
        short8 v = *reinterpret_cast<const short8*>(
            f + rc * CIN + kc * 32 + quad * 8);
        short8 o;
#pragma unroll
        for (int jj = 0; jj < 8; jj++) {
            int ch = kc * 32 + quad * 8 + jj;
            float u = b2f(v[jj]) * labF[ch] + labF[CIN + ch];
            o[jj] = f2b(u > 0.f ? u : 0.f);
        }
        af[kc] = rv ? o : (short8)0;
    }
    int sidx[8][4];
#pragma unroll
    for (int g4 = 0; g4 < 4; g4++) {
        long long sr = row0 + quad * 4 + g4;
#pragma unroll
        for (int k = 0; k < 8; k++)
            sidx[k][g4] = (sr < N) ? rb[sr * 8 + k] : -1;
    }
    unsigned pm = 0;
#pragma unroll
    for (int k = 0; k < 8; k++) {
        int anyv = (sidx[k][0] >= 0) | (sidx[k][1] >= 0) |
                   (sidx[k][2] >= 0) | (sidx[k][3] >= 0);
        pm |= __any(anyv) ? (1u << k) : 0u;
    }
    pm = __builtin_amdgcn_readfirstlane(pm);

    float s[NT], q[NT];
#pragma unroll
    for (int t = 0; t < NT; t++) { s[t] = 0.f; q[t] = 0.f; }

    __builtin_amdgcn_sched_barrier(0);
    asm volatile("s_waitcnt vmcnt(0)" ::: "memory");
    __builtin_amdgcn_s_barrier();
    __builtin_amdgcn_sched_barrier(0);
    asm volatile("" ::: "memory");

#pragma unroll
    for (int ph = 0; ph < NPH; ph++) {
#pragma unroll
        for (int j = 0; j < G; j++) {
            const int k = ph * G + j;
            if (pm & (1u << k)) {
                f32x4 acc[NT];
#pragma unroll
                for (int t = 0; t < NT; t++) acc[t] = (f32x4)0.f;
#pragma unroll
                for (int kc = 0; kc < NK; kc++) {
#pragma unroll
                    for (int t = 0; t < NT; t++) {
                        short8 b = *reinterpret_cast<const short8*>(
                            &sB[(j * NK * NT + kc * NT + t) * 512 + lane * 8]);
                        acc[t] = __builtin_amdgcn_mfma_f32_16x16x32_bf16(
                            af[kc], b, acc[t], 0, 0, 0);
                    }
                }
#pragma unroll
                for (int g4 = 0; g4 < 4; g4++) {
                    if (sidx[k][g4] >= 0) {
#pragma unroll
                        for (int t = 0; t < NT; t++) {
                            float v = acc[t][g4];
                            out[(long long)sidx[k][g4] * COUT + t * 16 + m] =
                                f2b(v);
                            s[t] += v; q[t] += v * v;
                        }
                    }
                }
            }
        }
        if (ph + 1 < NPH) {
            __builtin_amdgcn_sched_barrier(0);
            asm volatile("s_waitcnt lgkmcnt(0)" ::: "memory");
            __builtin_amdgcn_s_barrier();
            __builtin_amdgcn_sched_barrier(0);
            STAGE(ph + 1)
            __builtin_amdgcn_sched_barrier(0);
            asm volatile("s_waitcnt vmcnt(0)" ::: "memory");
            __builtin_amdgcn_s_barrier();
            __builtin_amdgcn_sched_barrier(0);
            asm volatile("" ::: "memory");
        }
    }
#undef STAGE
    float* pb = pstat + (blockIdx.x & 7) * 2 * COUT;
#pragma unroll
    for (int t = 0; t < NT; t++) {
        float sv = s[t], qv = q[t];
        sv += __shfl_xor(sv, 16); qv += __shfl_xor(qv, 16);
        sv += __shfl_xor(sv, 32); qv += __shfl_xor(qv, 32);
        if (quad == 0) {
            atomicAdd(&pb[t * 16 + m], sv);
            atomicAdd(&pb[COUT + t * 16 + m], qv);
        }
    }
}

// ---------- bnact_i: inline-BN relu pass -----------------------------------
template<int C>
__global__ __launch_bounds__(256) void bnact_i(
    const short* __restrict__ x, BNP p, short* __restrict__ y, long long total8) {
    __shared__ float lab[2 * C];
    const int tid = threadIdx.x;
    bn_load(p, C, lab, tid);
    __syncthreads();
    long long i = (long long)blockIdx.x * 256 + tid;
    if (i >= total8) return;
    long long base = i * 8;
    int c0 = (int)(base % C);
    short8 v = *reinterpret_cast<const short8*>(x + base);
    short8 o;
#pragma unroll
    for (int j = 0; j < 8; j++) {
        float f = b2f(v[j]) * lab[c0 + j] + lab[C + c0 + j];
        o[j] = f2b(f > 0.f ? f : 0.f);
    }
    *reinterpret_cast<short8*>(y + base) = o;
}

// ---------- bnact2_i: two tensors, inline BN -------------------------------
template<int C>
__global__ __launch_bounds__(256) void bnact2_i(
    const short* __restrict__ xa, BNP pa, short* __restrict__ ya,
    const short* __restrict__ xb, BNP pb, short* __restrict__ yb, long long n8) {
    __shared__ float la[2 * C], lb[2 * C];
    const int tid = threadIdx.x;
    bn_load(pa, C, la, tid);
    bn_load(pb, C, lb, tid);
    __syncthreads();
    long long i = (long long)blockIdx.x * 256 + tid;
    if (i >= 2 * n8) return;
    const short* x; const float* lab; short* y; long long ii;
    if (i < n8) { x = xa; lab = la; y = ya; ii = i; }
    else        { x = xb; lab = lb; y = yb; ii = i - n8; }
    long long base = ii * 8;
    int c0 = (int)(base % C);
    short8 v = *reinterpret_cast<const short8*>(x + base);
    short8 o;
#pragma unroll
    for (int j = 0; j < 8; j++) {
        float f = b2f(v[j]) * lab[c0 + j] + lab[C + c0 + j];
        o[j] = f2b(f > 0.f ? f : 0.f);
    }
    *reinterpret_cast<short8*>(y + base) = o;
}

// ---------- final linear (inline bnf), bf16 in, f32 out --------------------
__global__ __launch_bounds__(256) void final_k_i(
    const short* __restrict__ x, BNP p,
    const float* __restrict__ lw, const float* __restrict__ lb,
    float* __restrict__ out, int N) {
    __shared__ float lab[64];
    const int tid = threadIdx.x;
    bn_load(p, 32, lab, tid);
    __syncthreads();
    long long r = (long long)blockIdx.x * 256 + tid;
    if (r >= N) return;
    float a0 = lb[0], a1 = lb[1];
#pragma unroll
    for (int j = 0; j < 4; j++) {
        short8 v = *reinterpret_cast<const short8*>(x + r * 32 + j * 8);
#pragma unroll
        for (int t = 0; t < 8; t++) {
            int ci = 8 * j + t;
            float u = b2f(v[t]) * lab[ci] + lab[32 + ci];
            u = u > 0.f ? u : 0.f;
            a0 += u * lw[ci * 2];
            a1 += u * lw[ci * 2 + 1];
        }
    }
    out[2 * r]     = a0;
    out[2 * r + 1] = a1;
}

extern "C" void kernel_launch(void* const* d_in, const int* in_sizes, int n_in,
                              void* d_out, int out_size, void* d_ws, size_t ws_size,
                              hipStream_t stream) {
    const long long N0 = in_sizes[0] / 3;
    const long long N1 = in_sizes[26] / 8;
    const long long N2 = in_sizes[27] / 8;

    const float* feat = (const float*)d_in[0];
    const int* nbr0 = (const int*)d_in[23];
    const int* nbr1 = (const int*)d_in[24];
    const int* nbr2 = (const int*)d_in[25];
    const int* rb0  = (const int*)d_in[26];
    const int* rb1  = (const int*)d_in[27];

    // ---- arena ----
    char* p = (char*)d_ws;
    float*  pst  = (float*)p;             p += (size_t)10 * 2048 * 4;
    unsigned* msk0 = (unsigned*)p;        p += ((size_t)N0 * 4 + 63) & ~(size_t)63;
    const int wLayer[9] = {3, 5, 7, 9, 11, 13, 15, 17, 19};
    const int wK[9]  = {27, 8, 27, 8, 27, 8, 27, 8, 27};
    const int wCI[9] = {32, 32, 64, 64, 96, 96, 128, 64, 64};
    const int wCO[9] = {32, 64, 64, 96, 96, 64, 64, 32, 32};
    short* wt[9];
    WPA wpa;
    int cum = 0;
    for (int i = 0; i < 9; i++) {
        wt[i] = (short*)p;
        int n = wK[i] * wCI[i] * wCO[i];
        p += (((size_t)n * 2 + 63) & ~(size_t)63);
        wpa.src[i] = (const float*)d_in[wLayer[i]];
        wpa.dst[i] = wt[i];
        wpa.CI[i] = wCI[i]; wpa.CO[i] = wCO[i];
        wpa.cum[i] = cum; cum += n;
    }
    wpa.cum[9] = cum;
    auto balloc = [&](long long elems) {
        short* q = (short*)p;
        p += (((size_t)elems * 2 + 63) & ~(size_t)63);
        return q;
    };
    short* R0 = balloc(N0 * 32);   // t0 / d0 / d1 / u1 / u0 (raw)
    short* R1 = balloc(N0 * 32);   // x0 raw (persist)
    short* R2 = balloc(N1 * 64);   // x1 raw (persist)
    short* R3 = balloc(N0 * 32);   // x2 / y1 / y0 (raw)
    short* Xb = balloc(N0 * 32);   // act out #1
    short* Yb = balloc(N0 * 32);   // act out #2

    const int wb = (cum + 255) / 256;
    const int nb = (int)((N0 + 255) / 256);
    prep_all<<<wb + nb, 256, 0, stream>>>(wpa, cum, wb, nbr0, msk0, pst, (int)N0);

#define PS(SL) (pst + (SL) * 2048)
#define GB1(N_) (int)(((N_) + 63) / 64)
#define GB2(N_) (int)(((N_) + 127) / 128)

    auto mkp = [&](float* pstp, int gbi, int gbfull, int goff, double invN) {
        BNP b;
        b.pst = pstp; b.abd = nullptr;
        b.gb = (gbi >= 0) ? (const float*)d_in[gbi] : nullptr;
        b.gbfull = gbfull; b.goff = goff; b.invN = invN;
        return b;
    };
    BNP dummy = mkp(nullptr, -1, 0, 0, 0.0);

    // ---- level 0 ----
    conv_in_st<<<nb, 256, 0, stream>>>(
        feat, msk0, (const float*)d_in[1], R0, PS(9), (int)N0);           // t0 -> R0
    stencil0<32, 0, 32><<<GB2(N0), 256, 0, stream>>>(
        R0, nullptr, msk0, wt[0], R1, PS(0),
        mkp(PS(9), 2, 32, 0, 1.0 / (double)N0), dummy, (int)N0);          // x0 -> R1
    gmfma10<32, 0, 64, 8, 8, 2, true><<<GB2(N1), 256, 0, stream>>>(
        R1, nullptr, rb0, wt[1], R0, PS(1),
        mkp(PS(0), 4, 32, 0, 1.0 / (double)N0), (int)N1);                 // d0 -> R0

    // ---- level 1 ----
    bnact_i<64><<<(int)((N1 * 64 / 8 + 255) / 256), 256, 0, stream>>>(
        R0, mkp(PS(1), 6, 64, 0, 1.0 / (double)N1), Xb, N1 * 64 / 8);
    gmfma10<64, 0, 64, 27, 3, 2, false><<<GB2(N1), 256, 0, stream>>>(
        Xb, nullptr, nbr1, wt[2], R2, PS(2), dummy, (int)N1);             // x1 -> R2
    gmfma10<64, 0, 96, 8, 2, 1, true><<<GB1(N2), 256, 0, stream>>>(
        R2, nullptr, rb1, wt[3], R0, PS(3),
        mkp(PS(2), 8, 64, 0, 1.0 / (double)N1), (int)N2);                 // d1 -> R0

    // ---- level 2 ----
    bnact_i<96><<<(int)((N2 * 96 / 8 + 255) / 256), 256, 0, stream>>>(
        R0, mkp(PS(3), 10, 96, 0, 1.0 / (double)N2), Xb, N2 * 96 / 8);
    gmfma10<96, 0, 96, 27, 3, 1, false><<<GB1(N2), 256, 0, stream>>>(
        Xb, nullptr, nbr2, wt[4], R3, PS(4), dummy, (int)N2);             // x2 -> R3

    // ---- up to level 1 ----
    upmfma10<96, 64, 2><<<GB1(N2), 256, 0, stream>>>(
        R3, rb1, wt[5], R0, PS(5),
        mkp(PS(4), 12, 96, 0, 1.0 / (double)N2), (int)N2);                // u1 -> R0
    bnact2_i<64><<<(int)((2 * (N1 * 64 / 8) + 255) / 256), 256, 0, stream>>>(
        R2, mkp(PS(2), 14, 128, 0, 1.0 / (double)N1), Xb,
        R0, mkp(PS(5), 14, 128, 64, 1.0 / (double)N1), Yb, N1 * 64 / 8);
    gmfma10<64, 64, 64, 27, 3, 2, false><<<GB2(N1), 256, 0, stream>>>(
        Xb, Yb, nbr1, wt[6], R3, PS(6), dummy, (int)N1);                  // y1 -> R3

    // ---- up to level 0 ----
    upmfma10<64, 32, 4><<<GB1(N1), 256, 0, stream>>>(
        R3, rb0, wt[7], R0, PS(7),
        mkp(PS(6), 16, 64, 0, 1.0 / (double)N1), (int)N1);                // u0 -> R0
    stencil0<32, 32, 32><<<GB2(N0), 256, 0, stream>>>(
        R1, R0, msk0, wt[8], R3, PS(8),
        mkp(PS(0), 18, 64, 0, 1.0 / (double)N0),
        mkp(PS(7), 18, 64, 32, 1.0 / (double)N0), (int)N0);               // y0 -> R3

    final_k_i<<<nb, 256, 0, stream>>>(
        R3, mkp(PS(8), 20, 32, 0, 1.0 / (double)N0),
        (const float*)d_in[21], (const float*)d_in[22],
        (float*)d_out, (int)N0);

#undef PS
#undef GB1
#undef GB2
}